// Round 10
// baseline (3292.514 us; speedup 1.0000x reference)
//
#include <hip/hip_runtime.h>
#include <hip/hip_bf16.h>
#include <math.h>

// Problem dims
#define NB 16
#define NS 256
#define ND 512
#define NH 1024
#define NF 2048
#define NHID 256

typedef __attribute__((ext_vector_type(8))) short bf16x8;
typedef __attribute__((ext_vector_type(4))) float f32x4;

__device__ __forceinline__ unsigned short f2bf(float f) {
    unsigned u = __float_as_uint(f);
    unsigned r = u + 0x7fffu + ((u >> 16) & 1u);
    return (unsigned short)(r >> 16);
}
__device__ __forceinline__ float bf2f(unsigned short h) {
    return __uint_as_float(((unsigned)h) << 16);
}

// ---------------------------------------------------------------------------
// Split-bf16 MFMA GEMM v3: C[M,N] = A[M,K] @ B[N,K]^T (+bias)(+gelu)
// Pre-split hi/lo bf16 operands, 3-pass (Ah*Bh + Al*Bh + Ah*Bl ~ fp32).
// lda/ldb: row strides in u16 elems. global_load_lds width-16 staging,
// linear LDS (m97 structure). Tile 128x128, BK=32, 256 thr. Z-batched.
// ---------------------------------------------------------------------------
template<int ACT, int OUT_SPLIT>
__global__ __launch_bounds__(256) void sgemm3(
    const unsigned short* __restrict__ Ahi, const unsigned short* __restrict__ Alo,
    const unsigned short* __restrict__ Bhi, const unsigned short* __restrict__ Blo,
    const float* __restrict__ bias,
    float* __restrict__ C, unsigned short* __restrict__ Chi, unsigned short* __restrict__ Clo,
    int M, int N, int K, int lda, int ldb, long sA, long sB, long sC)
{
    __shared__ unsigned short Ah[128 * 32];
    __shared__ unsigned short Al[128 * 32];
    __shared__ unsigned short Bh[128 * 32];
    __shared__ unsigned short Bl[128 * 32];

    const int t = threadIdx.x;
    const int z = blockIdx.z;
    const int m0 = blockIdx.y * 128, n0 = blockIdx.x * 128;
    const int wid = t >> 6, lane = t & 63;
    const int wr = (wid >> 1) * 64, wc = (wid & 1) * 64;
    const int lr = lane & 15, lk = lane >> 4;
    const int rl = lane >> 2, sl = lane & 3;

    const unsigned short* pAh = Ahi + (size_t)z * sA;
    const unsigned short* pAl = Alo + (size_t)z * sA;
    const unsigned short* pBh = Bhi + (size_t)z * sB;
    const unsigned short* pBl = Blo + (size_t)z * sB;

    f32x4 acc[4][4];
    #pragma unroll
    for (int i = 0; i < 4; ++i)
        #pragma unroll
        for (int j = 0; j < 4; ++j) acc[i][j] = (f32x4){0.f, 0.f, 0.f, 0.f};

    for (int k0 = 0; k0 < K; k0 += 32) {
        #pragma unroll
        for (int e = 0; e < 2; ++e) {
            const int r = e * 64 + wid * 16 + rl;
            const size_t goA = (size_t)(m0 + r) * lda + k0 + sl * 8;
            const size_t goB = (size_t)(n0 + r) * ldb + k0 + sl * 8;
            const int lo = (e * 64 + wid * 16) * 32;
            __builtin_amdgcn_global_load_lds((const void*)(pAh + goA), (void*)&Ah[lo], 16, 0, 0);
            __builtin_amdgcn_global_load_lds((const void*)(pAl + goA), (void*)&Al[lo], 16, 0, 0);
            __builtin_amdgcn_global_load_lds((const void*)(pBh + goB), (void*)&Bh[lo], 16, 0, 0);
            __builtin_amdgcn_global_load_lds((const void*)(pBl + goB), (void*)&Bl[lo], 16, 0, 0);
        }
        __syncthreads();

        bf16x8 ah[4], al[4], bh[4], bl[4];
        #pragma unroll
        for (int mt = 0; mt < 4; ++mt) {
            int rf = wr + mt * 16 + lr;
            ah[mt] = *(const bf16x8*)&Ah[rf * 32 + lk * 8];
            al[mt] = *(const bf16x8*)&Al[rf * 32 + lk * 8];
        }
        #pragma unroll
        for (int nt = 0; nt < 4; ++nt) {
            int rf = wc + nt * 16 + lr;
            bh[nt] = *(const bf16x8*)&Bh[rf * 32 + lk * 8];
            bl[nt] = *(const bf16x8*)&Bl[rf * 32 + lk * 8];
        }
        #pragma unroll
        for (int mt = 0; mt < 4; ++mt)
            #pragma unroll
            for (int nt = 0; nt < 4; ++nt) {
                acc[mt][nt] = __builtin_amdgcn_mfma_f32_16x16x32_bf16(ah[mt], bh[nt], acc[mt][nt], 0, 0, 0);
                acc[mt][nt] = __builtin_amdgcn_mfma_f32_16x16x32_bf16(al[mt], bh[nt], acc[mt][nt], 0, 0, 0);
                acc[mt][nt] = __builtin_amdgcn_mfma_f32_16x16x32_bf16(ah[mt], bl[nt], acc[mt][nt], 0, 0, 0);
            }
        __syncthreads();
    }

    #pragma unroll
    for (int nt = 0; nt < 4; ++nt) {
        int col = n0 + wc + nt * 16 + lr;
        float bv = bias ? bias[col] : 0.0f;
        #pragma unroll
        for (int mt = 0; mt < 4; ++mt) {
            #pragma unroll
            for (int i = 0; i < 4; ++i) {
                int row = m0 + wr + mt * 16 + lk * 4 + i;
                float x = acc[mt][nt][i] + bv;
                if (ACT == 1) x = 0.5f * x * (1.0f + erff(x * 0.70710678118654752f));
                size_t oi = (size_t)z * sC + (size_t)row * N + col;
                if (OUT_SPLIT) {
                    unsigned short h = f2bf(x);
                    Chi[oi] = h;
                    Clo[oi] = f2bf(x - bf2f(h));
                } else {
                    C[oi] = x;
                }
            }
        }
    }
}

static void gemm_f(int act, const unsigned short* Ahi, const unsigned short* Alo,
                   const unsigned short* Bhi, const unsigned short* Blo,
                   const float* bias, float* C, int M, int N, int K, int lda, int ldb,
                   long sA, long sB, long sC, int Z, hipStream_t st)
{
    dim3 g(N / 128, M / 128, Z), b(256);
    if (act) sgemm3<1, 0><<<g, b, 0, st>>>(Ahi, Alo, Bhi, Blo, bias, C, nullptr, nullptr, M, N, K, lda, ldb, sA, sB, sC);
    else     sgemm3<0, 0><<<g, b, 0, st>>>(Ahi, Alo, Bhi, Blo, bias, C, nullptr, nullptr, M, N, K, lda, ldb, sA, sB, sC);
}
static void gemm_s(int act, const unsigned short* Ahi, const unsigned short* Alo,
                   const unsigned short* Bhi, const unsigned short* Blo,
                   const float* bias, unsigned short* Chi, unsigned short* Clo,
                   int M, int N, int K, int lda, int ldb,
                   long sA, long sB, long sC, int Z, hipStream_t st)
{
    dim3 g(N / 128, M / 128, Z), b(256);
    if (act) sgemm3<1, 1><<<g, b, 0, st>>>(Ahi, Alo, Bhi, Blo, bias, nullptr, Chi, Clo, M, N, K, lda, ldb, sA, sB, sC);
    else     sgemm3<0, 1><<<g, b, 0, st>>>(Ahi, Alo, Bhi, Blo, bias, nullptr, Chi, Clo, M, N, K, lda, ldb, sA, sB, sC);
}

// ---------------------------------------------------------------------------
// fp32 -> split bf16 hi/lo (n multiple of 1024)
// ---------------------------------------------------------------------------
__global__ __launch_bounds__(256) void cvt_split(const float* __restrict__ in,
                                                 unsigned short* __restrict__ hi,
                                                 unsigned short* __restrict__ lo)
{
    size_t i = ((size_t)blockIdx.x * 256 + threadIdx.x) * 4;
    float4 v = *(const float4*)(in + i);
    ushort4 h, l;
    h.x = f2bf(v.x); l.x = f2bf(v.x - bf2f(h.x));
    h.y = f2bf(v.y); l.y = f2bf(v.y - bf2f(h.y));
    h.z = f2bf(v.z); l.z = f2bf(v.z - bf2f(h.z));
    h.w = f2bf(v.w); l.w = f2bf(v.w - bf2f(h.w));
    *(ushort4*)(hi + i) = h;
    *(ushort4*)(lo + i) = l;
}

// ---------------------------------------------------------------------------
// bf16 (R,C) -> (C,R) transpose, z-batched. R,C multiples of 64.
// ---------------------------------------------------------------------------
__global__ __launch_bounds__(256) void tcvt_bf16(const unsigned short* __restrict__ in,
                                                 unsigned short* __restrict__ out,
                                                 int R, int C)
{
    __shared__ unsigned short tile[64 * 72];
    int z = blockIdx.z;
    in += (size_t)z * R * C;
    out += (size_t)z * R * C;
    int r0 = blockIdx.y * 64, c0 = blockIdx.x * 64;
    int t = threadIdx.x;
    int tr = t >> 2, tc = (t & 3) * 16;

    uint4 q0 = *(const uint4*)(in + (size_t)(r0 + tr) * C + c0 + tc);
    uint4 q1 = *(const uint4*)(in + (size_t)(r0 + tr) * C + c0 + tc + 8);
    unsigned short e[16];
    *(uint4*)(e) = q0;
    *(uint4*)(e + 8) = q1;
    #pragma unroll
    for (int i = 0; i < 16; ++i) tile[(tc + i) * 72 + tr] = e[i];
    __syncthreads();

    uint4 o0 = *(const uint4*)(&tile[tr * 72 + tc]);
    uint4 o1 = *(const uint4*)(&tile[tr * 72 + tc + 8]);
    *(uint4*)(out + (size_t)(c0 + tr) * R + r0 + tc) = o0;
    *(uint4*)(out + (size_t)(c0 + tr) * R + r0 + tc + 8) = o1;
}

// ---------------------------------------------------------------------------
// bias combine
// ---------------------------------------------------------------------------
__global__ __launch_bounds__(256) void bias_sum_kernel(
    const float* bihF, const float* bhhF, const float* bihB, const float* bhhB,
    float* out)
{
    int i = blockIdx.x * 256 + threadIdx.x;
    if (i < 1024) out[i] = bihF[i] + bhhF[i];
    else out[i] = bihB[i - 1024] + bhhB[i - 1024];
}

// ---------------------------------------------------------------------------
// LSTM recurrence v9: both directions staggered through one block so each
// chain's flag->poll->h-load MALL round trip hides under the other chain's
// compute. grid = 16 blocks (slice), block = 512 (8 waves).
// Wave wv: gate = wv&3, K-half = wv>>2; holds weight fragments for BOTH
// dirs (register-resident, split hi/lo). Flag protocol = rec6's proven
// fence-free release (vmcnt(0) + barrier + relaxed AGENT flag store);
// h packed u32 (bf16 hi|lo) per unit via relaxed AGENT atomics.
// Per iter: F{poll,load,MFMA,elemwise,release} then B{...}. flagF is
// released BEFORE the B phase, so next iter's F poll sees it ~1 phase later.
// ---------------------------------------------------------------------------
__global__ __launch_bounds__(512) void lstm_rec9(
    const float* __restrict__ pre,
    const float* __restrict__ WhhF, const float* __restrict__ WhhB,
    unsigned* __restrict__ hgu,   // [2 parity][2 dir][16 b][256 u] u32
    int* __restrict__ flags,      // [32]: [0..15]=F slices, [16..31]=B
    unsigned short* __restrict__ fhi, unsigned short* __restrict__ flo)
{
    const int slice = blockIdx.x;
    const int tid = threadIdx.x;
    const int wv = tid >> 6;                 // 0..7
    const int lane = tid & 63;
    const int lr = lane & 15, lk = lane >> 4;
    const int gate = wv & 3, kh = wv >> 2;   // gate, K-half (128 each)
    const int eb = (tid >> 4) & 15, eu = tid & 15;   // elementwise (tid<256)

    __shared__ unsigned short hF[16 * 264], lF[16 * 264];
    __shared__ unsigned short hB[16 * 264], lB[16 * 264];
    __shared__ float gp[2][4][16][17];       // [khalf][gate][batch][unit]

    // ---- one-time: weight fragments for both dirs (split hi/lo), 4 ktiles
    bf16x8 wFh[4], wFl[4], wBh[4], wBl[4];
    {
        const size_t ro = (size_t)(gate * 256 + slice * 16 + lr) * 256 + kh * 128 + lk * 8;
        const float* wf = WhhF + ro;
        const float* wb = WhhB + ro;
        #pragma unroll
        for (int kt = 0; kt < 4; ++kt) {
            float vf[8], vb[8];
            *(float4*)(vf)     = *(const float4*)(wf + kt * 32);
            *(float4*)(vf + 4) = *(const float4*)(wf + kt * 32 + 4);
            *(float4*)(vb)     = *(const float4*)(wb + kt * 32);
            *(float4*)(vb + 4) = *(const float4*)(wb + kt * 32 + 4);
            unsigned short fh[8], fl[8], bh[8], bl[8];
            #pragma unroll
            for (int i = 0; i < 8; ++i) {
                unsigned short h = f2bf(vf[i]);
                fh[i] = h; fl[i] = f2bf(vf[i] - bf2f(h));
                h = f2bf(vb[i]);
                bh[i] = h; bl[i] = f2bf(vb[i] - bf2f(h));
            }
            wFh[kt] = *(bf16x8*)fh; wFl[kt] = *(bf16x8*)fl;
            wBh[kt] = *(bf16x8*)bh; wBl[kt] = *(bf16x8*)bl;
        }
    }
    for (int i = tid; i < 16 * 264; i += 512) {
        hF[i] = 0; lF[i] = 0; hB[i] = 0; lB[i] = 0;
    }
    float cF = 0.0f, cB = 0.0f;
    __syncthreads();

    for (int si = 0; si < NS; ++si) {
        const int sF = si, sB = NS - 1 - si;
        // pre loads for both dirs, issued at iter start (hide under polls)
        float piF, pfF, pgF, poF, piB, pfB, pgB, poB;
        if (tid < 256) {
            const float* ppF = pre + ((size_t)(eb * NS + sF)) * 2048 + slice * 16 + eu;
            const float* ppB = pre + ((size_t)(eb * NS + sB)) * 2048 + 1024 + slice * 16 + eu;
            piF = ppF[0]; pfF = ppF[256]; pgF = ppF[512]; poF = ppF[768];
            piB = ppB[0]; pfB = ppB[256]; pgB = ppB[512]; poB = ppB[768];
        }

        // ================= F phase =================
        if (si > 0) {
            if (tid < 16) {
                while (__hip_atomic_load(&flags[tid], __ATOMIC_RELAXED,
                                         __HIP_MEMORY_SCOPE_AGENT) < si) {
                    __builtin_amdgcn_s_sleep(1);
                }
            }
            __syncthreads();
            const unsigned* src = hgu + (size_t)(((si - 1) & 1) * 2 + 0) * 4096;
            #pragma unroll
            for (int j = 0; j < 8; ++j) {
                int idx = tid + 512 * j;
                unsigned v = __hip_atomic_load(&src[idx], __ATOMIC_RELAXED,
                                               __HIP_MEMORY_SCOPE_AGENT);
                int b = idx >> 8, u = idx & 255;
                hF[b * 264 + u] = (unsigned short)(v & 0xffff);
                lF[b * 264 + u] = (unsigned short)(v >> 16);
            }
            __syncthreads();
        }
        {   // MFMA F: wave's gate, K-half
            f32x4 acc = (f32x4){0.f, 0.f, 0.f, 0.f};
            #pragma unroll
            for (int kt = 0; kt < 4; ++kt) {
                const char* hp = (const char*)hF + lr * 528 + kh * 256 + kt * 64 + lk * 16;
                const char* lp = (const char*)lF + lr * 528 + kh * 256 + kt * 64 + lk * 16;
                bf16x8 ah = *(const bf16x8*)hp;
                bf16x8 al = *(const bf16x8*)lp;
                acc = __builtin_amdgcn_mfma_f32_16x16x32_bf16(ah, wFh[kt], acc, 0, 0, 0);
                acc = __builtin_amdgcn_mfma_f32_16x16x32_bf16(al, wFh[kt], acc, 0, 0, 0);
                acc = __builtin_amdgcn_mfma_f32_16x16x32_bf16(ah, wFl[kt], acc, 0, 0, 0);
            }
            #pragma unroll
            for (int i = 0; i < 4; ++i) gp[kh][gate][lk * 4 + i][lr] = acc[i];
        }
        __syncthreads();
        if (tid < 256) {
            float ai = gp[0][0][eb][eu] + gp[1][0][eb][eu] + piF;
            float af = gp[0][1][eb][eu] + gp[1][1][eb][eu] + pfF;
            float ag = gp[0][2][eb][eu] + gp[1][2][eb][eu] + pgF;
            float ao = gp[0][3][eb][eu] + gp[1][3][eb][eu] + poF;
            float gi = 1.0f / (1.0f + expf(-ai));
            float gf = 1.0f / (1.0f + expf(-af));
            float gg = tanhf(ag);
            float go = 1.0f / (1.0f + expf(-ao));
            cF = gf * cF + gi * gg;
            float h = go * tanhf(cF);
            unsigned short h16 = f2bf(h);
            unsigned short l16 = f2bf(h - bf2f(h16));
            unsigned* dst = hgu + (size_t)((si & 1) * 2 + 0) * 4096;
            __hip_atomic_store(&dst[eb * 256 + slice * 16 + eu],
                               (unsigned)h16 | ((unsigned)l16 << 16),
                               __ATOMIC_RELAXED, __HIP_MEMORY_SCOPE_AGENT);
            size_t oi = ((size_t)(eb * NS + sF)) * 512 + slice * 16 + eu;
            fhi[oi] = h16;
            flo[oi] = l16;
        }
        asm volatile("s_waitcnt vmcnt(0)" ::: "memory");
        __syncthreads();
        if (tid == 0)
            __hip_atomic_store(&flags[slice], si + 1, __ATOMIC_RELAXED,
                               __HIP_MEMORY_SCOPE_AGENT);

        // ================= B phase =================
        if (si > 0) {
            if (tid < 16) {
                while (__hip_atomic_load(&flags[16 + tid], __ATOMIC_RELAXED,
                                         __HIP_MEMORY_SCOPE_AGENT) < si) {
                    __builtin_amdgcn_s_sleep(1);
                }
            }
            __syncthreads();
            const unsigned* src = hgu + (size_t)(((si - 1) & 1) * 2 + 1) * 4096;
            #pragma unroll
            for (int j = 0; j < 8; ++j) {
                int idx = tid + 512 * j;
                unsigned v = __hip_atomic_load(&src[idx], __ATOMIC_RELAXED,
                                               __HIP_MEMORY_SCOPE_AGENT);
                int b = idx >> 8, u = idx & 255;
                hB[b * 264 + u] = (unsigned short)(v & 0xffff);
                lB[b * 264 + u] = (unsigned short)(v >> 16);
            }
            __syncthreads();
        }
        {   // MFMA B
            f32x4 acc = (f32x4){0.f, 0.f, 0.f, 0.f};
            #pragma unroll
            for (int kt = 0; kt < 4; ++kt) {
                const char* hp = (const char*)hB + lr * 528 + kh * 256 + kt * 64 + lk * 16;
                const char* lp = (const char*)lB + lr * 528 + kh * 256 + kt * 64 + lk * 16;
                bf16x8 ah = *(const bf16x8*)hp;
                bf16x8 al = *(const bf16x8*)lp;
                acc = __builtin_amdgcn_mfma_f32_16x16x32_bf16(ah, wBh[kt], acc, 0, 0, 0);
                acc = __builtin_amdgcn_mfma_f32_16x16x32_bf16(al, wBh[kt], acc, 0, 0, 0);
                acc = __builtin_amdgcn_mfma_f32_16x16x32_bf16(ah, wBl[kt], acc, 0, 0, 0);
            }
            #pragma unroll
            for (int i = 0; i < 4; ++i) gp[kh][gate][lk * 4 + i][lr] = acc[i];
        }
        __syncthreads();
        if (tid < 256) {
            float ai = gp[0][0][eb][eu] + gp[1][0][eb][eu] + piB;
            float af = gp[0][1][eb][eu] + gp[1][1][eb][eu] + pfB;
            float ag = gp[0][2][eb][eu] + gp[1][2][eb][eu] + pgB;
            float ao = gp[0][3][eb][eu] + gp[1][3][eb][eu] + poB;
            float gi = 1.0f / (1.0f + expf(-ai));
            float gf = 1.0f / (1.0f + expf(-af));
            float gg = tanhf(ag);
            float go = 1.0f / (1.0f + expf(-ao));
            cB = gf * cB + gi * gg;
            float h = go * tanhf(cB);
            unsigned short h16 = f2bf(h);
            unsigned short l16 = f2bf(h - bf2f(h16));
            unsigned* dst = hgu + (size_t)((si & 1) * 2 + 1) * 4096;
            __hip_atomic_store(&dst[eb * 256 + slice * 16 + eu],
                               (unsigned)h16 | ((unsigned)l16 << 16),
                               __ATOMIC_RELAXED, __HIP_MEMORY_SCOPE_AGENT);
            size_t oi = ((size_t)(eb * NS + sB)) * 512 + 256 + slice * 16 + eu;
            fhi[oi] = h16;
            flo[oi] = l16;
        }
        asm volatile("s_waitcnt vmcnt(0)" ::: "memory");
        __syncthreads();
        if (tid == 0)
            __hip_atomic_store(&flags[16 + slice], si + 1, __ATOMIC_RELAXED,
                               __HIP_MEMORY_SCOPE_AGENT);
    }
}

// ---------------------------------------------------------------------------
// In-place split softmax: row of N fp32 -> same memory becomes
// [N hi bf16][N lo bf16]. grid = rows, block = 256, N in {256, 1024}.
// ---------------------------------------------------------------------------
__global__ __launch_bounds__(256) void softmax_ip(float* __restrict__ X, int N)
{
    float* row = X + (size_t)blockIdx.x * N;
    unsigned short* o = (unsigned short*)row;
    int t = threadIdx.x;
    int cnt = N >> 8;
    float v[4];
    float m = -1e30f;
    for (int i = 0; i < cnt; ++i) { v[i] = row[t + (i << 8)]; m = fmaxf(m, v[i]); }
    for (int sh = 32; sh; sh >>= 1) m = fmaxf(m, __shfl_xor(m, sh));
    __shared__ float lm[4];
    if ((t & 63) == 0) lm[t >> 6] = m;
    __syncthreads();
    m = fmaxf(fmaxf(lm[0], lm[1]), fmaxf(lm[2], lm[3]));
    float s = 0.0f;
    for (int i = 0; i < cnt; ++i) { v[i] = expf(v[i] - m); s += v[i]; }
    for (int sh = 32; sh; sh >>= 1) s += __shfl_xor(s, sh);
    __shared__ float ls[4];
    if ((t & 63) == 0) ls[t >> 6] = s;
    __syncthreads();
    s = ls[0] + ls[1] + ls[2] + ls[3];
    float inv = 1.0f / s;
    __syncthreads();
    for (int i = 0; i < cnt; ++i) {
        float y = v[i] * inv;
        unsigned short h = f2bf(y);
        int j = t + (i << 8);
        o[j] = h;
        o[N + j] = f2bf(y - bf2f(h));
    }
}

// ---------------------------------------------------------------------------
// LayerNorm rows of 512 fp32 -> split bf16 out. grid = rows, block = 256.
// ---------------------------------------------------------------------------
__global__ __launch_bounds__(256) void layernorm_split(
    const float* __restrict__ X, const float* __restrict__ g, const float* __restrict__ b,
    unsigned short* __restrict__ ohi, unsigned short* __restrict__ olo)
{
    const float* row = X + (size_t)blockIdx.x * 512;
    size_t ob = (size_t)blockIdx.x * 512;
    int t = threadIdx.x;
    float x0 = row[t], x1 = row[t + 256];
    float s = x0 + x1, sq = x0 * x0 + x1 * x1;
    for (int o = 32; o; o >>= 1) { s += __shfl_xor(s, o); sq += __shfl_xor(sq, o); }
    __shared__ float ls[8];
    int w = t >> 6;
    if ((t & 63) == 0) { ls[w] = s; ls[4 + w] = sq; }
    __syncthreads();
    s = ls[0] + ls[1] + ls[2] + ls[3];
    sq = ls[4] + ls[5] + ls[6] + ls[7];
    float mu = s * (1.0f / 512.0f);
    float var = sq * (1.0f / 512.0f) - mu * mu;
    float inv = rsqrtf(var + 1e-5f);
    float y0 = (x0 - mu) * inv * g[t]       + b[t];
    float y1 = (x1 - mu) * inv * g[t + 256] + b[t + 256];
    unsigned short h0 = f2bf(y0), h1 = f2bf(y1);
    ohi[ob + t]       = h0;  olo[ob + t]       = f2bf(y0 - bf2f(h0));
    ohi[ob + t + 256] = h1;  olo[ob + t + 256] = f2bf(y1 - bf2f(h1));
}

// ---------------------------------------------------------------------------
// out[b,h] = dot(q[b,h,:], projT[h,:]) with hi+lo reconstruction
// ---------------------------------------------------------------------------
__global__ __launch_bounds__(256) void outproj3(
    const unsigned short* __restrict__ qhi, const unsigned short* __restrict__ qlo,
    const unsigned short* __restrict__ phi, const unsigned short* __restrict__ plo,
    float* __restrict__ out)
{
    int gw = blockIdx.x * 4 + (threadIdx.x >> 6);
    int lane = threadIdx.x & 63;
    int h = gw & 1023;
    uint4 qh = ((const uint4*)(qhi + (size_t)gw * 512))[lane];
    uint4 ql = ((const uint4*)(qlo + (size_t)gw * 512))[lane];
    uint4 ph = ((const uint4*)(phi + (size_t)h * 512))[lane];
    uint4 pl = ((const uint4*)(plo + (size_t)h * 512))[lane];
    unsigned short qhe[8], qle[8], phe[8], ple[8];
    *(uint4*)qhe = qh; *(uint4*)qle = ql; *(uint4*)phe = ph; *(uint4*)ple = pl;
    float s = 0.0f;
    #pragma unroll
    for (int i = 0; i < 8; ++i) {
        float q = bf2f(qhe[i]) + bf2f(qle[i]);
        float p = bf2f(phe[i]) + bf2f(ple[i]);
        s += q * p;
    }
    for (int o = 32; o; o >>= 1) s += __shfl_xor(s, o);
    if (lane == 0) out[gw] = s;
}

// ---------------------------------------------------------------------------
// launcher
// ---------------------------------------------------------------------------
extern "C" void kernel_launch(void* const* d_in, const int* in_sizes, int n_in,
                              void* d_out, int out_size, void* d_ws, size_t ws_size,
                              hipStream_t stream)
{
    (void)in_sizes; (void)n_in; (void)out_size; (void)ws_size;

    const float* x     = (const float*)d_in[0];
    const float* le    = (const float*)d_in[1];
    const float* proj  = (const float*)d_in[2];
    const float* WihF  = (const float*)d_in[3];
    const float* WhhF  = (const float*)d_in[4];
    const float* bihF  = (const float*)d_in[5];
    const float* bhhF  = (const float*)d_in[6];
    const float* WihB  = (const float*)d_in[7];
    const float* WhhB  = (const float*)d_in[8];
    const float* bihB  = (const float*)d_in[9];
    const float* bhhB  = (const float*)d_in[10];
    const float* w1    = (const float*)d_in[11];
    const float* b1    = (const float*)d_in[12];
    const float* w2    = (const float*)d_in[13];
    const float* b2    = (const float*)d_in[14];
    const float* lng   = (const float*)d_in[15];
    const float* lnb   = (const float*)d_in[16];
    float* out = (float*)d_out;
    float* ws  = (float*)d_ws;
    unsigned short* wsu = (unsigned short*)d_ws;

    const size_t MEG = 1048576;
    const size_t R0    = 0;              // 8M: pre (4096x2048) -> qt-split (L1) -> lnsrc
    const size_t R1    = 8 * MEG;        // 8M: q2 split
    const size_t AR    = 16 * MEG;       // 17M arena
    const size_t QHI   = 33 * MEG;
    const size_t QLO   = 37 * MEG;
    const size_t FHI   = 41 * MEG;
    const size_t FLO   = 42 * MEG;
    const size_t FTHI  = 43 * MEG;
    const size_t FTLO  = 44 * MEG;
    const size_t LEHI  = 45 * MEG;
    const size_t LELO  = LEHI  + MEG / 4;
    const size_t LETHI = LELO  + MEG / 4;
    const size_t LETLO = LETHI + MEG / 4;
    const size_t WIHH  = 46 * MEG;
    const size_t WIHL  = WIHH + MEG / 2;
    const size_t SYNC  = 47 * MEG;       // flags[32] + hgu u32[16384]
    const size_t W1TH  = SYNC  + MEG / 4;
    const size_t W1TL  = W1TH  + MEG / 2;
    const size_t W2TH  = W1TL  + MEG / 2;
    const size_t W2TL  = W2TH  + MEG / 2;
    const size_t PTH   = W2TL  + MEG / 2;
    const size_t PTL   = PTH   + MEG / 4;
    const size_t BSUM  = PTL   + MEG / 4;

    float* pre    = ws + R0;             // (4096, 2048): [F 1024 | B 1024]
    float* lnsrc  = ws + R0;
    float* arena  = ws + AR;
    float* bsum   = ws + BSUM;
    int*   flags  = (int*)(ws + SYNC);              // 32 ints
    unsigned* hgu = (unsigned*)(ws + SYNC + 1024);  // 16384 u32 = 64KB
    unsigned short* qthi  = wsu + 2 * R0;
    unsigned short* qtlo  = wsu + 2 * (R0 + 4 * MEG);
    unsigned short* q2hi  = wsu + 2 * R1;
    unsigned short* q2lo  = wsu + 2 * (R1 + 4 * MEG);
    unsigned short* qhi   = wsu + 2 * QHI;
    unsigned short* qlo   = wsu + 2 * QLO;
    unsigned short* fhi   = wsu + 2 * FHI;
    unsigned short* flo   = wsu + 2 * FLO;
    unsigned short* fthi  = wsu + 2 * FTHI;
    unsigned short* ftlo  = wsu + 2 * FTLO;
    unsigned short* lehi  = wsu + 2 * LEHI;
    unsigned short* lelo  = wsu + 2 * LELO;
    unsigned short* lethi = wsu + 2 * LETHI;
    unsigned short* letlo = wsu + 2 * LETLO;
    unsigned short* wihh  = wsu + 2 * WIHH;
    unsigned short* wihl  = wsu + 2 * WIHL;
    unsigned short* w1th  = wsu + 2 * W1TH;
    unsigned short* w1tl  = wsu + 2 * W1TL;
    unsigned short* w2th  = wsu + 2 * W2TH;
    unsigned short* w2tl  = wsu + 2 * W2TL;
    unsigned short* pth   = wsu + 2 * PTH;
    unsigned short* ptl   = wsu + 2 * PTL;

    // ---- prep
    bias_sum_kernel<<<8, 256, 0, stream>>>(bihF, bhhF, bihB, bhhB, bsum);
    cvt_split<<<512, 256, 0, stream>>>(WihF, wihh, wihl);
    cvt_split<<<512, 256, 0, stream>>>(WihB, wihh + 524288, wihl + 524288);
    cvt_split<<<512, 256, 0, stream>>>(le, lehi, lelo);
    { dim3 g(512 / 64, 1024 / 64, 1);
      tcvt_bf16<<<g, 256, 0, stream>>>(lehi, lethi, 1024, 512);
      tcvt_bf16<<<g, 256, 0, stream>>>(lelo, letlo, 1024, 512); }
    hipMemsetAsync(flags, 0, 1024 * sizeof(float), stream);   // flags + hgu region head
    hipMemsetAsync(hgu, 0, 16384 * sizeof(unsigned), stream);

    // x -> split (arena scratch)
    unsigned short* xhi = wsu + 2 * AR;
    unsigned short* xlo = wsu + 2 * (AR + MEG);
    cvt_split<<<2048, 256, 0, stream>>>(x, xhi, xlo);

    // ---- LSTM input projection (merged F|B): pre = x @ [WihF;WihB]^T + bsum
    gemm_f(0, xhi, xlo, wihh, wihl, bsum, pre, NB * NS, 2048, ND, ND, ND, 0, 0, 0, 1, stream);

    // ---- recurrence -> features (split bf16), staggered dual-dir kernel
    lstm_rec9<<<16, 512, 0, stream>>>(pre, WhhF, WhhB, hgu, flags, fhi, flo);
    { dim3 g(512 / 64, 256 / 64, 16);
      tcvt_bf16<<<g, 256, 0, stream>>>(fhi, fthi, 256, 512);
      tcvt_bf16<<<g, 256, 0, stream>>>(flo, ftlo, 256, 512); }

    // ---- layers
    for (int l = 0; l < 2; ++l) {
        const float* b1l = b1 + (size_t)l * NF;
        const float* b2l = b2 + (size_t)l * ND;
        const float* gl  = lng + (size_t)l * ND;
        const float* bl  = lnb + (size_t)l * ND;

        // FFN weights -> split bf16, transposed (tmp in arena)
        unsigned short* wth = wsu + 2 * (AR + 2 * MEG);
        unsigned short* wtl = wsu + 2 * (AR + 2 * MEG + MEG / 2);
        cvt_split<<<1024, 256, 0, stream>>>(w1 + (size_t)l * ND * NF, wth, wtl);
        { dim3 g(NF / 64, ND / 64, 1);
          tcvt_bf16<<<g, 256, 0, stream>>>(wth, w1th, ND, NF);
          tcvt_bf16<<<g, 256, 0, stream>>>(wtl, w1tl, ND, NF); }
        cvt_split<<<1024, 256, 0, stream>>>(w2 + (size_t)l * NF * ND, wth, wtl);
        { dim3 g(ND / 64, NF / 64, 1);
          tcvt_bf16<<<g, 256, 0, stream>>>(wth, w2th, NF, ND);
          tcvt_bf16<<<g, 256, 0, stream>>>(wtl, w2tl, NF, ND); }

        if (l == 0) {
            float* wsc = arena;
            unsigned short* wscu = (unsigned short*)wsc;
            unsigned short* q1hi = wsu + 2 * (AR + 1 * MEG);
            unsigned short* q1lo = wsu + 2 * (AR + 1 * MEG + MEG / 4);
            float* s2s = arena + 4 * MEG;
            unsigned short* s2u = (unsigned short*)s2s;

            gemm_f(0, lehi, lelo, lehi, lelo, nullptr, wsc, NH, NH, ND, ND, ND, 0, 0, 0, 1, stream);
            softmax_ip<<<NH, 256, 0, stream>>>(wsc, NH);
            gemm_s(0, wscu, wscu + NH, lethi, letlo, nullptr, q1hi, q1lo,
                   NH, ND, NH, 2 * NH, NH, 0, 0, 0, 1, stream);
            gemm_f(0, q1hi, q1lo, fhi, flo, nullptr, s2s, NH, NS, ND, ND, ND,
                   0, (long)NS * ND, (long)NH * NS, 16, stream);
            softmax_ip<<<NB * NH, 256, 0, stream>>>(s2s, NS);
            gemm_s(0, s2u, s2u + NS, fthi, ftlo, nullptr, q2hi, q2lo,
                   NH, ND, NS, 2 * NS, NS,
                   (long)2 * NH * NS, (long)ND * NS, (long)NH * ND, 16, stream);
        } else {
            { dim3 g(512 / 64, 1024 / 64, 16);
              tcvt_bf16<<<g, 256, 0, stream>>>(qhi, qthi, 1024, 512);
              tcvt_bf16<<<g, 256, 0, stream>>>(qlo, qtlo, 1024, 512); }
            float* wsc = arena;
            unsigned short* wscu = (unsigned short*)wsc;
            unsigned short* q1hi = wsu + 2 * (AR + 8 * MEG);
            unsigned short* q1lo = wsu + 2 * (AR + 10 * MEG);
            float* s2s = arena + 12 * MEG;
            unsigned short* s2u = (unsigned short*)s2s;
            for (int g8 = 0; g8 < 2; ++g8) {
                size_t qo = (size_t)g8 * 8;
                gemm_f(0, qhi + qo * NH * ND, qlo + qo * NH * ND,
                       qhi + qo * NH * ND, qlo + qo * NH * ND, nullptr, wsc,
                       NH, NH, ND, ND, ND,
                       (long)NH * ND, (long)NH * ND, (long)NH * NH, 8, stream);
                softmax_ip<<<8 * NH, 256, 0, stream>>>(wsc, NH);
                gemm_s(0, wscu, wscu + NH, qthi + qo * ND * NH, qtlo + qo * ND * NH,
                       nullptr, q1hi, q1lo, NH, ND, NH, 2 * NH, NH,
                       (long)2 * NH * NH, (long)ND * NH, (long)NH * ND, 8, stream);
                gemm_f(0, q1hi, q1lo, fhi + qo * NS * ND, flo + qo * NS * ND,
                       nullptr, s2s, NH, NS, ND, ND, ND,
                       (long)NH * ND, (long)NS * ND, (long)NH * NS, 8, stream);
                softmax_ip<<<8 * NH, 256, 0, stream>>>(s2s, NS);
                gemm_s(0, s2u, s2u + NS, fthi + qo * ND * NS, ftlo + qo * ND * NS,
                       nullptr, q2hi + qo * NH * ND, q2lo + qo * NH * ND,
                       NH, ND, NS, 2 * NS, NS,
                       (long)2 * NH * NS, (long)ND * NS, (long)NH * ND, 8, stream);
            }
        }

        // FFN: 2 chunks of 8192 rows
        unsigned short* ffhi = wsu + 2 * AR;
        unsigned short* fflo = wsu + 2 * (AR + 8 * MEG);
        for (int ch = 0; ch < 2; ++ch) {
            const unsigned short* rih = q2hi + (size_t)ch * 8192 * ND;
            const unsigned short* ril = q2lo + (size_t)ch * 8192 * ND;
            float* rows_out = lnsrc + (size_t)ch * 8192 * ND;
            gemm_s(1, rih, ril, w1th, w1tl, b1l, ffhi, fflo,
                   8192, NF, ND, ND, ND, 0, 0, 0, 1, stream);
            gemm_f(0, ffhi, fflo, w2th, w2tl, b2l, rows_out,
                   8192, ND, NF, NF, NF, 0, 0, 0, 1, stream);
        }
        layernorm_split<<<NB * NH, 256, 0, stream>>>(lnsrc, gl, bl, qhi, qlo);
    }

    // ---- final projection
    {
        unsigned short* prh = wsu + 2 * AR;
        unsigned short* prl = wsu + 2 * (AR + MEG / 4);
        cvt_split<<<512, 256, 0, stream>>>(proj, prh, prl);
        dim3 g(1024 / 64, 512 / 64, 1);
        tcvt_bf16<<<g, 256, 0, stream>>>(prh, pth, 512, 1024);
        tcvt_bf16<<<g, 256, 0, stream>>>(prl, ptl, 512, 1024);
    }
    outproj3<<<4096, 256, 0, stream>>>(qhi, qlo, pth, ptl, out);
}

// Round 11
// 2032.376 us; speedup vs baseline: 1.6200x; 1.6200x over previous
//
#include <hip/hip_runtime.h>
#include <hip/hip_bf16.h>
#include <math.h>

// Problem dims
#define NB 16
#define NS 256
#define ND 512
#define NH 1024
#define NF 2048
#define NHID 256

typedef __attribute__((ext_vector_type(8))) short bf16x8;
typedef __attribute__((ext_vector_type(4))) float f32x4;

__device__ __forceinline__ unsigned short f2bf(float f) {
    unsigned u = __float_as_uint(f);
    unsigned r = u + 0x7fffu + ((u >> 16) & 1u);
    return (unsigned short)(r >> 16);
}
__device__ __forceinline__ float bf2f(unsigned short h) {
    return __uint_as_float(((unsigned)h) << 16);
}
__device__ __forceinline__ float sigmoid_fast(float x) {
    return 1.0f / (1.0f + __expf(-x));
}
__device__ __forceinline__ float tanh_fast(float x) {
    return 1.0f - 2.0f / (__expf(2.0f * x) + 1.0f);
}

// ---------------------------------------------------------------------------
// Split-bf16 MFMA GEMM v3: C[M,N] = A[M,K] @ B[N,K]^T (+bias)(+gelu)
// Pre-split hi/lo bf16 operands, 3-pass (Ah*Bh + Al*Bh + Ah*Bl ~ fp32).
// lda/ldb: row strides in u16 elems. global_load_lds width-16 staging,
// linear LDS (m97 structure). Tile 128x128, BK=32, 256 thr. Z-batched.
// ---------------------------------------------------------------------------
template<int ACT, int OUT_SPLIT>
__global__ __launch_bounds__(256) void sgemm3(
    const unsigned short* __restrict__ Ahi, const unsigned short* __restrict__ Alo,
    const unsigned short* __restrict__ Bhi, const unsigned short* __restrict__ Blo,
    const float* __restrict__ bias,
    float* __restrict__ C, unsigned short* __restrict__ Chi, unsigned short* __restrict__ Clo,
    int M, int N, int K, int lda, int ldb, long sA, long sB, long sC)
{
    __shared__ unsigned short Ah[128 * 32];
    __shared__ unsigned short Al[128 * 32];
    __shared__ unsigned short Bh[128 * 32];
    __shared__ unsigned short Bl[128 * 32];

    const int t = threadIdx.x;
    const int z = blockIdx.z;
    const int m0 = blockIdx.y * 128, n0 = blockIdx.x * 128;
    const int wid = t >> 6, lane = t & 63;
    const int wr = (wid >> 1) * 64, wc = (wid & 1) * 64;
    const int lr = lane & 15, lk = lane >> 4;
    const int rl = lane >> 2, sl = lane & 3;

    const unsigned short* pAh = Ahi + (size_t)z * sA;
    const unsigned short* pAl = Alo + (size_t)z * sA;
    const unsigned short* pBh = Bhi + (size_t)z * sB;
    const unsigned short* pBl = Blo + (size_t)z * sB;

    f32x4 acc[4][4];
    #pragma unroll
    for (int i = 0; i < 4; ++i)
        #pragma unroll
        for (int j = 0; j < 4; ++j) acc[i][j] = (f32x4){0.f, 0.f, 0.f, 0.f};

    for (int k0 = 0; k0 < K; k0 += 32) {
        #pragma unroll
        for (int e = 0; e < 2; ++e) {
            const int r = e * 64 + wid * 16 + rl;
            const size_t goA = (size_t)(m0 + r) * lda + k0 + sl * 8;
            const size_t goB = (size_t)(n0 + r) * ldb + k0 + sl * 8;
            const int lo = (e * 64 + wid * 16) * 32;
            __builtin_amdgcn_global_load_lds((const void*)(pAh + goA), (void*)&Ah[lo], 16, 0, 0);
            __builtin_amdgcn_global_load_lds((const void*)(pAl + goA), (void*)&Al[lo], 16, 0, 0);
            __builtin_amdgcn_global_load_lds((const void*)(pBh + goB), (void*)&Bh[lo], 16, 0, 0);
            __builtin_amdgcn_global_load_lds((const void*)(pBl + goB), (void*)&Bl[lo], 16, 0, 0);
        }
        __syncthreads();

        bf16x8 ah[4], al[4], bh[4], bl[4];
        #pragma unroll
        for (int mt = 0; mt < 4; ++mt) {
            int rf = wr + mt * 16 + lr;
            ah[mt] = *(const bf16x8*)&Ah[rf * 32 + lk * 8];
            al[mt] = *(const bf16x8*)&Al[rf * 32 + lk * 8];
        }
        #pragma unroll
        for (int nt = 0; nt < 4; ++nt) {
            int rf = wc + nt * 16 + lr;
            bh[nt] = *(const bf16x8*)&Bh[rf * 32 + lk * 8];
            bl[nt] = *(const bf16x8*)&Bl[rf * 32 + lk * 8];
        }
        #pragma unroll
        for (int mt = 0; mt < 4; ++mt)
            #pragma unroll
            for (int nt = 0; nt < 4; ++nt) {
                acc[mt][nt] = __builtin_amdgcn_mfma_f32_16x16x32_bf16(ah[mt], bh[nt], acc[mt][nt], 0, 0, 0);
                acc[mt][nt] = __builtin_amdgcn_mfma_f32_16x16x32_bf16(al[mt], bh[nt], acc[mt][nt], 0, 0, 0);
                acc[mt][nt] = __builtin_amdgcn_mfma_f32_16x16x32_bf16(ah[mt], bl[nt], acc[mt][nt], 0, 0, 0);
            }
        __syncthreads();
    }

    #pragma unroll
    for (int nt = 0; nt < 4; ++nt) {
        int col = n0 + wc + nt * 16 + lr;
        float bv = bias ? bias[col] : 0.0f;
        #pragma unroll
        for (int mt = 0; mt < 4; ++mt) {
            #pragma unroll
            for (int i = 0; i < 4; ++i) {
                int row = m0 + wr + mt * 16 + lk * 4 + i;
                float x = acc[mt][nt][i] + bv;
                if (ACT == 1) x = 0.5f * x * (1.0f + erff(x * 0.70710678118654752f));
                size_t oi = (size_t)z * sC + (size_t)row * N + col;
                if (OUT_SPLIT) {
                    unsigned short h = f2bf(x);
                    Chi[oi] = h;
                    Clo[oi] = f2bf(x - bf2f(h));
                } else {
                    C[oi] = x;
                }
            }
        }
    }
}

static void gemm_f(int act, const unsigned short* Ahi, const unsigned short* Alo,
                   const unsigned short* Bhi, const unsigned short* Blo,
                   const float* bias, float* C, int M, int N, int K, int lda, int ldb,
                   long sA, long sB, long sC, int Z, hipStream_t st)
{
    dim3 g(N / 128, M / 128, Z), b(256);
    if (act) sgemm3<1, 0><<<g, b, 0, st>>>(Ahi, Alo, Bhi, Blo, bias, C, nullptr, nullptr, M, N, K, lda, ldb, sA, sB, sC);
    else     sgemm3<0, 0><<<g, b, 0, st>>>(Ahi, Alo, Bhi, Blo, bias, C, nullptr, nullptr, M, N, K, lda, ldb, sA, sB, sC);
}
static void gemm_s(int act, const unsigned short* Ahi, const unsigned short* Alo,
                   const unsigned short* Bhi, const unsigned short* Blo,
                   const float* bias, unsigned short* Chi, unsigned short* Clo,
                   int M, int N, int K, int lda, int ldb,
                   long sA, long sB, long sC, int Z, hipStream_t st)
{
    dim3 g(N / 128, M / 128, Z), b(256);
    if (act) sgemm3<1, 1><<<g, b, 0, st>>>(Ahi, Alo, Bhi, Blo, bias, nullptr, Chi, Clo, M, N, K, lda, ldb, sA, sB, sC);
    else     sgemm3<0, 1><<<g, b, 0, st>>>(Ahi, Alo, Bhi, Blo, bias, nullptr, Chi, Clo, M, N, K, lda, ldb, sA, sB, sC);
}

// ---------------------------------------------------------------------------
// fp32 -> split bf16 hi/lo (n multiple of 1024)
// ---------------------------------------------------------------------------
__global__ __launch_bounds__(256) void cvt_split(const float* __restrict__ in,
                                                 unsigned short* __restrict__ hi,
                                                 unsigned short* __restrict__ lo)
{
    size_t i = ((size_t)blockIdx.x * 256 + threadIdx.x) * 4;
    float4 v = *(const float4*)(in + i);
    ushort4 h, l;
    h.x = f2bf(v.x); l.x = f2bf(v.x - bf2f(h.x));
    h.y = f2bf(v.y); l.y = f2bf(v.y - bf2f(h.y));
    h.z = f2bf(v.z); l.z = f2bf(v.z - bf2f(h.z));
    h.w = f2bf(v.w); l.w = f2bf(v.w - bf2f(h.w));
    *(ushort4*)(hi + i) = h;
    *(ushort4*)(lo + i) = l;
}

// ---------------------------------------------------------------------------
// Fused: fp32 (R,C) -> split bf16 hi/lo TRANSPOSED (C,R). R,C multiples of 64.
// ---------------------------------------------------------------------------
__global__ __launch_bounds__(256) void cvt_split_t(const float* __restrict__ in,
                                                   unsigned short* __restrict__ hiT,
                                                   unsigned short* __restrict__ loT,
                                                   int R, int C)
{
    __shared__ unsigned short tileH[64 * 72];
    __shared__ unsigned short tileL[64 * 72];
    int r0 = blockIdx.y * 64, c0 = blockIdx.x * 64;
    int t = threadIdx.x;
    int tr = t >> 2, tc = (t & 3) * 16;

    float v[16];
    const float* src = in + (size_t)(r0 + tr) * C + c0 + tc;
    *(float4*)(v)      = *(const float4*)(src);
    *(float4*)(v + 4)  = *(const float4*)(src + 4);
    *(float4*)(v + 8)  = *(const float4*)(src + 8);
    *(float4*)(v + 12) = *(const float4*)(src + 12);
    #pragma unroll
    for (int i = 0; i < 16; ++i) {
        unsigned short h = f2bf(v[i]);
        tileH[(tc + i) * 72 + tr] = h;
        tileL[(tc + i) * 72 + tr] = f2bf(v[i] - bf2f(h));
    }
    __syncthreads();

    size_t ob = (size_t)(c0 + tr) * R + r0 + tc;
    *(uint4*)(hiT + ob)     = *(const uint4*)(&tileH[tr * 72 + tc]);
    *(uint4*)(hiT + ob + 8) = *(const uint4*)(&tileH[tr * 72 + tc + 8]);
    *(uint4*)(loT + ob)     = *(const uint4*)(&tileL[tr * 72 + tc]);
    *(uint4*)(loT + ob + 8) = *(const uint4*)(&tileL[tr * 72 + tc + 8]);
}

// ---------------------------------------------------------------------------
// bf16 (R,C) -> (C,R) transpose, z-batched. R,C multiples of 64.
// ---------------------------------------------------------------------------
__global__ __launch_bounds__(256) void tcvt_bf16(const unsigned short* __restrict__ in,
                                                 unsigned short* __restrict__ out,
                                                 int R, int C)
{
    __shared__ unsigned short tile[64 * 72];
    int z = blockIdx.z;
    in += (size_t)z * R * C;
    out += (size_t)z * R * C;
    int r0 = blockIdx.y * 64, c0 = blockIdx.x * 64;
    int t = threadIdx.x;
    int tr = t >> 2, tc = (t & 3) * 16;

    uint4 q0 = *(const uint4*)(in + (size_t)(r0 + tr) * C + c0 + tc);
    uint4 q1 = *(const uint4*)(in + (size_t)(r0 + tr) * C + c0 + tc + 8);
    unsigned short e[16];
    *(uint4*)(e) = q0;
    *(uint4*)(e + 8) = q1;
    #pragma unroll
    for (int i = 0; i < 16; ++i) tile[(tc + i) * 72 + tr] = e[i];
    __syncthreads();

    uint4 o0 = *(const uint4*)(&tile[tr * 72 + tc]);
    uint4 o1 = *(const uint4*)(&tile[tr * 72 + tc + 8]);
    *(uint4*)(out + (size_t)(c0 + tr) * R + r0 + tc) = o0;
    *(uint4*)(out + (size_t)(c0 + tr) * R + r0 + tc + 8) = o1;
}

// ---------------------------------------------------------------------------
// bias combine
// ---------------------------------------------------------------------------
__global__ __launch_bounds__(256) void bias_sum_kernel(
    const float* bihF, const float* bhhF, const float* bihB, const float* bhhB,
    float* out)
{
    int i = blockIdx.x * 256 + threadIdx.x;
    if (i < 1024) out[i] = bihF[i] + bhhF[i];
    else out[i] = bihB[i - 1024] + bhhB[i - 1024];
}

// ---------------------------------------------------------------------------
// LSTM recurrence v6m: EXACT rec6 topology (best measured: 875us) with
// merged-pre addressing + fast exp elementwise.
// grid = 32 (dir=bid>>4, slice=bid&15), block = 256 (4 waves, wave = gate).
// Weight B-fragments (split hi/lo) register-resident. h exchanged via
// parity-double-buffered MALL buffer (u64 pairs, relaxed AGENT atomics);
// release = vmcnt(0) + barrier + relaxed flag store; 16-thread flag poll.
// ---------------------------------------------------------------------------
__global__ __launch_bounds__(256) void lstm_rec6m(
    const float* __restrict__ pre,     // (4096, 2048): [F 1024 | B 1024]
    const float* __restrict__ WhhF, const float* __restrict__ WhhB,
    unsigned long long* __restrict__ hg,   // [2 parity][2 dir][16 b][128] u64
    int* __restrict__ flags,               // [32], zeroed before launch
    unsigned short* __restrict__ fhi, unsigned short* __restrict__ flo)
{
    const int bid = blockIdx.x;
    const int dir = bid >> 4, slice = bid & 15;
    const float* Whh = dir ? WhhB : WhhF;

    const int tid = threadIdx.x;
    const int wv = tid >> 6;
    const int lane = tid & 63;
    const int lr = lane & 15;
    const int lk = lane >> 4;
    const int eb = tid >> 4;
    const int eu = tid & 15;

    __shared__ unsigned short hh[16 * 264];
    __shared__ unsigned short hl[16 * 264];
    __shared__ float gx[4][16][17];

    bf16x8 wfh[8], wfl[8];
    {
        const float* wrow = Whh + (size_t)(wv * 256 + slice * 16 + lr) * 256 + lk * 8;
        #pragma unroll
        for (int kt = 0; kt < 8; ++kt) {
            float4 a = *(const float4*)(wrow + kt * 32);
            float4 b = *(const float4*)(wrow + kt * 32 + 4);
            float v[8] = {a.x, a.y, a.z, a.w, b.x, b.y, b.z, b.w};
            unsigned short hhv[8], llv[8];
            #pragma unroll
            for (int i = 0; i < 8; ++i) {
                unsigned short h = f2bf(v[i]);
                hhv[i] = h;
                llv[i] = f2bf(v[i] - bf2f(h));
            }
            wfh[kt] = *(bf16x8*)hhv;
            wfl[kt] = *(bf16x8*)llv;
        }
    }
    for (int i = tid; i < 16 * 264; i += 256) { hh[i] = 0; hl[i] = 0; }

    float c = 0.0f;
    __syncthreads();

    for (int si = 0; si < NS; ++si) {
        const int s = dir ? (NS - 1 - si) : si;
        const float* pp = pre + ((size_t)(eb * NS + s)) * 2048 + dir * 1024 + slice * 16 + eu;
        float pi = pp[0], pf = pp[256], pg = pp[512], po = pp[768];

        if (si > 0) {
            if (tid < 16) {
                while (__hip_atomic_load(&flags[dir * 16 + tid], __ATOMIC_RELAXED,
                                         __HIP_MEMORY_SCOPE_AGENT) < si) {
                    __builtin_amdgcn_s_sleep(1);
                }
            }
            __syncthreads();
            const unsigned long long* src =
                hg + (size_t)(((si - 1) & 1) * 2 + dir) * 2048;
            const int b2 = tid >> 4, pb = (tid & 15) * 8;
            unsigned short hbuf[16], lbuf[16];
            #pragma unroll
            for (int j = 0; j < 8; ++j) {
                unsigned long long v = __hip_atomic_load(
                    &src[b2 * 128 + pb + j], __ATOMIC_RELAXED,
                    __HIP_MEMORY_SCOPE_AGENT);
                hbuf[2 * j]     = (unsigned short)(v & 0xffff);
                lbuf[2 * j]     = (unsigned short)((v >> 16) & 0xffff);
                hbuf[2 * j + 1] = (unsigned short)((v >> 32) & 0xffff);
                lbuf[2 * j + 1] = (unsigned short)(v >> 48);
            }
            char* dh = (char*)hh + b2 * 528 + (tid & 15) * 32;
            char* dl = (char*)hl + b2 * 528 + (tid & 15) * 32;
            *(uint4*)dh        = *(uint4*)(hbuf);
            *(uint4*)(dh + 16) = *(uint4*)(hbuf + 8);
            *(uint4*)dl        = *(uint4*)(lbuf);
            *(uint4*)(dl + 16) = *(uint4*)(lbuf + 8);
            __syncthreads();
        }

        f32x4 acc = (f32x4){0.f, 0.f, 0.f, 0.f};
        #pragma unroll
        for (int kt = 0; kt < 8; ++kt) {
            const char* hp = (const char*)hh + lr * 528 + kt * 64 + lk * 16;
            const char* lp = (const char*)hl + lr * 528 + kt * 64 + lk * 16;
            bf16x8 ah = *(const bf16x8*)hp;
            bf16x8 al = *(const bf16x8*)lp;
            acc = __builtin_amdgcn_mfma_f32_16x16x32_bf16(ah, wfh[kt], acc, 0, 0, 0);
            acc = __builtin_amdgcn_mfma_f32_16x16x32_bf16(al, wfh[kt], acc, 0, 0, 0);
            acc = __builtin_amdgcn_mfma_f32_16x16x32_bf16(ah, wfl[kt], acc, 0, 0, 0);
        }
        #pragma unroll
        for (int i = 0; i < 4; ++i) gx[wv][lk * 4 + i][lr] = acc[i];
        __syncthreads();

        float ai = gx[0][eb][eu] + pi;
        float af = gx[1][eb][eu] + pf;
        float ag = gx[2][eb][eu] + pg;
        float ao = gx[3][eb][eu] + po;
        float gi = sigmoid_fast(ai);
        float gf = sigmoid_fast(af);
        float gg = tanh_fast(ag);
        float go = sigmoid_fast(ao);
        c = gf * c + gi * gg;
        float h = go * tanh_fast(c);

        unsigned short h16 = f2bf(h);
        unsigned short l16 = f2bf(h - bf2f(h16));
        unsigned my = (unsigned)h16 | ((unsigned)l16 << 16);
        unsigned oth = __shfl_xor(my, 1);
        if ((eu & 1) == 0) {
            unsigned long long v = (unsigned long long)my |
                                   ((unsigned long long)oth << 32);
            unsigned long long* dst =
                hg + (size_t)((si & 1) * 2 + dir) * 2048;
            __hip_atomic_store(&dst[eb * 128 + slice * 8 + (eu >> 1)], v,
                               __ATOMIC_RELAXED, __HIP_MEMORY_SCOPE_AGENT);
        }
        size_t oi = ((size_t)(eb * NS + s)) * 512 + dir * 256 + slice * 16 + eu;
        fhi[oi] = h16;
        flo[oi] = l16;

        asm volatile("s_waitcnt vmcnt(0)" ::: "memory");
        __syncthreads();
        if (tid == 0)
            __hip_atomic_store(&flags[bid], si + 1, __ATOMIC_RELAXED,
                               __HIP_MEMORY_SCOPE_AGENT);
    }
}

// ---------------------------------------------------------------------------
// In-place split softmax: row of N fp32 -> same memory becomes
// [N hi bf16][N lo bf16]. grid = rows, block = 256, N in {256, 1024}.
// ---------------------------------------------------------------------------
__global__ __launch_bounds__(256) void softmax_ip(float* __restrict__ X, int N)
{
    float* row = X + (size_t)blockIdx.x * N;
    unsigned short* o = (unsigned short*)row;
    int t = threadIdx.x;
    int cnt = N >> 8;
    float v[4];
    float m = -1e30f;
    for (int i = 0; i < cnt; ++i) { v[i] = row[t + (i << 8)]; m = fmaxf(m, v[i]); }
    for (int sh = 32; sh; sh >>= 1) m = fmaxf(m, __shfl_xor(m, sh));
    __shared__ float lm[4];
    if ((t & 63) == 0) lm[t >> 6] = m;
    __syncthreads();
    m = fmaxf(fmaxf(lm[0], lm[1]), fmaxf(lm[2], lm[3]));
    float s = 0.0f;
    for (int i = 0; i < cnt; ++i) { v[i] = expf(v[i] - m); s += v[i]; }
    for (int sh = 32; sh; sh >>= 1) s += __shfl_xor(s, sh);
    __shared__ float ls[4];
    if ((t & 63) == 0) ls[t >> 6] = s;
    __syncthreads();
    s = ls[0] + ls[1] + ls[2] + ls[3];
    float inv = 1.0f / s;
    __syncthreads();
    for (int i = 0; i < cnt; ++i) {
        float y = v[i] * inv;
        unsigned short h = f2bf(y);
        int j = t + (i << 8);
        o[j] = h;
        o[N + j] = f2bf(y - bf2f(h));
    }
}

// ---------------------------------------------------------------------------
// LayerNorm rows of 512 fp32 -> split bf16 out. grid = rows, block = 256.
// ---------------------------------------------------------------------------
__global__ __launch_bounds__(256) void layernorm_split(
    const float* __restrict__ X, const float* __restrict__ g, const float* __restrict__ b,
    unsigned short* __restrict__ ohi, unsigned short* __restrict__ olo)
{
    const float* row = X + (size_t)blockIdx.x * 512;
    size_t ob = (size_t)blockIdx.x * 512;
    int t = threadIdx.x;
    float x0 = row[t], x1 = row[t + 256];
    float s = x0 + x1, sq = x0 * x0 + x1 * x1;
    for (int o = 32; o; o >>= 1) { s += __shfl_xor(s, o); sq += __shfl_xor(sq, o); }
    __shared__ float ls[8];
    int w = t >> 6;
    if ((t & 63) == 0) { ls[w] = s; ls[4 + w] = sq; }
    __syncthreads();
    s = ls[0] + ls[1] + ls[2] + ls[3];
    sq = ls[4] + ls[5] + ls[6] + ls[7];
    float mu = s * (1.0f / 512.0f);
    float var = sq * (1.0f / 512.0f) - mu * mu;
    float inv = rsqrtf(var + 1e-5f);
    float y0 = (x0 - mu) * inv * g[t]       + b[t];
    float y1 = (x1 - mu) * inv * g[t + 256] + b[t + 256];
    unsigned short h0 = f2bf(y0), h1 = f2bf(y1);
    ohi[ob + t]       = h0;  olo[ob + t]       = f2bf(y0 - bf2f(h0));
    ohi[ob + t + 256] = h1;  olo[ob + t + 256] = f2bf(y1 - bf2f(h1));
}

// ---------------------------------------------------------------------------
// out[b,h] = dot(q[b,h,:], projT[h,:]) with hi+lo reconstruction
// ---------------------------------------------------------------------------
__global__ __launch_bounds__(256) void outproj3(
    const unsigned short* __restrict__ qhi, const unsigned short* __restrict__ qlo,
    const unsigned short* __restrict__ phi, const unsigned short* __restrict__ plo,
    float* __restrict__ out)
{
    int gw = blockIdx.x * 4 + (threadIdx.x >> 6);
    int lane = threadIdx.x & 63;
    int h = gw & 1023;
    uint4 qh = ((const uint4*)(qhi + (size_t)gw * 512))[lane];
    uint4 ql = ((const uint4*)(qlo + (size_t)gw * 512))[lane];
    uint4 ph = ((const uint4*)(phi + (size_t)h * 512))[lane];
    uint4 pl = ((const uint4*)(plo + (size_t)h * 512))[lane];
    unsigned short qhe[8], qle[8], phe[8], ple[8];
    *(uint4*)qhe = qh; *(uint4*)qle = ql; *(uint4*)phe = ph; *(uint4*)ple = pl;
    float s = 0.0f;
    #pragma unroll
    for (int i = 0; i < 8; ++i) {
        float q = bf2f(qhe[i]) + bf2f(qle[i]);
        float p = bf2f(phe[i]) + bf2f(ple[i]);
        s += q * p;
    }
    for (int o = 32; o; o >>= 1) s += __shfl_xor(s, o);
    if (lane == 0) out[gw] = s;
}

// ---------------------------------------------------------------------------
// launcher
// ---------------------------------------------------------------------------
extern "C" void kernel_launch(void* const* d_in, const int* in_sizes, int n_in,
                              void* d_out, int out_size, void* d_ws, size_t ws_size,
                              hipStream_t stream)
{
    (void)in_sizes; (void)n_in; (void)out_size; (void)ws_size;

    const float* x     = (const float*)d_in[0];
    const float* le    = (const float*)d_in[1];
    const float* proj  = (const float*)d_in[2];
    const float* WihF  = (const float*)d_in[3];
    const float* WhhF  = (const float*)d_in[4];
    const float* bihF  = (const float*)d_in[5];
    const float* bhhF  = (const float*)d_in[6];
    const float* WihB  = (const float*)d_in[7];
    const float* WhhB  = (const float*)d_in[8];
    const float* bihB  = (const float*)d_in[9];
    const float* bhhB  = (const float*)d_in[10];
    const float* w1    = (const float*)d_in[11];
    const float* b1    = (const float*)d_in[12];
    const float* w2    = (const float*)d_in[13];
    const float* b2    = (const float*)d_in[14];
    const float* lng   = (const float*)d_in[15];
    const float* lnb   = (const float*)d_in[16];
    float* out = (float*)d_out;
    float* ws  = (float*)d_ws;
    unsigned short* wsu = (unsigned short*)d_ws;

    const size_t MEG = 1048576;
    const size_t R0    = 0;              // 8M: pre (4096x2048) -> qt-split (L1) -> lnsrc
    const size_t R1    = 8 * MEG;        // 8M: q2 split
    const size_t AR    = 16 * MEG;       // 17M arena
    const size_t QHI   = 33 * MEG;
    const size_t QLO   = 37 * MEG;
    const size_t FHI   = 41 * MEG;
    const size_t FLO   = 42 * MEG;
    const size_t FTHI  = 43 * MEG;
    const size_t FTLO  = 44 * MEG;
    const size_t LEHI  = 45 * MEG;
    const size_t LELO  = LEHI  + MEG / 4;
    const size_t LETHI = LELO  + MEG / 4;
    const size_t LETLO = LETHI + MEG / 4;
    const size_t WIHH  = 46 * MEG;
    const size_t WIHL  = WIHH + MEG / 2;
    const size_t SYNC  = 47 * MEG;       // flags[32] + hg u64[8192]
    const size_t W1TH  = SYNC  + MEG / 4;
    const size_t W1TL  = W1TH  + MEG / 2;
    const size_t W2TH  = W1TL  + MEG / 2;
    const size_t W2TL  = W2TH  + MEG / 2;
    const size_t PTH   = W2TL  + MEG / 2;
    const size_t PTL   = PTH   + MEG / 4;
    const size_t BSUM  = PTL   + MEG / 4;

    float* pre    = ws + R0;             // (4096, 2048): [F 1024 | B 1024]
    float* lnsrc  = ws + R0;
    float* arena  = ws + AR;
    float* bsum   = ws + BSUM;
    int*   flags  = (int*)(ws + SYNC);
    unsigned long long* hg = (unsigned long long*)(ws + SYNC + 1024);   // 8192 u64
    unsigned short* qthi  = wsu + 2 * R0;
    unsigned short* qtlo  = wsu + 2 * (R0 + 4 * MEG);
    unsigned short* q2hi  = wsu + 2 * R1;
    unsigned short* q2lo  = wsu + 2 * (R1 + 4 * MEG);
    unsigned short* qhi   = wsu + 2 * QHI;
    unsigned short* qlo   = wsu + 2 * QLO;
    unsigned short* fhi   = wsu + 2 * FHI;
    unsigned short* flo   = wsu + 2 * FLO;
    unsigned short* fthi  = wsu + 2 * FTHI;
    unsigned short* ftlo  = wsu + 2 * FTLO;
    unsigned short* lehi  = wsu + 2 * LEHI;
    unsigned short* lelo  = wsu + 2 * LELO;
    unsigned short* lethi = wsu + 2 * LETHI;
    unsigned short* letlo = wsu + 2 * LETLO;
    unsigned short* wihh  = wsu + 2 * WIHH;
    unsigned short* wihl  = wsu + 2 * WIHL;
    unsigned short* w1th  = wsu + 2 * W1TH;
    unsigned short* w1tl  = wsu + 2 * W1TL;
    unsigned short* w2th  = wsu + 2 * W2TH;
    unsigned short* w2tl  = wsu + 2 * W2TL;
    unsigned short* pth   = wsu + 2 * PTH;
    unsigned short* ptl   = wsu + 2 * PTL;

    // ---- prep
    bias_sum_kernel<<<8, 256, 0, stream>>>(bihF, bhhF, bihB, bhhB, bsum);
    cvt_split<<<512, 256, 0, stream>>>(WihF, wihh, wihl);
    cvt_split<<<512, 256, 0, stream>>>(WihB, wihh + 524288, wihl + 524288);
    cvt_split<<<512, 256, 0, stream>>>(le, lehi, lelo);
    { dim3 g(512 / 64, 1024 / 64, 1);
      cvt_split_t<<<g, 256, 0, stream>>>(le, lethi, letlo, 1024, 512); }
    hipMemsetAsync(flags, 0, 32 * sizeof(int), stream);

    // x -> split (arena scratch)
    unsigned short* xhi = wsu + 2 * AR;
    unsigned short* xlo = wsu + 2 * (AR + MEG);
    cvt_split<<<2048, 256, 0, stream>>>(x, xhi, xlo);

    // ---- LSTM input projection (merged F|B): pre = x @ [WihF;WihB]^T + bsum
    gemm_f(0, xhi, xlo, wihh, wihl, bsum, pre, NB * NS, 2048, ND, ND, ND, 0, 0, 0, 1, stream);

    // ---- recurrence -> features (split bf16), rec6 topology
    lstm_rec6m<<<32, 256, 0, stream>>>(pre, WhhF, WhhB, hg, flags, fhi, flo);
    { dim3 g(512 / 64, 256 / 64, 16);
      tcvt_bf16<<<g, 256, 0, stream>>>(fhi, fthi, 256, 512);
      tcvt_bf16<<<g, 256, 0, stream>>>(flo, ftlo, 256, 512); }

    // ---- layers
    for (int l = 0; l < 2; ++l) {
        const float* b1l = b1 + (size_t)l * NF;
        const float* b2l = b2 + (size_t)l * ND;
        const float* gl  = lng + (size_t)l * ND;
        const float* bl  = lnb + (size_t)l * ND;

        // FFN weights -> split bf16, transposed (fused one-pass)
        { dim3 g(NF / 64, ND / 64, 1);
          cvt_split_t<<<g, 256, 0, stream>>>(w1 + (size_t)l * ND * NF, w1th, w1tl, ND, NF); }  // (2048,512)
        { dim3 g(ND / 64, NF / 64, 1);
          cvt_split_t<<<g, 256, 0, stream>>>(w2 + (size_t)l * NF * ND, w2th, w2tl, NF, ND); }  // (512,2048)

        if (l == 0) {
            float* wsc = arena;
            unsigned short* wscu = (unsigned short*)wsc;
            unsigned short* q1hi = wsu + 2 * (AR + 1 * MEG);
            unsigned short* q1lo = wsu + 2 * (AR + 1 * MEG + MEG / 4);
            float* s2s = arena + 4 * MEG;
            unsigned short* s2u = (unsigned short*)s2s;

            gemm_f(0, lehi, lelo, lehi, lelo, nullptr, wsc, NH, NH, ND, ND, ND, 0, 0, 0, 1, stream);
            softmax_ip<<<NH, 256, 0, stream>>>(wsc, NH);
            gemm_s(0, wscu, wscu + NH, lethi, letlo, nullptr, q1hi, q1lo,
                   NH, ND, NH, 2 * NH, NH, 0, 0, 0, 1, stream);
            gemm_f(0, q1hi, q1lo, fhi, flo, nullptr, s2s, NH, NS, ND, ND, ND,
                   0, (long)NS * ND, (long)NH * NS, 16, stream);
            softmax_ip<<<NB * NH, 256, 0, stream>>>(s2s, NS);
            gemm_s(0, s2u, s2u + NS, fthi, ftlo, nullptr, q2hi, q2lo,
                   NH, ND, NS, 2 * NS, NS,
                   (long)2 * NH * NS, (long)ND * NS, (long)NH * ND, 16, stream);
        } else {
            { dim3 g(512 / 64, 1024 / 64, 16);
              tcvt_bf16<<<g, 256, 0, stream>>>(qhi, qthi, 1024, 512);
              tcvt_bf16<<<g, 256, 0, stream>>>(qlo, qtlo, 1024, 512); }
            float* wsc = arena;
            unsigned short* wscu = (unsigned short*)wsc;
            unsigned short* q1hi = wsu + 2 * (AR + 8 * MEG);
            unsigned short* q1lo = wsu + 2 * (AR + 10 * MEG);
            float* s2s = arena + 12 * MEG;
            unsigned short* s2u = (unsigned short*)s2s;
            for (int g8 = 0; g8 < 2; ++g8) {
                size_t qo = (size_t)g8 * 8;
                gemm_f(0, qhi + qo * NH * ND, qlo + qo * NH * ND,
                       qhi + qo * NH * ND, qlo + qo * NH * ND, nullptr, wsc,
                       NH, NH, ND, ND, ND,
                       (long)NH * ND, (long)NH * ND, (long)NH * NH, 8, stream);
                softmax_ip<<<8 * NH, 256, 0, stream>>>(wsc, NH);
                gemm_s(0, wscu, wscu + NH, qthi + qo * ND * NH, qtlo + qo * ND * NH,
                       nullptr, q1hi, q1lo, NH, ND, NH, 2 * NH, NH,
                       (long)2 * NH * NH, (long)ND * NH, (long)NH * ND, 8, stream);
                gemm_f(0, q1hi, q1lo, fhi + qo * NS * ND, flo + qo * NS * ND,
                       nullptr, s2s, NH, NS, ND, ND, ND,
                       (long)NH * ND, (long)NS * ND, (long)NH * NS, 8, stream);
                softmax_ip<<<8 * NH, 256, 0, stream>>>(s2s, NS);
                gemm_s(0, s2u, s2u + NS, fthi + qo * ND * NS, ftlo + qo * ND * NS,
                       nullptr, q2hi + qo * NH * ND, q2lo + qo * NH * ND,
                       NH, ND, NS, 2 * NS, NS,
                       (long)2 * NH * NS, (long)ND * NS, (long)NH * ND, 8, stream);
            }
        }

        // FFN: 2 chunks of 8192 rows
        unsigned short* ffhi = wsu + 2 * AR;
        unsigned short* fflo = wsu + 2 * (AR + 8 * MEG);
        for (int ch = 0; ch < 2; ++ch) {
            const unsigned short* rih = q2hi + (size_t)ch * 8192 * ND;
            const unsigned short* ril = q2lo + (size_t)ch * 8192 * ND;
            float* rows_out = lnsrc + (size_t)ch * 8192 * ND;
            gemm_s(1, rih, ril, w1th, w1tl, b1l, ffhi, fflo,
                   8192, NF, ND, ND, ND, 0, 0, 0, 1, stream);
            gemm_f(0, ffhi, fflo, w2th, w2tl, b2l, rows_out,
                   8192, ND, NF, NF, NF, 0, 0, 0, 1, stream);
        }
        layernorm_split<<<NB * NH, 256, 0, stream>>>(lnsrc, gl, bl, qhi, qlo);
    }

    // ---- final projection (fused split+transpose)
    { dim3 g(1024 / 64, 512 / 64, 1);
      cvt_split_t<<<g, 256, 0, stream>>>(proj, pth, ptl, 512, 1024); }
    outproj3<<<4096, 256, 0, stream>>>(qhi, qlo, pth, ptl, out);
}

// Round 12
// 1618.488 us; speedup vs baseline: 2.0343x; 1.2557x over previous
//
#include <hip/hip_runtime.h>
#include <hip/hip_bf16.h>
#include <math.h>

// Problem dims
#define NB 16
#define NS 256
#define ND 512
#define NH 1024
#define NF 2048
#define NHID 256

typedef __attribute__((ext_vector_type(8))) short bf16x8;
typedef __attribute__((ext_vector_type(4))) float f32x4;

__device__ __forceinline__ unsigned short f2bf(float f) {
    unsigned u = __float_as_uint(f);
    unsigned r = u + 0x7fffu + ((u >> 16) & 1u);
    return (unsigned short)(r >> 16);
}
__device__ __forceinline__ float bf2f(unsigned short h) {
    return __uint_as_float(((unsigned)h) << 16);
}
__device__ __forceinline__ float sigmoid_fast(float x) {
    return 1.0f / (1.0f + __expf(-x));
}
__device__ __forceinline__ float tanh_fast(float x) {
    return 1.0f - 2.0f / (__expf(2.0f * x) + 1.0f);
}

// ---------------------------------------------------------------------------
// MFMA GEMM v4: C[M,N] = A[M,K] @ B[N,K]^T (+bias)(+gelu)
// PASSES=3: split hi/lo operands, 3-pass (~fp32). PASSES=1: hi only (bf16).
// OUT: 0 = fp32 C, 1 = split hi/lo, 2 = hi only.
// lda/ldb row strides (u16 elems). global_load_lds width-16, linear LDS.
// Tile 128x128, BK=32, 256 thr. Z-batched.
// ---------------------------------------------------------------------------
template<int PASSES, int ACT, int OUT>
__global__ __launch_bounds__(256) void sgemm4(
    const unsigned short* __restrict__ Ahi, const unsigned short* __restrict__ Alo,
    const unsigned short* __restrict__ Bhi, const unsigned short* __restrict__ Blo,
    const float* __restrict__ bias,
    float* __restrict__ C, unsigned short* __restrict__ Chi, unsigned short* __restrict__ Clo,
    int M, int N, int K, int lda, int ldb, long sA, long sB, long sC)
{
    __shared__ unsigned short Ah[128 * 32];
    __shared__ unsigned short Bh[128 * 32];
    __shared__ unsigned short Al[(PASSES == 3) ? 128 * 32 : 64];
    __shared__ unsigned short Bl[(PASSES == 3) ? 128 * 32 : 64];

    const int t = threadIdx.x;
    const int z = blockIdx.z;
    const int m0 = blockIdx.y * 128, n0 = blockIdx.x * 128;
    const int wid = t >> 6, lane = t & 63;
    const int wr = (wid >> 1) * 64, wc = (wid & 1) * 64;
    const int lr = lane & 15, lk = lane >> 4;
    const int rl = lane >> 2, sl = lane & 3;

    const unsigned short* pAh = Ahi + (size_t)z * sA;
    const unsigned short* pBh = Bhi + (size_t)z * sB;
    const unsigned short* pAl = (PASSES == 3) ? Alo + (size_t)z * sA : nullptr;
    const unsigned short* pBl = (PASSES == 3) ? Blo + (size_t)z * sB : nullptr;

    f32x4 acc[4][4];
    #pragma unroll
    for (int i = 0; i < 4; ++i)
        #pragma unroll
        for (int j = 0; j < 4; ++j) acc[i][j] = (f32x4){0.f, 0.f, 0.f, 0.f};

    for (int k0 = 0; k0 < K; k0 += 32) {
        #pragma unroll
        for (int e = 0; e < 2; ++e) {
            const int r = e * 64 + wid * 16 + rl;
            const size_t goA = (size_t)(m0 + r) * lda + k0 + sl * 8;
            const size_t goB = (size_t)(n0 + r) * ldb + k0 + sl * 8;
            const int lo = (e * 64 + wid * 16) * 32;
            __builtin_amdgcn_global_load_lds((const void*)(pAh + goA), (void*)&Ah[lo], 16, 0, 0);
            __builtin_amdgcn_global_load_lds((const void*)(pBh + goB), (void*)&Bh[lo], 16, 0, 0);
            if (PASSES == 3) {
                __builtin_amdgcn_global_load_lds((const void*)(pAl + goA), (void*)&Al[lo], 16, 0, 0);
                __builtin_amdgcn_global_load_lds((const void*)(pBl + goB), (void*)&Bl[lo], 16, 0, 0);
            }
        }
        __syncthreads();

        bf16x8 ah[4], bh[4], al[4], bl[4];
        #pragma unroll
        for (int mt = 0; mt < 4; ++mt) {
            int rf = wr + mt * 16 + lr;
            ah[mt] = *(const bf16x8*)&Ah[rf * 32 + lk * 8];
            if (PASSES == 3) al[mt] = *(const bf16x8*)&Al[rf * 32 + lk * 8];
        }
        #pragma unroll
        for (int nt = 0; nt < 4; ++nt) {
            int rf = wc + nt * 16 + lr;
            bh[nt] = *(const bf16x8*)&Bh[rf * 32 + lk * 8];
            if (PASSES == 3) bl[nt] = *(const bf16x8*)&Bl[rf * 32 + lk * 8];
        }
        #pragma unroll
        for (int mt = 0; mt < 4; ++mt)
            #pragma unroll
            for (int nt = 0; nt < 4; ++nt) {
                acc[mt][nt] = __builtin_amdgcn_mfma_f32_16x16x32_bf16(ah[mt], bh[nt], acc[mt][nt], 0, 0, 0);
                if (PASSES == 3) {
                    acc[mt][nt] = __builtin_amdgcn_mfma_f32_16x16x32_bf16(al[mt], bh[nt], acc[mt][nt], 0, 0, 0);
                    acc[mt][nt] = __builtin_amdgcn_mfma_f32_16x16x32_bf16(ah[mt], bl[nt], acc[mt][nt], 0, 0, 0);
                }
            }
        __syncthreads();
    }

    #pragma unroll
    for (int nt = 0; nt < 4; ++nt) {
        int col = n0 + wc + nt * 16 + lr;
        float bv = bias ? bias[col] : 0.0f;
        #pragma unroll
        for (int mt = 0; mt < 4; ++mt) {
            #pragma unroll
            for (int i = 0; i < 4; ++i) {
                int row = m0 + wr + mt * 16 + lk * 4 + i;
                float x = acc[mt][nt][i] + bv;
                if (ACT == 1) x = 0.5f * x * (1.0f + erff(x * 0.70710678118654752f));
                size_t oi = (size_t)z * sC + (size_t)row * N + col;
                if (OUT == 1) {
                    unsigned short h = f2bf(x);
                    Chi[oi] = h;
                    Clo[oi] = f2bf(x - bf2f(h));
                } else if (OUT == 2) {
                    Chi[oi] = f2bf(x);
                } else {
                    C[oi] = x;
                }
            }
        }
    }
}

// dispatch helper (only instantiates the used combos)
static void gemm4(int passes, int act, int outm,
                  const unsigned short* Ahi, const unsigned short* Alo,
                  const unsigned short* Bhi, const unsigned short* Blo,
                  const float* bias, float* C, unsigned short* Chi, unsigned short* Clo,
                  int M, int N, int K, int lda, int ldb,
                  long sA, long sB, long sC, int Z, hipStream_t st)
{
    dim3 g(N / 128, M / 128, Z), b(256);
    if (passes == 3) {
        sgemm4<3, 0, 0><<<g, b, 0, st>>>(Ahi, Alo, Bhi, Blo, bias, C, Chi, Clo, M, N, K, lda, ldb, sA, sB, sC);
    } else if (outm == 1) {
        sgemm4<1, 0, 1><<<g, b, 0, st>>>(Ahi, Alo, Bhi, Blo, bias, C, Chi, Clo, M, N, K, lda, ldb, sA, sB, sC);
    } else if (outm == 2 && act == 1) {
        sgemm4<1, 1, 2><<<g, b, 0, st>>>(Ahi, Alo, Bhi, Blo, bias, C, Chi, Clo, M, N, K, lda, ldb, sA, sB, sC);
    } else if (outm == 2) {
        sgemm4<1, 0, 2><<<g, b, 0, st>>>(Ahi, Alo, Bhi, Blo, bias, C, Chi, Clo, M, N, K, lda, ldb, sA, sB, sC);
    } else {
        sgemm4<1, 0, 0><<<g, b, 0, st>>>(Ahi, Alo, Bhi, Blo, bias, C, Chi, Clo, M, N, K, lda, ldb, sA, sB, sC);
    }
}

// ---------------------------------------------------------------------------
// fp32 -> split bf16 hi/lo (n multiple of 1024)
// ---------------------------------------------------------------------------
__global__ __launch_bounds__(256) void cvt_split(const float* __restrict__ in,
                                                 unsigned short* __restrict__ hi,
                                                 unsigned short* __restrict__ lo)
{
    size_t i = ((size_t)blockIdx.x * 256 + threadIdx.x) * 4;
    float4 v = *(const float4*)(in + i);
    ushort4 h, l;
    h.x = f2bf(v.x); l.x = f2bf(v.x - bf2f(h.x));
    h.y = f2bf(v.y); l.y = f2bf(v.y - bf2f(h.y));
    h.z = f2bf(v.z); l.z = f2bf(v.z - bf2f(h.z));
    h.w = f2bf(v.w); l.w = f2bf(v.w - bf2f(h.w));
    *(ushort4*)(hi + i) = h;
    *(ushort4*)(lo + i) = l;
}

// ---------------------------------------------------------------------------
// Fused: fp32 (R,C) -> split bf16 hi/lo TRANSPOSED (C,R). R,C mult of 64.
// ---------------------------------------------------------------------------
__global__ __launch_bounds__(256) void cvt_split_t(const float* __restrict__ in,
                                                   unsigned short* __restrict__ hiT,
                                                   unsigned short* __restrict__ loT,
                                                   int R, int C)
{
    __shared__ unsigned short tileH[64 * 72];
    __shared__ unsigned short tileL[64 * 72];
    int r0 = blockIdx.y * 64, c0 = blockIdx.x * 64;
    int t = threadIdx.x;
    int tr = t >> 2, tc = (t & 3) * 16;

    float v[16];
    const float* src = in + (size_t)(r0 + tr) * C + c0 + tc;
    *(float4*)(v)      = *(const float4*)(src);
    *(float4*)(v + 4)  = *(const float4*)(src + 4);
    *(float4*)(v + 8)  = *(const float4*)(src + 8);
    *(float4*)(v + 12) = *(const float4*)(src + 12);
    #pragma unroll
    for (int i = 0; i < 16; ++i) {
        unsigned short h = f2bf(v[i]);
        tileH[(tc + i) * 72 + tr] = h;
        tileL[(tc + i) * 72 + tr] = f2bf(v[i] - bf2f(h));
    }
    __syncthreads();

    size_t ob = (size_t)(c0 + tr) * R + r0 + tc;
    *(uint4*)(hiT + ob)     = *(const uint4*)(&tileH[tr * 72 + tc]);
    *(uint4*)(hiT + ob + 8) = *(const uint4*)(&tileH[tr * 72 + tc + 8]);
    *(uint4*)(loT + ob)     = *(const uint4*)(&tileL[tr * 72 + tc]);
    *(uint4*)(loT + ob + 8) = *(const uint4*)(&tileL[tr * 72 + tc + 8]);
}

// ---------------------------------------------------------------------------
// fp32 (R,C) -> bf16 hi TRANSPOSED (C,R) only (for 1-pass GEMM weights)
// ---------------------------------------------------------------------------
__global__ __launch_bounds__(256) void cvt_t_hi(const float* __restrict__ in,
                                                unsigned short* __restrict__ hiT,
                                                int R, int C)
{
    __shared__ unsigned short tileH[64 * 72];
    int r0 = blockIdx.y * 64, c0 = blockIdx.x * 64;
    int t = threadIdx.x;
    int tr = t >> 2, tc = (t & 3) * 16;

    float v[16];
    const float* src = in + (size_t)(r0 + tr) * C + c0 + tc;
    *(float4*)(v)      = *(const float4*)(src);
    *(float4*)(v + 4)  = *(const float4*)(src + 4);
    *(float4*)(v + 8)  = *(const float4*)(src + 8);
    *(float4*)(v + 12) = *(const float4*)(src + 12);
    #pragma unroll
    for (int i = 0; i < 16; ++i) tileH[(tc + i) * 72 + tr] = f2bf(v[i]);
    __syncthreads();

    size_t ob = (size_t)(c0 + tr) * R + r0 + tc;
    *(uint4*)(hiT + ob)     = *(const uint4*)(&tileH[tr * 72 + tc]);
    *(uint4*)(hiT + ob + 8) = *(const uint4*)(&tileH[tr * 72 + tc + 8]);
}

// ---------------------------------------------------------------------------
// bf16 (R,C) -> (C,R) transpose, z-batched. R,C multiples of 64.
// ---------------------------------------------------------------------------
__global__ __launch_bounds__(256) void tcvt_bf16(const unsigned short* __restrict__ in,
                                                 unsigned short* __restrict__ out,
                                                 int R, int C)
{
    __shared__ unsigned short tile[64 * 72];
    int z = blockIdx.z;
    in += (size_t)z * R * C;
    out += (size_t)z * R * C;
    int r0 = blockIdx.y * 64, c0 = blockIdx.x * 64;
    int t = threadIdx.x;
    int tr = t >> 2, tc = (t & 3) * 16;

    uint4 q0 = *(const uint4*)(in + (size_t)(r0 + tr) * C + c0 + tc);
    uint4 q1 = *(const uint4*)(in + (size_t)(r0 + tr) * C + c0 + tc + 8);
    unsigned short e[16];
    *(uint4*)(e) = q0;
    *(uint4*)(e + 8) = q1;
    #pragma unroll
    for (int i = 0; i < 16; ++i) tile[(tc + i) * 72 + tr] = e[i];
    __syncthreads();

    uint4 o0 = *(const uint4*)(&tile[tr * 72 + tc]);
    uint4 o1 = *(const uint4*)(&tile[tr * 72 + tc + 8]);
    *(uint4*)(out + (size_t)(c0 + tr) * R + r0 + tc) = o0;
    *(uint4*)(out + (size_t)(c0 + tr) * R + r0 + tc + 8) = o1;
}

// ---------------------------------------------------------------------------
// bias combine
// ---------------------------------------------------------------------------
__global__ __launch_bounds__(256) void bias_sum_kernel(
    const float* bihF, const float* bhhF, const float* bihB, const float* bhhB,
    float* out)
{
    int i = blockIdx.x * 256 + threadIdx.x;
    if (i < 1024) out[i] = bihF[i] + bhhF[i];
    else out[i] = bihB[i - 1024] + bhhB[i - 1024];
}

// ---------------------------------------------------------------------------
// LSTM recurrence v6m (unchanged, measured 822us).
// ---------------------------------------------------------------------------
__global__ __launch_bounds__(256) void lstm_rec6m(
    const float* __restrict__ pre,
    const float* __restrict__ WhhF, const float* __restrict__ WhhB,
    unsigned long long* __restrict__ hg,
    int* __restrict__ flags,
    unsigned short* __restrict__ fhi, unsigned short* __restrict__ flo)
{
    const int bid = blockIdx.x;
    const int dir = bid >> 4, slice = bid & 15;
    const float* Whh = dir ? WhhB : WhhF;

    const int tid = threadIdx.x;
    const int wv = tid >> 6;
    const int lane = tid & 63;
    const int lr = lane & 15;
    const int lk = lane >> 4;
    const int eb = tid >> 4;
    const int eu = tid & 15;

    __shared__ unsigned short hh[16 * 264];
    __shared__ unsigned short hl[16 * 264];
    __shared__ float gx[4][16][17];

    bf16x8 wfh[8], wfl[8];
    {
        const float* wrow = Whh + (size_t)(wv * 256 + slice * 16 + lr) * 256 + lk * 8;
        #pragma unroll
        for (int kt = 0; kt < 8; ++kt) {
            float4 a = *(const float4*)(wrow + kt * 32);
            float4 b = *(const float4*)(wrow + kt * 32 + 4);
            float v[8] = {a.x, a.y, a.z, a.w, b.x, b.y, b.z, b.w};
            unsigned short hhv[8], llv[8];
            #pragma unroll
            for (int i = 0; i < 8; ++i) {
                unsigned short h = f2bf(v[i]);
                hhv[i] = h;
                llv[i] = f2bf(v[i] - bf2f(h));
            }
            wfh[kt] = *(bf16x8*)hhv;
            wfl[kt] = *(bf16x8*)llv;
        }
    }
    for (int i = tid; i < 16 * 264; i += 256) { hh[i] = 0; hl[i] = 0; }

    float c = 0.0f;
    __syncthreads();

    for (int si = 0; si < NS; ++si) {
        const int s = dir ? (NS - 1 - si) : si;
        const float* pp = pre + ((size_t)(eb * NS + s)) * 2048 + dir * 1024 + slice * 16 + eu;
        float pi = pp[0], pf = pp[256], pg = pp[512], po = pp[768];

        if (si > 0) {
            if (tid < 16) {
                while (__hip_atomic_load(&flags[dir * 16 + tid], __ATOMIC_RELAXED,
                                         __HIP_MEMORY_SCOPE_AGENT) < si) {
                    __builtin_amdgcn_s_sleep(1);
                }
            }
            __syncthreads();
            const unsigned long long* src =
                hg + (size_t)(((si - 1) & 1) * 2 + dir) * 2048;
            const int b2 = tid >> 4, pb = (tid & 15) * 8;
            unsigned short hbuf[16], lbuf[16];
            #pragma unroll
            for (int j = 0; j < 8; ++j) {
                unsigned long long v = __hip_atomic_load(
                    &src[b2 * 128 + pb + j], __ATOMIC_RELAXED,
                    __HIP_MEMORY_SCOPE_AGENT);
                hbuf[2 * j]     = (unsigned short)(v & 0xffff);
                lbuf[2 * j]     = (unsigned short)((v >> 16) & 0xffff);
                hbuf[2 * j + 1] = (unsigned short)((v >> 32) & 0xffff);
                lbuf[2 * j + 1] = (unsigned short)(v >> 48);
            }
            char* dh = (char*)hh + b2 * 528 + (tid & 15) * 32;
            char* dl = (char*)hl + b2 * 528 + (tid & 15) * 32;
            *(uint4*)dh        = *(uint4*)(hbuf);
            *(uint4*)(dh + 16) = *(uint4*)(hbuf + 8);
            *(uint4*)dl        = *(uint4*)(lbuf);
            *(uint4*)(dl + 16) = *(uint4*)(lbuf + 8);
            __syncthreads();
        }

        f32x4 acc = (f32x4){0.f, 0.f, 0.f, 0.f};
        #pragma unroll
        for (int kt = 0; kt < 8; ++kt) {
            const char* hp = (const char*)hh + lr * 528 + kt * 64 + lk * 16;
            const char* lp = (const char*)hl + lr * 528 + kt * 64 + lk * 16;
            bf16x8 ah = *(const bf16x8*)hp;
            bf16x8 al = *(const bf16x8*)lp;
            acc = __builtin_amdgcn_mfma_f32_16x16x32_bf16(ah, wfh[kt], acc, 0, 0, 0);
            acc = __builtin_amdgcn_mfma_f32_16x16x32_bf16(al, wfh[kt], acc, 0, 0, 0);
            acc = __builtin_amdgcn_mfma_f32_16x16x32_bf16(ah, wfl[kt], acc, 0, 0, 0);
        }
        #pragma unroll
        for (int i = 0; i < 4; ++i) gx[wv][lk * 4 + i][lr] = acc[i];
        __syncthreads();

        float ai = gx[0][eb][eu] + pi;
        float af = gx[1][eb][eu] + pf;
        float ag = gx[2][eb][eu] + pg;
        float ao = gx[3][eb][eu] + po;
        float gi = sigmoid_fast(ai);
        float gf = sigmoid_fast(af);
        float gg = tanh_fast(ag);
        float go = sigmoid_fast(ao);
        c = gf * c + gi * gg;
        float h = go * tanh_fast(c);

        unsigned short h16 = f2bf(h);
        unsigned short l16 = f2bf(h - bf2f(h16));
        unsigned my = (unsigned)h16 | ((unsigned)l16 << 16);
        unsigned oth = __shfl_xor(my, 1);
        if ((eu & 1) == 0) {
            unsigned long long v = (unsigned long long)my |
                                   ((unsigned long long)oth << 32);
            unsigned long long* dst =
                hg + (size_t)((si & 1) * 2 + dir) * 2048;
            __hip_atomic_store(&dst[eb * 128 + slice * 8 + (eu >> 1)], v,
                               __ATOMIC_RELAXED, __HIP_MEMORY_SCOPE_AGENT);
        }
        size_t oi = ((size_t)(eb * NS + s)) * 512 + dir * 256 + slice * 16 + eu;
        fhi[oi] = h16;
        flo[oi] = l16;

        asm volatile("s_waitcnt vmcnt(0)" ::: "memory");
        __syncthreads();
        if (tid == 0)
            __hip_atomic_store(&flags[bid], si + 1, __ATOMIC_RELAXED,
                               __HIP_MEMORY_SCOPE_AGENT);
    }
}

// ---------------------------------------------------------------------------
// In-place split softmax: row of N fp32 -> [N hi bf16][N lo bf16].
// ---------------------------------------------------------------------------
__global__ __launch_bounds__(256) void softmax_ip(float* __restrict__ X, int N)
{
    float* row = X + (size_t)blockIdx.x * N;
    unsigned short* o = (unsigned short*)row;
    int t = threadIdx.x;
    int cnt = N >> 8;
    float v[4];
    float m = -1e30f;
    for (int i = 0; i < cnt; ++i) { v[i] = row[t + (i << 8)]; m = fmaxf(m, v[i]); }
    for (int sh = 32; sh; sh >>= 1) m = fmaxf(m, __shfl_xor(m, sh));
    __shared__ float lm[4];
    if ((t & 63) == 0) lm[t >> 6] = m;
    __syncthreads();
    m = fmaxf(fmaxf(lm[0], lm[1]), fmaxf(lm[2], lm[3]));
    float s = 0.0f;
    for (int i = 0; i < cnt; ++i) { v[i] = expf(v[i] - m); s += v[i]; }
    for (int sh = 32; sh; sh >>= 1) s += __shfl_xor(s, sh);
    __shared__ float ls[4];
    if ((t & 63) == 0) ls[t >> 6] = s;
    __syncthreads();
    s = ls[0] + ls[1] + ls[2] + ls[3];
    float inv = 1.0f / s;
    __syncthreads();
    for (int i = 0; i < cnt; ++i) {
        float y = v[i] * inv;
        unsigned short h = f2bf(y);
        int j = t + (i << 8);
        o[j] = h;
        o[N + j] = f2bf(y - bf2f(h));
    }
}

// ---------------------------------------------------------------------------
// LayerNorm rows of 512 fp32 -> split bf16 out.
// ---------------------------------------------------------------------------
__global__ __launch_bounds__(256) void layernorm_split(
    const float* __restrict__ X, const float* __restrict__ g, const float* __restrict__ b,
    unsigned short* __restrict__ ohi, unsigned short* __restrict__ olo)
{
    const float* row = X + (size_t)blockIdx.x * 512;
    size_t ob = (size_t)blockIdx.x * 512;
    int t = threadIdx.x;
    float x0 = row[t], x1 = row[t + 256];
    float s = x0 + x1, sq = x0 * x0 + x1 * x1;
    for (int o = 32; o; o >>= 1) { s += __shfl_xor(s, o); sq += __shfl_xor(sq, o); }
    __shared__ float ls[8];
    int w = t >> 6;
    if ((t & 63) == 0) { ls[w] = s; ls[4 + w] = sq; }
    __syncthreads();
    s = ls[0] + ls[1] + ls[2] + ls[3];
    sq = ls[4] + ls[5] + ls[6] + ls[7];
    float mu = s * (1.0f / 512.0f);
    float var = sq * (1.0f / 512.0f) - mu * mu;
    float inv = rsqrtf(var + 1e-5f);
    float y0 = (x0 - mu) * inv * g[t]       + b[t];
    float y1 = (x1 - mu) * inv * g[t + 256] + b[t + 256];
    unsigned short h0 = f2bf(y0), h1 = f2bf(y1);
    ohi[ob + t]       = h0;  olo[ob + t]       = f2bf(y0 - bf2f(h0));
    ohi[ob + t + 256] = h1;  olo[ob + t + 256] = f2bf(y1 - bf2f(h1));
}

// ---------------------------------------------------------------------------
// out[b,h] = dot(q[b,h,:], projT[h,:]) with hi+lo reconstruction
// ---------------------------------------------------------------------------
__global__ __launch_bounds__(256) void outproj3(
    const unsigned short* __restrict__ qhi, const unsigned short* __restrict__ qlo,
    const unsigned short* __restrict__ phi, const unsigned short* __restrict__ plo,
    float* __restrict__ out)
{
    int gw = blockIdx.x * 4 + (threadIdx.x >> 6);
    int lane = threadIdx.x & 63;
    int h = gw & 1023;
    uint4 qh = ((const uint4*)(qhi + (size_t)gw * 512))[lane];
    uint4 ql = ((const uint4*)(qlo + (size_t)gw * 512))[lane];
    uint4 ph = ((const uint4*)(phi + (size_t)h * 512))[lane];
    uint4 pl = ((const uint4*)(plo + (size_t)h * 512))[lane];
    unsigned short qhe[8], qle[8], phe[8], ple[8];
    *(uint4*)qhe = qh; *(uint4*)qle = ql; *(uint4*)phe = ph; *(uint4*)ple = pl;
    float s = 0.0f;
    #pragma unroll
    for (int i = 0; i < 8; ++i) {
        float q = bf2f(qhe[i]) + bf2f(qle[i]);
        float p = bf2f(phe[i]) + bf2f(ple[i]);
        s += q * p;
    }
    for (int o = 32; o; o >>= 1) s += __shfl_xor(s, o);
    if (lane == 0) out[gw] = s;
}

// ---------------------------------------------------------------------------
// launcher
// ---------------------------------------------------------------------------
extern "C" void kernel_launch(void* const* d_in, const int* in_sizes, int n_in,
                              void* d_out, int out_size, void* d_ws, size_t ws_size,
                              hipStream_t stream)
{
    (void)in_sizes; (void)n_in; (void)out_size; (void)ws_size;

    const float* x     = (const float*)d_in[0];
    const float* le    = (const float*)d_in[1];
    const float* proj  = (const float*)d_in[2];
    const float* WihF  = (const float*)d_in[3];
    const float* WhhF  = (const float*)d_in[4];
    const float* bihF  = (const float*)d_in[5];
    const float* bhhF  = (const float*)d_in[6];
    const float* WihB  = (const float*)d_in[7];
    const float* WhhB  = (const float*)d_in[8];
    const float* bihB  = (const float*)d_in[9];
    const float* bhhB  = (const float*)d_in[10];
    const float* w1    = (const float*)d_in[11];
    const float* b1    = (const float*)d_in[12];
    const float* w2    = (const float*)d_in[13];
    const float* b2    = (const float*)d_in[14];
    const float* lng   = (const float*)d_in[15];
    const float* lnb   = (const float*)d_in[16];
    float* out = (float*)d_out;
    float* ws  = (float*)d_ws;
    unsigned short* wsu = (unsigned short*)d_ws;

    const size_t MEG = 1048576;
    const size_t R0    = 0;              // 8M: pre (4096x2048) -> qtT hi (L1) -> lnsrc
    const size_t R1    = 8 * MEG;        // 8M: q2 hi
    const size_t AR    = 16 * MEG;       // 17M arena
    const size_t QHI   = 33 * MEG;
    const size_t QLO   = 37 * MEG;
    const size_t FHI   = 41 * MEG;
    const size_t FLO   = 42 * MEG;
    const size_t FTHI  = 43 * MEG;
    const size_t FTLO  = 44 * MEG;
    const size_t LEHI  = 45 * MEG;
    const size_t LELO  = LEHI  + MEG / 4;
    const size_t LETHI = LELO  + MEG / 4;
    const size_t LETLO = LETHI + MEG / 4;
    const size_t WIHH  = 46 * MEG;
    const size_t WIHL  = WIHH + MEG / 2;
    const size_t SYNC  = 47 * MEG;       // flags[32] + hg u64[8192]
    const size_t W1TH  = SYNC  + MEG / 4;
    const size_t W1TL  = W1TH  + MEG / 2;    // unused (1-pass) but reserved
    const size_t W2TH  = W1TL  + MEG / 2;
    const size_t W2TL  = W2TH  + MEG / 2;    // unused
    const size_t PTH   = W2TL  + MEG / 2;
    const size_t PTL   = PTH   + MEG / 4;
    const size_t BSUM  = PTL   + MEG / 4;

    float* pre    = ws + R0;             // (4096, 2048): [F 1024 | B 1024]
    float* lnsrc  = ws + R0;
    float* arena  = ws + AR;
    float* bsum   = ws + BSUM;
    int*   flags  = (int*)(ws + SYNC);
    unsigned long long* hg = (unsigned long long*)(ws + SYNC + 1024);
    unsigned short* qthi  = wsu + 2 * R0;                 // (L1 attn only)
    unsigned short* q2hi  = wsu + 2 * R1;                 // (16,1024,512) hi
    unsigned short* qhi   = wsu + 2 * QHI;
    unsigned short* qlo   = wsu + 2 * QLO;
    unsigned short* fhi   = wsu + 2 * FHI;
    unsigned short* flo   = wsu + 2 * FLO;
    unsigned short* fthi  = wsu + 2 * FTHI;
    unsigned short* ftlo  = wsu + 2 * FTLO;
    unsigned short* lehi  = wsu + 2 * LEHI;
    unsigned short* lelo  = wsu + 2 * LELO;
    unsigned short* lethi = wsu + 2 * LETHI;
    unsigned short* letlo = wsu + 2 * LETLO;
    unsigned short* wihh  = wsu + 2 * WIHH;
    unsigned short* wihl  = wsu + 2 * WIHL;
    unsigned short* w1th  = wsu + 2 * W1TH;
    unsigned short* w2th  = wsu + 2 * W2TH;
    unsigned short* pth   = wsu + 2 * PTH;
    unsigned short* ptl   = wsu + 2 * PTL;

    // ---- prep
    bias_sum_kernel<<<8, 256, 0, stream>>>(bihF, bhhF, bihB, bhhB, bsum);
    cvt_split<<<512, 256, 0, stream>>>(WihF, wihh, wihl);
    cvt_split<<<512, 256, 0, stream>>>(WihB, wihh + 524288, wihl + 524288);
    cvt_split<<<512, 256, 0, stream>>>(le, lehi, lelo);
    { dim3 g(512 / 64, 1024 / 64, 1);
      cvt_split_t<<<g, 256, 0, stream>>>(le, lethi, letlo, 1024, 512); }
    hipMemsetAsync(flags, 0, 32 * sizeof(int), stream);

    // x -> split (arena scratch)
    unsigned short* xhi = wsu + 2 * AR;
    unsigned short* xlo = wsu + 2 * (AR + MEG);
    cvt_split<<<2048, 256, 0, stream>>>(x, xhi, xlo);

    // ---- LSTM input projection (merged F|B, 3-pass): pre = x @ WihT + bsum
    gemm4(3, 0, 0, xhi, xlo, wihh, wihl, bsum, pre, nullptr, nullptr,
          NB * NS, 2048, ND, ND, ND, 0, 0, 0, 1, stream);

    // ---- recurrence -> features (split bf16)
    lstm_rec6m<<<32, 256, 0, stream>>>(pre, WhhF, WhhB, hg, flags, fhi, flo);
    { dim3 g(512 / 64, 256 / 64, 16);
      tcvt_bf16<<<g, 256, 0, stream>>>(fhi, fthi, 256, 512);
      tcvt_bf16<<<g, 256, 0, stream>>>(flo, ftlo, 256, 512); }

    // ---- layers
    for (int l = 0; l < 2; ++l) {
        const float* b1l = b1 + (size_t)l * NF;
        const float* b2l = b2 + (size_t)l * ND;
        const float* gl  = lng + (size_t)l * ND;
        const float* bl  = lnb + (size_t)l * ND;

        // FFN weights -> bf16 hi transposed (1-pass GEMMs need hi only)
        { dim3 g(NF / 64, ND / 64, 1);
          cvt_t_hi<<<g, 256, 0, stream>>>(w1 + (size_t)l * ND * NF, w1th, ND, NF); }  // (2048,512)
        { dim3 g(ND / 64, NF / 64, 1);
          cvt_t_hi<<<g, 256, 0, stream>>>(w2 + (size_t)l * NF * ND, w2th, NF, ND); }  // (512,2048)

        if (l == 0) {
            float* wsc = arena;
            unsigned short* wscu = (unsigned short*)wsc;
            unsigned short* q1hi = wsu + 2 * (AR + 1 * MEG);
            unsigned short* q1lo = wsu + 2 * (AR + 1 * MEG + MEG / 4);
            float* s2s = arena + 4 * MEG;
            unsigned short* s2u = (unsigned short*)s2s;

            // scores: 3-pass (precision); PV: 1-pass
            gemm4(3, 0, 0, lehi, lelo, lehi, lelo, nullptr, wsc, nullptr, nullptr,
                  NH, NH, ND, ND, ND, 0, 0, 0, 1, stream);
            softmax_ip<<<NH, 256, 0, stream>>>(wsc, NH);
            gemm4(1, 0, 1, wscu, nullptr, lethi, nullptr, nullptr, nullptr, q1hi, q1lo,
                  NH, ND, NH, 2 * NH, NH, 0, 0, 0, 1, stream);
            gemm4(3, 0, 0, q1hi, q1lo, fhi, flo, nullptr, s2s, nullptr, nullptr,
                  NH, NS, ND, ND, ND, 0, (long)NS * ND, (long)NH * NS, 16, stream);
            softmax_ip<<<NB * NH, 256, 0, stream>>>(s2s, NS);
            gemm4(1, 0, 2, s2u, nullptr, fthi, nullptr, nullptr, nullptr, q2hi, nullptr,
                  NH, ND, NS, 2 * NS, NS,
                  (long)2 * NH * NS, (long)ND * NS, (long)NH * ND, 16, stream);
        } else {
            { dim3 g(512 / 64, 1024 / 64, 16);
              tcvt_bf16<<<g, 256, 0, stream>>>(qhi, qthi, 1024, 512); }
            float* wsc = arena;
            unsigned short* wscu = (unsigned short*)wsc;
            unsigned short* q1hi = wsu + 2 * (AR + 8 * MEG);
            unsigned short* q1lo = wsu + 2 * (AR + 10 * MEG);
            float* s2s = arena + 12 * MEG;
            unsigned short* s2u = (unsigned short*)s2s;
            for (int g8 = 0; g8 < 2; ++g8) {
                size_t qo = (size_t)g8 * 8;
                gemm4(3, 0, 0, qhi + qo * NH * ND, qlo + qo * NH * ND,
                      qhi + qo * NH * ND, qlo + qo * NH * ND, nullptr, wsc, nullptr, nullptr,
                      NH, NH, ND, ND, ND,
                      (long)NH * ND, (long)NH * ND, (long)NH * NH, 8, stream);
                softmax_ip<<<8 * NH, 256, 0, stream>>>(wsc, NH);
                gemm4(1, 0, 1, wscu, nullptr, qthi + qo * ND * NH, nullptr,
                      nullptr, nullptr, q1hi, q1lo, NH, ND, NH, 2 * NH, NH,
                      (long)2 * NH * NH, (long)ND * NH, (long)NH * ND, 8, stream);
                gemm4(3, 0, 0, q1hi, q1lo, fhi + qo * NS * ND, flo + qo * NS * ND,
                      nullptr, s2s, nullptr, nullptr, NH, NS, ND, ND, ND,
                      (long)NH * ND, (long)NS * ND, (long)NH * NS, 8, stream);
                softmax_ip<<<8 * NH, 256, 0, stream>>>(s2s, NS);
                gemm4(1, 0, 2, s2u, nullptr, fthi + qo * ND * NS, nullptr,
                      nullptr, nullptr, q2hi + qo * NH * ND, nullptr,
                      NH, ND, NS, 2 * NS, NS,
                      (long)2 * NH * NS, (long)ND * NS, (long)NH * ND, 8, stream);
            }
        }

        // FFN (1-pass bf16): 2 chunks of 8192 rows; hi-only hidden
        unsigned short* ffhi = wsu + 2 * AR;
        for (int ch = 0; ch < 2; ++ch) {
            const unsigned short* rih = q2hi + (size_t)ch * 8192 * ND;
            float* rows_out = lnsrc + (size_t)ch * 8192 * ND;
            gemm4(1, 1, 2, rih, nullptr, w1th, nullptr, b1l, nullptr, ffhi, nullptr,
                  8192, NF, ND, ND, ND, 0, 0, 0, 1, stream);
            gemm4(1, 0, 0, ffhi, nullptr, w2th, nullptr, b2l, rows_out, nullptr, nullptr,
                  8192, ND, NF, NF, NF, 0, 0, 0, 1, stream);
        }
        layernorm_split<<<NB * NH, 256, 0, stream>>>(lnsrc, gl, bl, qhi, qlo);
    }

    // ---- final projection (split, exact)
    { dim3 g(1024 / 64, 512 / 64, 1);
      cvt_split_t<<<g, 256, 0, stream>>>(proj, pth, ptl, 512, 1024); }
    outproj3<<<4096, 256, 0, stream>>>(qhi, qlo, pth, ptl, out);
}

// Round 13
// 1510.035 us; speedup vs baseline: 2.1804x; 1.0718x over previous
//
#include <hip/hip_runtime.h>
#include <hip/hip_bf16.h>
#include <math.h>

// Problem dims
#define NB 16
#define NS 256
#define ND 512
#define NH 1024
#define NF 2048
#define NHID 256

typedef __attribute__((ext_vector_type(8))) short bf16x8;
typedef __attribute__((ext_vector_type(4))) float f32x4;

__device__ __forceinline__ unsigned short f2bf(float f) {
    unsigned u = __float_as_uint(f);
    unsigned r = u + 0x7fffu + ((u >> 16) & 1u);
    return (unsigned short)(r >> 16);
}
__device__ __forceinline__ float bf2f(unsigned short h) {
    return __uint_as_float(((unsigned)h) << 16);
}
__device__ __forceinline__ float sigmoid_fast(float x) {
    return 1.0f / (1.0f + __expf(-x));
}
__device__ __forceinline__ float tanh_fast(float x) {
    return 1.0f - 2.0f / (__expf(2.0f * x) + 1.0f);
}

// ---------------------------------------------------------------------------
// MFMA GEMM v4 (unchanged from round 12): C[M,N] = A[M,K] @ B[N,K]^T
// PASSES=3 split hi/lo (~fp32); PASSES=1 bf16. OUT: 0 fp32, 1 split, 2 hi.
// ---------------------------------------------------------------------------
template<int PASSES, int ACT, int OUT>
__global__ __launch_bounds__(256) void sgemm4(
    const unsigned short* __restrict__ Ahi, const unsigned short* __restrict__ Alo,
    const unsigned short* __restrict__ Bhi, const unsigned short* __restrict__ Blo,
    const float* __restrict__ bias,
    float* __restrict__ C, unsigned short* __restrict__ Chi, unsigned short* __restrict__ Clo,
    int M, int N, int K, int lda, int ldb, long sA, long sB, long sC)
{
    __shared__ unsigned short Ah[128 * 32];
    __shared__ unsigned short Bh[128 * 32];
    __shared__ unsigned short Al[(PASSES == 3) ? 128 * 32 : 64];
    __shared__ unsigned short Bl[(PASSES == 3) ? 128 * 32 : 64];

    const int t = threadIdx.x;
    const int z = blockIdx.z;
    const int m0 = blockIdx.y * 128, n0 = blockIdx.x * 128;
    const int wid = t >> 6, lane = t & 63;
    const int wr = (wid >> 1) * 64, wc = (wid & 1) * 64;
    const int lr = lane & 15, lk = lane >> 4;
    const int rl = lane >> 2, sl = lane & 3;

    const unsigned short* pAh = Ahi + (size_t)z * sA;
    const unsigned short* pBh = Bhi + (size_t)z * sB;
    const unsigned short* pAl = (PASSES == 3) ? Alo + (size_t)z * sA : nullptr;
    const unsigned short* pBl = (PASSES == 3) ? Blo + (size_t)z * sB : nullptr;

    f32x4 acc[4][4];
    #pragma unroll
    for (int i = 0; i < 4; ++i)
        #pragma unroll
        for (int j = 0; j < 4; ++j) acc[i][j] = (f32x4){0.f, 0.f, 0.f, 0.f};

    for (int k0 = 0; k0 < K; k0 += 32) {
        #pragma unroll
        for (int e = 0; e < 2; ++e) {
            const int r = e * 64 + wid * 16 + rl;
            const size_t goA = (size_t)(m0 + r) * lda + k0 + sl * 8;
            const size_t goB = (size_t)(n0 + r) * ldb + k0 + sl * 8;
            const int lo = (e * 64 + wid * 16) * 32;
            __builtin_amdgcn_global_load_lds((const void*)(pAh + goA), (void*)&Ah[lo], 16, 0, 0);
            __builtin_amdgcn_global_load_lds((const void*)(pBh + goB), (void*)&Bh[lo], 16, 0, 0);
            if (PASSES == 3) {
                __builtin_amdgcn_global_load_lds((const void*)(pAl + goA), (void*)&Al[lo], 16, 0, 0);
                __builtin_amdgcn_global_load_lds((const void*)(pBl + goB), (void*)&Bl[lo], 16, 0, 0);
            }
        }
        __syncthreads();

        bf16x8 ah[4], bh[4], al[4], bl[4];
        #pragma unroll
        for (int mt = 0; mt < 4; ++mt) {
            int rf = wr + mt * 16 + lr;
            ah[mt] = *(const bf16x8*)&Ah[rf * 32 + lk * 8];
            if (PASSES == 3) al[mt] = *(const bf16x8*)&Al[rf * 32 + lk * 8];
        }
        #pragma unroll
        for (int nt = 0; nt < 4; ++nt) {
            int rf = wc + nt * 16 + lr;
            bh[nt] = *(const bf16x8*)&Bh[rf * 32 + lk * 8];
            if (PASSES == 3) bl[nt] = *(const bf16x8*)&Bl[rf * 32 + lk * 8];
        }
        #pragma unroll
        for (int mt = 0; mt < 4; ++mt)
            #pragma unroll
            for (int nt = 0; nt < 4; ++nt) {
                acc[mt][nt] = __builtin_amdgcn_mfma_f32_16x16x32_bf16(ah[mt], bh[nt], acc[mt][nt], 0, 0, 0);
                if (PASSES == 3) {
                    acc[mt][nt] = __builtin_amdgcn_mfma_f32_16x16x32_bf16(al[mt], bh[nt], acc[mt][nt], 0, 0, 0);
                    acc[mt][nt] = __builtin_amdgcn_mfma_f32_16x16x32_bf16(ah[mt], bl[nt], acc[mt][nt], 0, 0, 0);
                }
            }
        __syncthreads();
    }

    #pragma unroll
    for (int nt = 0; nt < 4; ++nt) {
        int col = n0 + wc + nt * 16 + lr;
        float bv = bias ? bias[col] : 0.0f;
        #pragma unroll
        for (int mt = 0; mt < 4; ++mt) {
            #pragma unroll
            for (int i = 0; i < 4; ++i) {
                int row = m0 + wr + mt * 16 + lk * 4 + i;
                float x = acc[mt][nt][i] + bv;
                if (ACT == 1) x = 0.5f * x * (1.0f + erff(x * 0.70710678118654752f));
                size_t oi = (size_t)z * sC + (size_t)row * N + col;
                if (OUT == 1) {
                    unsigned short h = f2bf(x);
                    Chi[oi] = h;
                    Clo[oi] = f2bf(x - bf2f(h));
                } else if (OUT == 2) {
                    Chi[oi] = f2bf(x);
                } else {
                    C[oi] = x;
                }
            }
        }
    }
}

static void gemm4(int passes, int act, int outm,
                  const unsigned short* Ahi, const unsigned short* Alo,
                  const unsigned short* Bhi, const unsigned short* Blo,
                  const float* bias, float* C, unsigned short* Chi, unsigned short* Clo,
                  int M, int N, int K, int lda, int ldb,
                  long sA, long sB, long sC, int Z, hipStream_t st)
{
    dim3 g(N / 128, M / 128, Z), b(256);
    if (passes == 3) {
        sgemm4<3, 0, 0><<<g, b, 0, st>>>(Ahi, Alo, Bhi, Blo, bias, C, Chi, Clo, M, N, K, lda, ldb, sA, sB, sC);
    } else if (outm == 1) {
        sgemm4<1, 0, 1><<<g, b, 0, st>>>(Ahi, Alo, Bhi, Blo, bias, C, Chi, Clo, M, N, K, lda, ldb, sA, sB, sC);
    } else if (outm == 2 && act == 1) {
        sgemm4<1, 1, 2><<<g, b, 0, st>>>(Ahi, Alo, Bhi, Blo, bias, C, Chi, Clo, M, N, K, lda, ldb, sA, sB, sC);
    } else if (outm == 2) {
        sgemm4<1, 0, 2><<<g, b, 0, st>>>(Ahi, Alo, Bhi, Blo, bias, C, Chi, Clo, M, N, K, lda, ldb, sA, sB, sC);
    } else {
        sgemm4<1, 0, 0><<<g, b, 0, st>>>(Ahi, Alo, Bhi, Blo, bias, C, Chi, Clo, M, N, K, lda, ldb, sA, sB, sC);
    }
}

// ---------------------------------------------------------------------------
// fp32 -> split bf16 hi/lo (n multiple of 1024)
// ---------------------------------------------------------------------------
__global__ __launch_bounds__(256) void cvt_split(const float* __restrict__ in,
                                                 unsigned short* __restrict__ hi,
                                                 unsigned short* __restrict__ lo)
{
    size_t i = ((size_t)blockIdx.x * 256 + threadIdx.x) * 4;
    float4 v = *(const float4*)(in + i);
    ushort4 h, l;
    h.x = f2bf(v.x); l.x = f2bf(v.x - bf2f(h.x));
    h.y = f2bf(v.y); l.y = f2bf(v.y - bf2f(h.y));
    h.z = f2bf(v.z); l.z = f2bf(v.z - bf2f(h.z));
    h.w = f2bf(v.w); l.w = f2bf(v.w - bf2f(h.w));
    *(ushort4*)(hi + i) = h;
    *(ushort4*)(lo + i) = l;
}

// ---------------------------------------------------------------------------
// Fused: fp32 (R,C) -> split bf16 hi/lo TRANSPOSED (C,R) (standalone kernel,
// still used pre-rec for leT)
// ---------------------------------------------------------------------------
__global__ __launch_bounds__(256) void cvt_split_t(const float* __restrict__ in,
                                                   unsigned short* __restrict__ hiT,
                                                   unsigned short* __restrict__ loT,
                                                   int R, int C)
{
    __shared__ unsigned short tileH[64 * 72];
    __shared__ unsigned short tileL[64 * 72];
    int r0 = blockIdx.y * 64, c0 = blockIdx.x * 64;
    int t = threadIdx.x;
    int tr = t >> 2, tc = (t & 3) * 16;

    float v[16];
    const float* src = in + (size_t)(r0 + tr) * C + c0 + tc;
    *(float4*)(v)      = *(const float4*)(src);
    *(float4*)(v + 4)  = *(const float4*)(src + 4);
    *(float4*)(v + 8)  = *(const float4*)(src + 8);
    *(float4*)(v + 12) = *(const float4*)(src + 12);
    #pragma unroll
    for (int i = 0; i < 16; ++i) {
        unsigned short h = f2bf(v[i]);
        tileH[(tc + i) * 72 + tr] = h;
        tileL[(tc + i) * 72 + tr] = f2bf(v[i] - bf2f(h));
    }
    __syncthreads();

    size_t ob = (size_t)(c0 + tr) * R + r0 + tc;
    *(uint4*)(hiT + ob)     = *(const uint4*)(&tileH[tr * 72 + tc]);
    *(uint4*)(hiT + ob + 8) = *(const uint4*)(&tileH[tr * 72 + tc + 8]);
    *(uint4*)(loT + ob)     = *(const uint4*)(&tileL[tr * 72 + tc]);
    *(uint4*)(loT + ob + 8) = *(const uint4*)(&tileL[tr * 72 + tc + 8]);
}

// ---------------------------------------------------------------------------
// bf16 (R,C) -> (C,R) transpose, z-batched. R,C multiples of 64.
// ---------------------------------------------------------------------------
__global__ __launch_bounds__(256) void tcvt_bf16(const unsigned short* __restrict__ in,
                                                 unsigned short* __restrict__ out,
                                                 int R, int C)
{
    __shared__ unsigned short tile[64 * 72];
    int z = blockIdx.z;
    in += (size_t)z * R * C;
    out += (size_t)z * R * C;
    int r0 = blockIdx.y * 64, c0 = blockIdx.x * 64;
    int t = threadIdx.x;
    int tr = t >> 2, tc = (t & 3) * 16;

    uint4 q0 = *(const uint4*)(in + (size_t)(r0 + tr) * C + c0 + tc);
    uint4 q1 = *(const uint4*)(in + (size_t)(r0 + tr) * C + c0 + tc + 8);
    unsigned short e[16];
    *(uint4*)(e) = q0;
    *(uint4*)(e + 8) = q1;
    #pragma unroll
    for (int i = 0; i < 16; ++i) tile[(tc + i) * 72 + tr] = e[i];
    __syncthreads();

    uint4 o0 = *(const uint4*)(&tile[tr * 72 + tc]);
    uint4 o1 = *(const uint4*)(&tile[tr * 72 + tc + 8]);
    *(uint4*)(out + (size_t)(c0 + tr) * R + r0 + tc) = o0;
    *(uint4*)(out + (size_t)(c0 + tr) * R + r0 + tc + 8) = o1;
}

// ---------------------------------------------------------------------------
// bias combine
// ---------------------------------------------------------------------------
__global__ __launch_bounds__(256) void bias_sum_kernel(
    const float* bihF, const float* bhhF, const float* bihB, const float* bhhB,
    float* out)
{
    int i = blockIdx.x * 256 + threadIdx.x;
    if (i < 1024) out[i] = bihF[i] + bhhF[i];
    else out[i] = bihB[i - 1024] + bhhB[i - 1024];
}

// ---------------------------------------------------------------------------
// FUSED rec + helpers. grid = 256 blocks x 256 thr.
//  blocks 0..31 : lstm_rec6m body (untouched semantics; 822us measured)
//  blocks 32..95: one 128x128 tile each of L0 self-attn score GEMM
//                 wsc = le @ le^T (3-pass split, reg-staged, identical math)
//  blocks 32..255: grid-stride over 1152 conversion tiles
//                 (w1/w2 hi-T for both layers, proj split-T)
// Helpers are fully independent of rec blocks; their outputs are consumed
// only after this kernel completes. LDS: separate arrays per role (~71KB).
// ---------------------------------------------------------------------------
__global__ __launch_bounds__(256) void rec_fused(
    const float* __restrict__ pre,
    const float* __restrict__ WhhF, const float* __restrict__ WhhB,
    unsigned long long* __restrict__ hg, int* __restrict__ flags,
    unsigned short* __restrict__ fhi, unsigned short* __restrict__ flo,
    const unsigned short* __restrict__ lehi, const unsigned short* __restrict__ lelo,
    float* __restrict__ wsc,
    const float* __restrict__ w1, const float* __restrict__ w2,
    unsigned short* __restrict__ w1th0, unsigned short* __restrict__ w2th0,
    unsigned short* __restrict__ w1th1, unsigned short* __restrict__ w2th1,
    const float* __restrict__ proj,
    unsigned short* __restrict__ pth, unsigned short* __restrict__ ptl)
{
    // rec LDS
    __shared__ unsigned short hh[16 * 264];
    __shared__ unsigned short hl[16 * 264];
    __shared__ float gx[4][16][17];
    // helper GEMM LDS
    __shared__ unsigned short gAh[128 * 32];
    __shared__ unsigned short gAl[128 * 32];
    __shared__ unsigned short gBh[128 * 32];
    __shared__ unsigned short gBl[128 * 32];
    // helper cvt LDS
    __shared__ unsigned short tH[64 * 72];
    __shared__ unsigned short tL[64 * 72];

    const int tid = threadIdx.x;

    if (blockIdx.x < 32) {
        // ================= REC (identical to lstm_rec6m) =================
        const int bid = blockIdx.x;
        const int dir = bid >> 4, slice = bid & 15;
        const float* Whh = dir ? WhhB : WhhF;
        const int wv = tid >> 6;
        const int lane = tid & 63;
        const int lr = lane & 15;
        const int lk = lane >> 4;
        const int eb = tid >> 4;
        const int eu = tid & 15;

        bf16x8 wfh[8], wfl[8];
        {
            const float* wrow = Whh + (size_t)(wv * 256 + slice * 16 + lr) * 256 + lk * 8;
            #pragma unroll
            for (int kt = 0; kt < 8; ++kt) {
                float4 a = *(const float4*)(wrow + kt * 32);
                float4 b = *(const float4*)(wrow + kt * 32 + 4);
                float v[8] = {a.x, a.y, a.z, a.w, b.x, b.y, b.z, b.w};
                unsigned short hhv[8], llv[8];
                #pragma unroll
                for (int i = 0; i < 8; ++i) {
                    unsigned short h = f2bf(v[i]);
                    hhv[i] = h;
                    llv[i] = f2bf(v[i] - bf2f(h));
                }
                wfh[kt] = *(bf16x8*)hhv;
                wfl[kt] = *(bf16x8*)llv;
            }
        }
        for (int i = tid; i < 16 * 264; i += 256) { hh[i] = 0; hl[i] = 0; }

        float c = 0.0f;
        __syncthreads();

        for (int si = 0; si < NS; ++si) {
            const int s = dir ? (NS - 1 - si) : si;
            const float* pp = pre + ((size_t)(eb * NS + s)) * 2048 + dir * 1024 + slice * 16 + eu;
            float pi = pp[0], pf = pp[256], pg = pp[512], po = pp[768];

            if (si > 0) {
                if (tid < 16) {
                    while (__hip_atomic_load(&flags[dir * 16 + tid], __ATOMIC_RELAXED,
                                             __HIP_MEMORY_SCOPE_AGENT) < si) {
                        __builtin_amdgcn_s_sleep(1);
                    }
                }
                __syncthreads();
                const unsigned long long* src =
                    hg + (size_t)(((si - 1) & 1) * 2 + dir) * 2048;
                const int b2 = tid >> 4, pb = (tid & 15) * 8;
                unsigned short hbuf[16], lbuf[16];
                #pragma unroll
                for (int j = 0; j < 8; ++j) {
                    unsigned long long v = __hip_atomic_load(
                        &src[b2 * 128 + pb + j], __ATOMIC_RELAXED,
                        __HIP_MEMORY_SCOPE_AGENT);
                    hbuf[2 * j]     = (unsigned short)(v & 0xffff);
                    lbuf[2 * j]     = (unsigned short)((v >> 16) & 0xffff);
                    hbuf[2 * j + 1] = (unsigned short)((v >> 32) & 0xffff);
                    lbuf[2 * j + 1] = (unsigned short)(v >> 48);
                }
                char* dh = (char*)hh + b2 * 528 + (tid & 15) * 32;
                char* dl = (char*)hl + b2 * 528 + (tid & 15) * 32;
                *(uint4*)dh        = *(uint4*)(hbuf);
                *(uint4*)(dh + 16) = *(uint4*)(hbuf + 8);
                *(uint4*)dl        = *(uint4*)(lbuf);
                *(uint4*)(dl + 16) = *(uint4*)(lbuf + 8);
                __syncthreads();
            }

            f32x4 acc = (f32x4){0.f, 0.f, 0.f, 0.f};
            #pragma unroll
            for (int kt = 0; kt < 8; ++kt) {
                const char* hp = (const char*)hh + lr * 528 + kt * 64 + lk * 16;
                const char* lp = (const char*)hl + lr * 528 + kt * 64 + lk * 16;
                bf16x8 ah = *(const bf16x8*)hp;
                bf16x8 al = *(const bf16x8*)lp;
                acc = __builtin_amdgcn_mfma_f32_16x16x32_bf16(ah, wfh[kt], acc, 0, 0, 0);
                acc = __builtin_amdgcn_mfma_f32_16x16x32_bf16(al, wfh[kt], acc, 0, 0, 0);
                acc = __builtin_amdgcn_mfma_f32_16x16x32_bf16(ah, wfl[kt], acc, 0, 0, 0);
            }
            #pragma unroll
            for (int i = 0; i < 4; ++i) gx[wv][lk * 4 + i][lr] = acc[i];
            __syncthreads();

            float ai = gx[0][eb][eu] + pi;
            float af = gx[1][eb][eu] + pf;
            float ag = gx[2][eb][eu] + pg;
            float ao = gx[3][eb][eu] + po;
            float gi = sigmoid_fast(ai);
            float gf = sigmoid_fast(af);
            float gg = tanh_fast(ag);
            float go = sigmoid_fast(ao);
            c = gf * c + gi * gg;
            float h = go * tanh_fast(c);

            unsigned short h16 = f2bf(h);
            unsigned short l16 = f2bf(h - bf2f(h16));
            unsigned my = (unsigned)h16 | ((unsigned)l16 << 16);
            unsigned oth = __shfl_xor(my, 1);
            if ((eu & 1) == 0) {
                unsigned long long v = (unsigned long long)my |
                                       ((unsigned long long)oth << 32);
                unsigned long long* dst =
                    hg + (size_t)((si & 1) * 2 + dir) * 2048;
                __hip_atomic_store(&dst[eb * 128 + slice * 8 + (eu >> 1)], v,
                                   __ATOMIC_RELAXED, __HIP_MEMORY_SCOPE_AGENT);
            }
            size_t oi = ((size_t)(eb * NS + s)) * 512 + dir * 256 + slice * 16 + eu;
            fhi[oi] = h16;
            flo[oi] = l16;

            asm volatile("s_waitcnt vmcnt(0)" ::: "memory");
            __syncthreads();
            if (tid == 0)
                __hip_atomic_store(&flags[bid], si + 1, __ATOMIC_RELAXED,
                                   __HIP_MEMORY_SCOPE_AGENT);
        }
        return;
    }

    // ================= HELPERS =================
    const int hid = blockIdx.x - 32;            // 0..223
    const int lane = tid & 63;
    const int wid = tid >> 6;
    const int lr = lane & 15, lk = lane >> 4;

    // ---- Phase A: L0 score GEMM wsc = le @ le^T (3-pass), 64 tiles, reg-staged
    if (hid < 64) {
        const int m0 = (hid >> 3) * 128, n0 = (hid & 7) * 128;
        const int wr = (wid >> 1) * 64, wc = (wid & 1) * 64;
        const int sr = tid >> 1, sc = (tid & 1) * 16;

        f32x4 acc[4][4];
        #pragma unroll
        for (int i = 0; i < 4; ++i)
            #pragma unroll
            for (int j = 0; j < 4; ++j) acc[i][j] = (f32x4){0.f, 0.f, 0.f, 0.f};

        for (int k0 = 0; k0 < ND; k0 += 32) {
            {   // stage A rows (m0), B rows (n0), hi+lo
                size_t oa = (size_t)(m0 + sr) * ND + k0 + sc;
                size_t ob = (size_t)(n0 + sr) * ND + k0 + sc;
                *(uint4*)&gAh[sr * 32 + sc]     = *(const uint4*)(lehi + oa);
                *(uint4*)&gAh[sr * 32 + sc + 8] = *(const uint4*)(lehi + oa + 8);
                *(uint4*)&gAl[sr * 32 + sc]     = *(const uint4*)(lelo + oa);
                *(uint4*)&gAl[sr * 32 + sc + 8] = *(const uint4*)(lelo + oa + 8);
                *(uint4*)&gBh[sr * 32 + sc]     = *(const uint4*)(lehi + ob);
                *(uint4*)&gBh[sr * 32 + sc + 8] = *(const uint4*)(lehi + ob + 8);
                *(uint4*)&gBl[sr * 32 + sc]     = *(const uint4*)(lelo + ob);
                *(uint4*)&gBl[sr * 32 + sc + 8] = *(const uint4*)(lelo + ob + 8);
            }
            __syncthreads();

            bf16x8 ah[4], al[4], bh[4], bl[4];
            #pragma unroll
            for (int mt = 0; mt < 4; ++mt) {
                int rf = wr + mt * 16 + lr;
                ah[mt] = *(const bf16x8*)&gAh[rf * 32 + lk * 8];
                al[mt] = *(const bf16x8*)&gAl[rf * 32 + lk * 8];
            }
            #pragma unroll
            for (int nt = 0; nt < 4; ++nt) {
                int rf = wc + nt * 16 + lr;
                bh[nt] = *(const bf16x8*)&gBh[rf * 32 + lk * 8];
                bl[nt] = *(const bf16x8*)&gBl[rf * 32 + lk * 8];
            }
            #pragma unroll
            for (int mt = 0; mt < 4; ++mt)
                #pragma unroll
                for (int nt = 0; nt < 4; ++nt) {
                    acc[mt][nt] = __builtin_amdgcn_mfma_f32_16x16x32_bf16(ah[mt], bh[nt], acc[mt][nt], 0, 0, 0);
                    acc[mt][nt] = __builtin_amdgcn_mfma_f32_16x16x32_bf16(al[mt], bh[nt], acc[mt][nt], 0, 0, 0);
                    acc[mt][nt] = __builtin_amdgcn_mfma_f32_16x16x32_bf16(ah[mt], bl[nt], acc[mt][nt], 0, 0, 0);
                }
            __syncthreads();
        }
        const int wr2 = (wid >> 1) * 64, wc2 = (wid & 1) * 64;
        #pragma unroll
        for (int nt = 0; nt < 4; ++nt) {
            int col = n0 + wc2 + nt * 16 + lr;
            #pragma unroll
            for (int mt = 0; mt < 4; ++mt)
                #pragma unroll
                for (int i = 0; i < 4; ++i) {
                    int row = m0 + wr2 + mt * 16 + lk * 4 + i;
                    wsc[(size_t)row * NH + col] = acc[mt][nt][i];
                }
        }
    }

    // ---- Phase B: conversion tiles, grid-stride over 1152 jobs
    const int tr = tid >> 2, tc = (tid & 3) * 16;
    for (int job = hid; job < 1152; job += 224) {
        const float* in;
        unsigned short* outH;
        unsigned short* outL = nullptr;
        int R, C, by, bx;
        if (job < 256)        { int j = job;        in = w1;              outH = w1th0; R = ND; C = NF; by = j >> 5, bx = j & 31; }
        else if (job < 512)   { int j = job - 256;  in = w2;              outH = w2th0; R = NF; C = ND; by = j >> 3, bx = j & 7; }
        else if (job < 768)   { int j = job - 512;  in = w1 + (size_t)ND * NF; outH = w1th1; R = ND; C = NF; by = j >> 5, bx = j & 31; }
        else if (job < 1024)  { int j = job - 768;  in = w2 + (size_t)NF * ND; outH = w2th1; R = NF; C = ND; by = j >> 3, bx = j & 7; }
        else                  { int j = job - 1024; in = proj;            outH = pth; outL = ptl; R = 512; C = 1024; by = j >> 4, bx = j & 15; }

        int r0 = by * 64, c0 = bx * 64;
        __syncthreads();
        float v[16];
        const float* src = in + (size_t)(r0 + tr) * C + c0 + tc;
        *(float4*)(v)      = *(const float4*)(src);
        *(float4*)(v + 4)  = *(const float4*)(src + 4);
        *(float4*)(v + 8)  = *(const float4*)(src + 8);
        *(float4*)(v + 12) = *(const float4*)(src + 12);
        if (outL) {
            #pragma unroll
            for (int i = 0; i < 16; ++i) {
                unsigned short h = f2bf(v[i]);
                tH[(tc + i) * 72 + tr] = h;
                tL[(tc + i) * 72 + tr] = f2bf(v[i] - bf2f(h));
            }
        } else {
            #pragma unroll
            for (int i = 0; i < 16; ++i) tH[(tc + i) * 72 + tr] = f2bf(v[i]);
        }
        __syncthreads();
        size_t ob = (size_t)(c0 + tr) * R + r0 + tc;
        *(uint4*)(outH + ob)     = *(const uint4*)(&tH[tr * 72 + tc]);
        *(uint4*)(outH + ob + 8) = *(const uint4*)(&tH[tr * 72 + tc + 8]);
        if (outL) {
            *(uint4*)(outL + ob)     = *(const uint4*)(&tL[tr * 72 + tc]);
            *(uint4*)(outL + ob + 8) = *(const uint4*)(&tL[tr * 72 + tc + 8]);
        }
    }
}

// ---------------------------------------------------------------------------
// In-place split softmax: row of N fp32 -> [N hi bf16][N lo bf16].
// ---------------------------------------------------------------------------
__global__ __launch_bounds__(256) void softmax_ip(float* __restrict__ X, int N)
{
    float* row = X + (size_t)blockIdx.x * N;
    unsigned short* o = (unsigned short*)row;
    int t = threadIdx.x;
    int cnt = N >> 8;
    float v[4];
    float m = -1e30f;
    for (int i = 0; i < cnt; ++i) { v[i] = row[t + (i << 8)]; m = fmaxf(m, v[i]); }
    for (int sh = 32; sh; sh >>= 1) m = fmaxf(m, __shfl_xor(m, sh));
    __shared__ float lm[4];
    if ((t & 63) == 0) lm[t >> 6] = m;
    __syncthreads();
    m = fmaxf(fmaxf(lm[0], lm[1]), fmaxf(lm[2], lm[3]));
    float s = 0.0f;
    for (int i = 0; i < cnt; ++i) { v[i] = expf(v[i] - m); s += v[i]; }
    for (int sh = 32; sh; sh >>= 1) s += __shfl_xor(s, sh);
    __shared__ float ls[4];
    if ((t & 63) == 0) ls[t >> 6] = s;
    __syncthreads();
    s = ls[0] + ls[1] + ls[2] + ls[3];
    float inv = 1.0f / s;
    __syncthreads();
    for (int i = 0; i < cnt; ++i) {
        float y = v[i] * inv;
        unsigned short h = f2bf(y);
        int j = t + (i << 8);
        o[j] = h;
        o[N + j] = f2bf(y - bf2f(h));
    }
}

// ---------------------------------------------------------------------------
// LayerNorm rows of 512 fp32 -> split bf16 out.
// ---------------------------------------------------------------------------
__global__ __launch_bounds__(256) void layernorm_split(
    const float* __restrict__ X, const float* __restrict__ g, const float* __restrict__ b,
    unsigned short* __restrict__ ohi, unsigned short* __restrict__ olo)
{
    const float* row = X + (size_t)blockIdx.x * 512;
    size_t ob = (size_t)blockIdx.x * 512;
    int t = threadIdx.x;
    float x0 = row[t], x1 = row[t + 256];
    float s = x0 + x1, sq = x0 * x0 + x1 * x1;
    for (int o = 32; o; o >>= 1) { s += __shfl_xor(s, o); sq += __shfl_xor(sq, o); }
    __shared__ float ls[8];
    int w = t >> 6;
    if ((t & 63) == 0) { ls[w] = s; ls[4 + w] = sq; }
    __syncthreads();
    s = ls[0] + ls[1] + ls[2] + ls[3];
    sq = ls[4] + ls[5] + ls[6] + ls[7];
    float mu = s * (1.0f / 512.0f);
    float var = sq * (1.0f / 512.0f) - mu * mu;
    float inv = rsqrtf(var + 1e-5f);
    float y0 = (x0 - mu) * inv * g[t]       + b[t];
    float y1 = (x1 - mu) * inv * g[t + 256] + b[t + 256];
    unsigned short h0 = f2bf(y0), h1 = f2bf(y1);
    ohi[ob + t]       = h0;  olo[ob + t]       = f2bf(y0 - bf2f(h0));
    ohi[ob + t + 256] = h1;  olo[ob + t + 256] = f2bf(y1 - bf2f(h1));
}

// ---------------------------------------------------------------------------
// out[b,h] = dot(q[b,h,:], projT[h,:]) with hi+lo reconstruction
// ---------------------------------------------------------------------------
__global__ __launch_bounds__(256) void outproj3(
    const unsigned short* __restrict__ qhi, const unsigned short* __restrict__ qlo,
    const unsigned short* __restrict__ phi, const unsigned short* __restrict__ plo,
    float* __restrict__ out)
{
    int gw = blockIdx.x * 4 + (threadIdx.x >> 6);
    int lane = threadIdx.x & 63;
    int h = gw & 1023;
    uint4 qh = ((const uint4*)(qhi + (size_t)gw * 512))[lane];
    uint4 ql = ((const uint4*)(qlo + (size_t)gw * 512))[lane];
    uint4 ph = ((const uint4*)(phi + (size_t)h * 512))[lane];
    uint4 pl = ((const uint4*)(plo + (size_t)h * 512))[lane];
    unsigned short qhe[8], qle[8], phe[8], ple[8];
    *(uint4*)qhe = qh; *(uint4*)qle = ql; *(uint4*)phe = ph; *(uint4*)ple = pl;
    float s = 0.0f;
    #pragma unroll
    for (int i = 0; i < 8; ++i) {
        float q = bf2f(qhe[i]) + bf2f(qle[i]);
        float p = bf2f(phe[i]) + bf2f(ple[i]);
        s += q * p;
    }
    for (int o = 32; o; o >>= 1) s += __shfl_xor(s, o);
    if (lane == 0) out[gw] = s;
}

// ---------------------------------------------------------------------------
// launcher
// ---------------------------------------------------------------------------
extern "C" void kernel_launch(void* const* d_in, const int* in_sizes, int n_in,
                              void* d_out, int out_size, void* d_ws, size_t ws_size,
                              hipStream_t stream)
{
    (void)in_sizes; (void)n_in; (void)out_size; (void)ws_size;

    const float* x     = (const float*)d_in[0];
    const float* le    = (const float*)d_in[1];
    const float* proj  = (const float*)d_in[2];
    const float* WihF  = (const float*)d_in[3];
    const float* WhhF  = (const float*)d_in[4];
    const float* bihF  = (const float*)d_in[5];
    const float* bhhF  = (const float*)d_in[6];
    const float* WihB  = (const float*)d_in[7];
    const float* WhhB  = (const float*)d_in[8];
    const float* bihB  = (const float*)d_in[9];
    const float* bhhB  = (const float*)d_in[10];
    const float* w1    = (const float*)d_in[11];
    const float* b1    = (const float*)d_in[12];
    const float* w2    = (const float*)d_in[13];
    const float* b2    = (const float*)d_in[14];
    const float* lng   = (const float*)d_in[15];
    const float* lnb   = (const float*)d_in[16];
    float* out = (float*)d_out;
    float* ws  = (float*)d_ws;
    unsigned short* wsu = (unsigned short*)d_ws;

    const size_t MEG = 1048576;
    const size_t R0    = 0;              // 8M: pre (4096x2048) -> qtT hi (L1) -> lnsrc
    const size_t R1    = 8 * MEG;        // 8M: q2 hi
    const size_t AR    = 16 * MEG;       // 17M arena
    const size_t QHI   = 33 * MEG;
    const size_t QLO   = 37 * MEG;
    const size_t FHI   = 41 * MEG;
    const size_t FLO   = 42 * MEG;
    const size_t FTHI  = 43 * MEG;
    const size_t FTLO  = 44 * MEG;
    const size_t LEHI  = 45 * MEG;
    const size_t LELO  = LEHI  + MEG / 4;
    const size_t LETHI = LELO  + MEG / 4;
    const size_t LETLO = LETHI + MEG / 4;
    const size_t WIHH  = 46 * MEG;
    const size_t WIHL  = WIHH + MEG / 2;
    const size_t SYNC  = 47 * MEG;       // flags[32] + hg u64[8192]
    const size_t W1TH0 = SYNC  + MEG / 4;    // .5M fl each
    const size_t W1TH1 = W1TH0 + MEG / 2;
    const size_t W2TH0 = W1TH1 + MEG / 2;
    const size_t W2TH1 = W2TH0 + MEG / 2;
    const size_t PTH   = W2TH1 + MEG / 2;
    const size_t PTL   = PTH   + MEG / 4;
    const size_t BSUM  = PTL   + MEG / 4;

    float* pre    = ws + R0;             // (4096, 2048): [F 1024 | B 1024]
    float* lnsrc  = ws + R0;
    float* arena  = ws + AR;
    float* bsum   = ws + BSUM;
    int*   flags  = (int*)(ws + SYNC);
    unsigned long long* hg = (unsigned long long*)(ws + SYNC + 1024);
    unsigned short* qthi  = wsu + 2 * R0;                 // (L1 attn only)
    unsigned short* q2hi  = wsu + 2 * R1;                 // (16,1024,512) hi
    unsigned short* qhi   = wsu + 2 * QHI;
    unsigned short* qlo   = wsu + 2 * QLO;
    unsigned short* fhi   = wsu + 2 * FHI;
    unsigned short* flo   = wsu + 2 * FLO;
    unsigned short* fthi  = wsu + 2 * FTHI;
    unsigned short* ftlo  = wsu + 2 * FTLO;
    unsigned short* lehi  = wsu + 2 * LEHI;
    unsigned short* lelo  = wsu + 2 * LELO;
    unsigned short* lethi = wsu + 2 * LETHI;
    unsigned short* letlo = wsu + 2 * LETLO;
    unsigned short* wihh  = wsu + 2 * WIHH;
    unsigned short* wihl  = wsu + 2 * WIHL;
    unsigned short* w1th0 = wsu + 2 * W1TH0;
    unsigned short* w1th1 = wsu + 2 * W1TH1;
    unsigned short* w2th0 = wsu + 2 * W2TH0;
    unsigned short* w2th1 = wsu + 2 * W2TH1;
    unsigned short* pth   = wsu + 2 * PTH;
    unsigned short* ptl   = wsu + 2 * PTL;

    // ---- prep (feeds pre-GEMM)
    bias_sum_kernel<<<8, 256, 0, stream>>>(bihF, bhhF, bihB, bhhB, bsum);
    cvt_split<<<512, 256, 0, stream>>>(WihF, wihh, wihl);
    cvt_split<<<512, 256, 0, stream>>>(WihB, wihh + 524288, wihl + 524288);
    cvt_split<<<512, 256, 0, stream>>>(le, lehi, lelo);
    { dim3 g(512 / 64, 1024 / 64, 1);
      cvt_split_t<<<g, 256, 0, stream>>>(le, lethi, letlo, 1024, 512); }
    hipMemsetAsync(flags, 0, 32 * sizeof(int), stream);

    unsigned short* xhi = wsu + 2 * AR;
    unsigned short* xlo = wsu + 2 * (AR + MEG);
    cvt_split<<<2048, 256, 0, stream>>>(x, xhi, xlo);

    // ---- LSTM input projection (merged F|B, 3-pass): pre = x @ WihT + bsum
    gemm4(3, 0, 0, xhi, xlo, wihh, wihl, bsum, pre, nullptr, nullptr,
          NB * NS, 2048, ND, ND, ND, 0, 0, 0, 1, stream);

    // ---- FUSED: recurrence (32 blocks) + L0 score GEMM + weight/proj cvts
    float* wsc_l0 = arena;   // 1M fl (xhi/xlo dead after pre-GEMM)
    rec_fused<<<256, 256, 0, stream>>>(pre, WhhF, WhhB, hg, flags, fhi, flo,
                                       lehi, lelo, wsc_l0,
                                       w1, w2, w1th0, w2th0, w1th1, w2th1,
                                       proj, pth, ptl);
    { dim3 g(512 / 64, 256 / 64, 16);
      tcvt_bf16<<<g, 256, 0, stream>>>(fhi, fthi, 256, 512);
      tcvt_bf16<<<g, 256, 0, stream>>>(flo, ftlo, 256, 512); }

    // ---- layers
    for (int l = 0; l < 2; ++l) {
        const float* b1l = b1 + (size_t)l * NF;
        const float* b2l = b2 + (size_t)l * ND;
        const float* gl  = lng + (size_t)l * ND;
        const float* bl  = lnb + (size_t)l * ND;
        unsigned short* w1th = l ? w1th1 : w1th0;
        unsigned short* w2th = l ? w2th1 : w2th0;

        if (l == 0) {
            float* wsc = wsc_l0;
            unsigned short* wscu = (unsigned short*)wsc;
            unsigned short* q1hi = wsu + 2 * (AR + 1 * MEG);
            unsigned short* q1lo = wsu + 2 * (AR + 1 * MEG + MEG / 4);
            float* s2s = arena + 4 * MEG;
            unsigned short* s2u = (unsigned short*)s2s;

            softmax_ip<<<NH, 256, 0, stream>>>(wsc, NH);
            gemm4(1, 0, 1, wscu, nullptr, lethi, nullptr, nullptr, nullptr, q1hi, q1lo,
                  NH, ND, NH, 2 * NH, NH, 0, 0, 0, 1, stream);
            gemm4(3, 0, 0, q1hi, q1lo, fhi, flo, nullptr, s2s, nullptr, nullptr,
                  NH, NS, ND, ND, ND, 0, (long)NS * ND, (long)NH * NS, 16, stream);
            softmax_ip<<<NB * NH, 256, 0, stream>>>(s2s, NS);
            gemm4(1, 0, 2, s2u, nullptr, fthi, nullptr, nullptr, nullptr, q2hi, nullptr,
                  NH, ND, NS, 2 * NS, NS,
                  (long)2 * NH * NS, (long)ND * NS, (long)NH * ND, 16, stream);
        } else {
            { dim3 g(512 / 64, 1024 / 64, 16);
              tcvt_bf16<<<g, 256, 0, stream>>>(qhi, qthi, 1024, 512); }
            float* wsc = arena;
            unsigned short* wscu = (unsigned short*)wsc;
            unsigned short* q1hi = wsu + 2 * (AR + 8 * MEG);
            unsigned short* q1lo = wsu + 2 * (AR + 10 * MEG);
            float* s2s = arena + 12 * MEG;
            unsigned short* s2u = (unsigned short*)s2s;
            for (int g8 = 0; g8 < 2; ++g8) {
                size_t qo = (size_t)g8 * 8;
                gemm4(3, 0, 0, qhi + qo * NH * ND, qlo + qo * NH * ND,
                      qhi + qo * NH * ND, qlo + qo * NH * ND, nullptr, wsc, nullptr, nullptr,
                      NH, NH, ND, ND, ND,
                      (long)NH * ND, (long)NH * ND, (long)NH * NH, 8, stream);
                softmax_ip<<<8 * NH, 256, 0, stream>>>(wsc, NH);
                gemm4(1, 0, 1, wscu, nullptr, qthi + qo * ND * NH, nullptr,
                      nullptr, nullptr, q1hi, q1lo, NH, ND, NH, 2 * NH, NH,
                      (long)2 * NH * NH, (long)ND * NH, (long)NH * ND, 8, stream);
                gemm4(3, 0, 0, q1hi, q1lo, fhi + qo * NS * ND, flo + qo * NS * ND,
                      nullptr, s2s, nullptr, nullptr, NH, NS, ND, ND, ND,
                      (long)NH * ND, (long)NS * ND, (long)NH * NS, 8, stream);
                softmax_ip<<<8 * NH, 256, 0, stream>>>(s2s, NS);
                gemm4(1, 0, 2, s2u, nullptr, fthi + qo * ND * NS, nullptr,
                      nullptr, nullptr, q2hi + qo * NH * ND, nullptr,
                      NH, ND, NS, 2 * NS, NS,
                      (long)2 * NH * NS, (long)ND * NS, (long)NH * ND, 8, stream);
            }
        }

        // FFN (1-pass bf16): single 16384-row launches
        unsigned short* ffhi = wsu + 2 * AR;
        gemm4(1, 1, 2, q2hi, nullptr, w1th, nullptr, b1l, nullptr, ffhi, nullptr,
              16384, NF, ND, ND, ND, 0, 0, 0, 1, stream);
        gemm4(1, 0, 0, ffhi, nullptr, w2th, nullptr, b2l, lnsrc, nullptr, nullptr,
              16384, ND, NF, NF, NF, 0, 0, 0, 1, stream);
        layernorm_split<<<NB * NH, 256, 0, stream>>>(lnsrc, gl, bl, qhi, qlo);
    }

    // ---- final projection
    outproj3<<<4096, 256, 0, stream>>>(qhi, qlo, pth, ptl, out);
}

// Round 14
// 1501.881 us; speedup vs baseline: 2.1923x; 1.0054x over previous
//
#include <hip/hip_runtime.h>
#include <hip/hip_bf16.h>
#include <math.h>

// Problem dims
#define NB 16
#define NS 256
#define ND 512
#define NH 1024
#define NF 2048
#define NHID 256

typedef __attribute__((ext_vector_type(8))) short bf16x8;
typedef __attribute__((ext_vector_type(4))) float f32x4;

__device__ __forceinline__ unsigned short f2bf(float f) {
    unsigned u = __float_as_uint(f);
    unsigned r = u + 0x7fffu + ((u >> 16) & 1u);
    return (unsigned short)(r >> 16);
}
__device__ __forceinline__ float bf2f(unsigned short h) {
    return __uint_as_float(((unsigned)h) << 16);
}
__device__ __forceinline__ float sigmoid_fast(float x) {
    return 1.0f / (1.0f + __expf(-x));
}
__device__ __forceinline__ float tanh_fast(float x) {
    return 1.0f - 2.0f / (__expf(2.0f * x) + 1.0f);
}

// ---------------------------------------------------------------------------
// MFMA GEMM v4: C[M,N] = A[M,K] @ B[N,K]^T (+bias)(+gelu)
// PASSES=3 split hi/lo (~fp32); PASSES=1 bf16. OUT: 0 fp32, 1 split, 2 hi.
// ---------------------------------------------------------------------------
template<int PASSES, int ACT, int OUT>
__global__ __launch_bounds__(256) void sgemm4(
    const unsigned short* __restrict__ Ahi, const unsigned short* __restrict__ Alo,
    const unsigned short* __restrict__ Bhi, const unsigned short* __restrict__ Blo,
    const float* __restrict__ bias,
    float* __restrict__ C, unsigned short* __restrict__ Chi, unsigned short* __restrict__ Clo,
    int M, int N, int K, int lda, int ldb, long sA, long sB, long sC)
{
    __shared__ unsigned short Ah[128 * 32];
    __shared__ unsigned short Bh[128 * 32];
    __shared__ unsigned short Al[(PASSES == 3) ? 128 * 32 : 64];
    __shared__ unsigned short Bl[(PASSES == 3) ? 128 * 32 : 64];

    const int t = threadIdx.x;
    const int z = blockIdx.z;
    const int m0 = blockIdx.y * 128, n0 = blockIdx.x * 128;
    const int wid = t >> 6, lane = t & 63;
    const int wr = (wid >> 1) * 64, wc = (wid & 1) * 64;
    const int lr = lane & 15, lk = lane >> 4;
    const int rl = lane >> 2, sl = lane & 3;

    const unsigned short* pAh = Ahi + (size_t)z * sA;
    const unsigned short* pBh = Bhi + (size_t)z * sB;
    const unsigned short* pAl = (PASSES == 3) ? Alo + (size_t)z * sA : nullptr;
    const unsigned short* pBl = (PASSES == 3) ? Blo + (size_t)z * sB : nullptr;

    f32x4 acc[4][4];
    #pragma unroll
    for (int i = 0; i < 4; ++i)
        #pragma unroll
        for (int j = 0; j < 4; ++j) acc[i][j] = (f32x4){0.f, 0.f, 0.f, 0.f};

    for (int k0 = 0; k0 < K; k0 += 32) {
        #pragma unroll
        for (int e = 0; e < 2; ++e) {
            const int r = e * 64 + wid * 16 + rl;
            const size_t goA = (size_t)(m0 + r) * lda + k0 + sl * 8;
            const size_t goB = (size_t)(n0 + r) * ldb + k0 + sl * 8;
            const int lo = (e * 64 + wid * 16) * 32;
            __builtin_amdgcn_global_load_lds((const void*)(pAh + goA), (void*)&Ah[lo], 16, 0, 0);
            __builtin_amdgcn_global_load_lds((const void*)(pBh + goB), (void*)&Bh[lo], 16, 0, 0);
            if (PASSES == 3) {
                __builtin_amdgcn_global_load_lds((const void*)(pAl + goA), (void*)&Al[lo], 16, 0, 0);
                __builtin_amdgcn_global_load_lds((const void*)(pBl + goB), (void*)&Bl[lo], 16, 0, 0);
            }
        }
        __syncthreads();

        bf16x8 ah[4], bh[4], al[4], bl[4];
        #pragma unroll
        for (int mt = 0; mt < 4; ++mt) {
            int rf = wr + mt * 16 + lr;
            ah[mt] = *(const bf16x8*)&Ah[rf * 32 + lk * 8];
            if (PASSES == 3) al[mt] = *(const bf16x8*)&Al[rf * 32 + lk * 8];
        }
        #pragma unroll
        for (int nt = 0; nt < 4; ++nt) {
            int rf = wc + nt * 16 + lr;
            bh[nt] = *(const bf16x8*)&Bh[rf * 32 + lk * 8];
            if (PASSES == 3) bl[nt] = *(const bf16x8*)&Bl[rf * 32 + lk * 8];
        }
        #pragma unroll
        for (int mt = 0; mt < 4; ++mt)
            #pragma unroll
            for (int nt = 0; nt < 4; ++nt) {
                acc[mt][nt] = __builtin_amdgcn_mfma_f32_16x16x32_bf16(ah[mt], bh[nt], acc[mt][nt], 0, 0, 0);
                if (PASSES == 3) {
                    acc[mt][nt] = __builtin_amdgcn_mfma_f32_16x16x32_bf16(al[mt], bh[nt], acc[mt][nt], 0, 0, 0);
                    acc[mt][nt] = __builtin_amdgcn_mfma_f32_16x16x32_bf16(ah[mt], bl[nt], acc[mt][nt], 0, 0, 0);
                }
            }
        __syncthreads();
    }

    #pragma unroll
    for (int nt = 0; nt < 4; ++nt) {
        int col = n0 + wc + nt * 16 + lr;
        float bv = bias ? bias[col] : 0.0f;
        #pragma unroll
        for (int mt = 0; mt < 4; ++mt) {
            #pragma unroll
            for (int i = 0; i < 4; ++i) {
                int row = m0 + wr + mt * 16 + lk * 4 + i;
                float x = acc[mt][nt][i] + bv;
                if (ACT == 1) x = 0.5f * x * (1.0f + erff(x * 0.70710678118654752f));
                size_t oi = (size_t)z * sC + (size_t)row * N + col;
                if (OUT == 1) {
                    unsigned short h = f2bf(x);
                    Chi[oi] = h;
                    Clo[oi] = f2bf(x - bf2f(h));
                } else if (OUT == 2) {
                    Chi[oi] = f2bf(x);
                } else {
                    C[oi] = x;
                }
            }
        }
    }
}

static void gemm4(int passes, int act, int outm,
                  const unsigned short* Ahi, const unsigned short* Alo,
                  const unsigned short* Bhi, const unsigned short* Blo,
                  const float* bias, float* C, unsigned short* Chi, unsigned short* Clo,
                  int M, int N, int K, int lda, int ldb,
                  long sA, long sB, long sC, int Z, hipStream_t st)
{
    dim3 g(N / 128, M / 128, Z), b(256);
    if (passes == 3) {
        sgemm4<3, 0, 0><<<g, b, 0, st>>>(Ahi, Alo, Bhi, Blo, bias, C, Chi, Clo, M, N, K, lda, ldb, sA, sB, sC);
    } else if (outm == 1) {
        sgemm4<1, 0, 1><<<g, b, 0, st>>>(Ahi, Alo, Bhi, Blo, bias, C, Chi, Clo, M, N, K, lda, ldb, sA, sB, sC);
    } else if (outm == 2 && act == 1) {
        sgemm4<1, 1, 2><<<g, b, 0, st>>>(Ahi, Alo, Bhi, Blo, bias, C, Chi, Clo, M, N, K, lda, ldb, sA, sB, sC);
    } else if (outm == 2) {
        sgemm4<1, 0, 2><<<g, b, 0, st>>>(Ahi, Alo, Bhi, Blo, bias, C, Chi, Clo, M, N, K, lda, ldb, sA, sB, sC);
    } else {
        sgemm4<1, 0, 0><<<g, b, 0, st>>>(Ahi, Alo, Bhi, Blo, bias, C, Chi, Clo, M, N, K, lda, ldb, sA, sB, sC);
    }
}

// ---------------------------------------------------------------------------
// FUSED FFN2 + bias + LayerNorm + split output.
// C row-block per workgroup: tile M=64 x N=512 (full LN row in-block).
// A = ffhi bf16 (16384 x 2048); B = w2th bf16 (512 x 2048); out qhi/qlo.
// Same BK=32 ascending K loop as sgemm4 -> identical GEMM accumulation.
// grid = 256 blocks x 256 thr (4 waves; wave w owns cols w*128..+128).
// ---------------------------------------------------------------------------
__global__ __launch_bounds__(256) void ffn2_ln(
    const unsigned short* __restrict__ A, const unsigned short* __restrict__ B,
    const float* __restrict__ bias, const float* __restrict__ g, const float* __restrict__ bb,
    unsigned short* __restrict__ Ohi, unsigned short* __restrict__ Olo)
{
    __shared__ unsigned short Ah[64 * 32];       // 4KB
    __shared__ unsigned short Bh[512 * 32];      // 32KB
    __shared__ float stats[64][4][2];            // 2KB

    const int t = threadIdx.x;
    const int m0 = blockIdx.x * 64;
    const int wid = t >> 6, lane = t & 63;
    const int lr = lane & 15, lk = lane >> 4;
    const int wc = wid * 128;
    const int rl = lane >> 2, sl = lane & 3;

    f32x4 acc[4][8];
    #pragma unroll
    for (int i = 0; i < 4; ++i)
        #pragma unroll
        for (int j = 0; j < 8; ++j) acc[i][j] = (f32x4){0.f, 0.f, 0.f, 0.f};

    for (int k0 = 0; k0 < NF; k0 += 32) {
        // stage A (64 rows): wave wid covers rows wid*16..+16
        __builtin_amdgcn_global_load_lds(
            (const void*)(A + (size_t)(m0 + wid * 16 + rl) * NF + k0 + sl * 8),
            (void*)&Ah[(wid * 16) * 32], 16, 0, 0);
        // stage B (512 rows): 8 x (4 waves x 16 rows)
        #pragma unroll
        for (int e = 0; e < 8; ++e) {
            int r = e * 64 + wid * 16 + rl;
            __builtin_amdgcn_global_load_lds(
                (const void*)(B + (size_t)r * NF + k0 + sl * 8),
                (void*)&Bh[(e * 64 + wid * 16) * 32], 16, 0, 0);
        }
        __syncthreads();

        bf16x8 af[4], bf[8];
        #pragma unroll
        for (int mt = 0; mt < 4; ++mt)
            af[mt] = *(const bf16x8*)&Ah[(mt * 16 + lr) * 32 + lk * 8];
        #pragma unroll
        for (int nt = 0; nt < 8; ++nt)
            bf[nt] = *(const bf16x8*)&Bh[(wc + nt * 16 + lr) * 32 + lk * 8];
        #pragma unroll
        for (int mt = 0; mt < 4; ++mt)
            #pragma unroll
            for (int nt = 0; nt < 8; ++nt)
                acc[mt][nt] = __builtin_amdgcn_mfma_f32_16x16x32_bf16(af[mt], bf[nt], acc[mt][nt], 0, 0, 0);
        __syncthreads();
    }

    // x = acc + bias (C layout: row = mt*16 + lk*4 + i, col = wc + nt*16 + lr)
    float bv[8];
    #pragma unroll
    for (int nt = 0; nt < 8; ++nt) bv[nt] = bias[wc + nt * 16 + lr];

    float psum[4][4], psq[4][4];
    #pragma unroll
    for (int mt = 0; mt < 4; ++mt)
        #pragma unroll
        for (int i = 0; i < 4; ++i) {
            float s = 0.f, q = 0.f;
            #pragma unroll
            for (int nt = 0; nt < 8; ++nt) {
                float x = acc[mt][nt][i] + bv[nt];
                acc[mt][nt][i] = x;
                s += x;
                q += x * x;
            }
            psum[mt][i] = s;
            psq[mt][i] = q;
        }
    // reduce across the 16 lr-lanes (lane bits 0..3)
    #pragma unroll
    for (int o = 1; o <= 8; o <<= 1)
        #pragma unroll
        for (int mt = 0; mt < 4; ++mt)
            #pragma unroll
            for (int i = 0; i < 4; ++i) {
                psum[mt][i] += __shfl_xor(psum[mt][i], o);
                psq[mt][i]  += __shfl_xor(psq[mt][i], o);
            }
    if (lr == 0) {
        #pragma unroll
        for (int mt = 0; mt < 4; ++mt)
            #pragma unroll
            for (int i = 0; i < 4; ++i) {
                int r = mt * 16 + lk * 4 + i;
                stats[r][wid][0] = psum[mt][i];
                stats[r][wid][1] = psq[mt][i];
            }
    }
    __syncthreads();

    float gv[8], betav[8];
    #pragma unroll
    for (int nt = 0; nt < 8; ++nt) {
        gv[nt]    = g[wc + nt * 16 + lr];
        betav[nt] = bb[wc + nt * 16 + lr];
    }
    #pragma unroll
    for (int mt = 0; mt < 4; ++mt)
        #pragma unroll
        for (int i = 0; i < 4; ++i) {
            int r = mt * 16 + lk * 4 + i;
            float s = stats[r][0][0] + stats[r][1][0] + stats[r][2][0] + stats[r][3][0];
            float q = stats[r][0][1] + stats[r][1][1] + stats[r][2][1] + stats[r][3][1];
            float mu = s * (1.0f / 512.0f);
            float var = q * (1.0f / 512.0f) - mu * mu;
            float inv = rsqrtf(var + 1e-5f);
            #pragma unroll
            for (int nt = 0; nt < 8; ++nt) {
                float y = (acc[mt][nt][i] - mu) * inv * gv[nt] + betav[nt];
                size_t oi = (size_t)(m0 + r) * 512 + wc + nt * 16 + lr;
                unsigned short h = f2bf(y);
                Ohi[oi] = h;
                Olo[oi] = f2bf(y - bf2f(h));
            }
        }
}

// ---------------------------------------------------------------------------
// fp32 -> split bf16 hi/lo (n multiple of 1024)
// ---------------------------------------------------------------------------
__global__ __launch_bounds__(256) void cvt_split(const float* __restrict__ in,
                                                 unsigned short* __restrict__ hi,
                                                 unsigned short* __restrict__ lo)
{
    size_t i = ((size_t)blockIdx.x * 256 + threadIdx.x) * 4;
    float4 v = *(const float4*)(in + i);
    ushort4 h, l;
    h.x = f2bf(v.x); l.x = f2bf(v.x - bf2f(h.x));
    h.y = f2bf(v.y); l.y = f2bf(v.y - bf2f(h.y));
    h.z = f2bf(v.z); l.z = f2bf(v.z - bf2f(h.z));
    h.w = f2bf(v.w); l.w = f2bf(v.w - bf2f(h.w));
    *(ushort4*)(hi + i) = h;
    *(ushort4*)(lo + i) = l;
}

// ---------------------------------------------------------------------------
// fp32 (R,C) -> split bf16 hi/lo TRANSPOSED (C,R). R,C mult of 64.
// ---------------------------------------------------------------------------
__global__ __launch_bounds__(256) void cvt_split_t(const float* __restrict__ in,
                                                   unsigned short* __restrict__ hiT,
                                                   unsigned short* __restrict__ loT,
                                                   int R, int C)
{
    __shared__ unsigned short tileH[64 * 72];
    __shared__ unsigned short tileL[64 * 72];
    int r0 = blockIdx.y * 64, c0 = blockIdx.x * 64;
    int t = threadIdx.x;
    int tr = t >> 2, tc = (t & 3) * 16;

    float v[16];
    const float* src = in + (size_t)(r0 + tr) * C + c0 + tc;
    *(float4*)(v)      = *(const float4*)(src);
    *(float4*)(v + 4)  = *(const float4*)(src + 4);
    *(float4*)(v + 8)  = *(const float4*)(src + 8);
    *(float4*)(v + 12) = *(const float4*)(src + 12);
    #pragma unroll
    for (int i = 0; i < 16; ++i) {
        unsigned short h = f2bf(v[i]);
        tileH[(tc + i) * 72 + tr] = h;
        tileL[(tc + i) * 72 + tr] = f2bf(v[i] - bf2f(h));
    }
    __syncthreads();

    size_t ob = (size_t)(c0 + tr) * R + r0 + tc;
    *(uint4*)(hiT + ob)     = *(const uint4*)(&tileH[tr * 72 + tc]);
    *(uint4*)(hiT + ob + 8) = *(const uint4*)(&tileH[tr * 72 + tc + 8]);
    *(uint4*)(loT + ob)     = *(const uint4*)(&tileL[tr * 72 + tc]);
    *(uint4*)(loT + ob + 8) = *(const uint4*)(&tileL[tr * 72 + tc + 8]);
}

// ---------------------------------------------------------------------------
// bf16 (R,C) -> (C,R) transpose, z-batched. R,C multiples of 64.
// ---------------------------------------------------------------------------
__global__ __launch_bounds__(256) void tcvt_bf16(const unsigned short* __restrict__ in,
                                                 unsigned short* __restrict__ out,
                                                 int R, int C)
{
    __shared__ unsigned short tile[64 * 72];
    int z = blockIdx.z;
    in += (size_t)z * R * C;
    out += (size_t)z * R * C;
    int r0 = blockIdx.y * 64, c0 = blockIdx.x * 64;
    int t = threadIdx.x;
    int tr = t >> 2, tc = (t & 3) * 16;

    uint4 q0 = *(const uint4*)(in + (size_t)(r0 + tr) * C + c0 + tc);
    uint4 q1 = *(const uint4*)(in + (size_t)(r0 + tr) * C + c0 + tc + 8);
    unsigned short e[16];
    *(uint4*)(e) = q0;
    *(uint4*)(e + 8) = q1;
    #pragma unroll
    for (int i = 0; i < 16; ++i) tile[(tc + i) * 72 + tr] = e[i];
    __syncthreads();

    uint4 o0 = *(const uint4*)(&tile[tr * 72 + tc]);
    uint4 o1 = *(const uint4*)(&tile[tr * 72 + tc + 8]);
    *(uint4*)(out + (size_t)(c0 + tr) * R + r0 + tc) = o0;
    *(uint4*)(out + (size_t)(c0 + tr) * R + r0 + tc + 8) = o1;
}

// ---------------------------------------------------------------------------
// bias combine
// ---------------------------------------------------------------------------
__global__ __launch_bounds__(256) void bias_sum_kernel(
    const float* bihF, const float* bhhF, const float* bihB, const float* bhhB,
    float* out)
{
    int i = blockIdx.x * 256 + threadIdx.x;
    if (i < 1024) out[i] = bihF[i] + bhhF[i];
    else out[i] = bihB[i - 1024] + bhhB[i - 1024];
}

// ---------------------------------------------------------------------------
// FUSED rec + helpers (unchanged from round 13; rec path identical).
// ---------------------------------------------------------------------------
__global__ __launch_bounds__(256) void rec_fused(
    const float* __restrict__ pre,
    const float* __restrict__ WhhF, const float* __restrict__ WhhB,
    unsigned long long* __restrict__ hg, int* __restrict__ flags,
    unsigned short* __restrict__ fhi, unsigned short* __restrict__ flo,
    const unsigned short* __restrict__ lehi, const unsigned short* __restrict__ lelo,
    float* __restrict__ wsc,
    const float* __restrict__ w1, const float* __restrict__ w2,
    unsigned short* __restrict__ w1th0, unsigned short* __restrict__ w2th0,
    unsigned short* __restrict__ w1th1, unsigned short* __restrict__ w2th1,
    const float* __restrict__ proj,
    unsigned short* __restrict__ pth, unsigned short* __restrict__ ptl)
{
    __shared__ unsigned short hh[16 * 264];
    __shared__ unsigned short hl[16 * 264];
    __shared__ float gx[4][16][17];
    __shared__ unsigned short gAh[128 * 32];
    __shared__ unsigned short gAl[128 * 32];
    __shared__ unsigned short gBh[128 * 32];
    __shared__ unsigned short gBl[128 * 32];
    __shared__ unsigned short tH[64 * 72];
    __shared__ unsigned short tL[64 * 72];

    const int tid = threadIdx.x;

    if (blockIdx.x < 32) {
        const int bid = blockIdx.x;
        const int dir = bid >> 4, slice = bid & 15;
        const float* Whh = dir ? WhhB : WhhF;
        const int wv = tid >> 6;
        const int lane = tid & 63;
        const int lr = lane & 15;
        const int lk = lane >> 4;
        const int eb = tid >> 4;
        const int eu = tid & 15;

        bf16x8 wfh[8], wfl[8];
        {
            const float* wrow = Whh + (size_t)(wv * 256 + slice * 16 + lr) * 256 + lk * 8;
            #pragma unroll
            for (int kt = 0; kt < 8; ++kt) {
                float4 a = *(const float4*)(wrow + kt * 32);
                float4 b = *(const float4*)(wrow + kt * 32 + 4);
                float v[8] = {a.x, a.y, a.z, a.w, b.x, b.y, b.z, b.w};
                unsigned short hhv[8], llv[8];
                #pragma unroll
                for (int i = 0; i < 8; ++i) {
                    unsigned short h = f2bf(v[i]);
                    hhv[i] = h;
                    llv[i] = f2bf(v[i] - bf2f(h));
                }
                wfh[kt] = *(bf16x8*)hhv;
                wfl[kt] = *(bf16x8*)llv;
            }
        }
        for (int i = tid; i < 16 * 264; i += 256) { hh[i] = 0; hl[i] = 0; }

        float c = 0.0f;
        __syncthreads();

        for (int si = 0; si < NS; ++si) {
            const int s = dir ? (NS - 1 - si) : si;
            const float* pp = pre + ((size_t)(eb * NS + s)) * 2048 + dir * 1024 + slice * 16 + eu;
            float pi = pp[0], pf = pp[256], pg = pp[512], po = pp[768];

            if (si > 0) {
                if (tid < 16) {
                    while (__hip_atomic_load(&flags[dir * 16 + tid], __ATOMIC_RELAXED,
                                             __HIP_MEMORY_SCOPE_AGENT) < si) {
                        __builtin_amdgcn_s_sleep(1);
                    }
                }
                __syncthreads();
                const unsigned long long* src =
                    hg + (size_t)(((si - 1) & 1) * 2 + dir) * 2048;
                const int b2 = tid >> 4, pb = (tid & 15) * 8;
                unsigned short hbuf[16], lbuf[16];
                #pragma unroll
                for (int j = 0; j < 8; ++j) {
                    unsigned long long v = __hip_atomic_load(
                        &src[b2 * 128 + pb + j], __ATOMIC_RELAXED,
                        __HIP_MEMORY_SCOPE_AGENT);
                    hbuf[2 * j]     = (unsigned short)(v & 0xffff);
                    lbuf[2 * j]     = (unsigned short)((v >> 16) & 0xffff);
                    hbuf[2 * j + 1] = (unsigned short)((v >> 32) & 0xffff);
                    lbuf[2 * j + 1] = (unsigned short)(v >> 48);
                }
                char* dh = (char*)hh + b2 * 528 + (tid & 15) * 32;
                char* dl = (char*)hl + b2 * 528 + (tid & 15) * 32;
                *(uint4*)dh        = *(uint4*)(hbuf);
                *(uint4*)(dh + 16) = *(uint4*)(hbuf + 8);
                *(uint4*)dl        = *(uint4*)(lbuf);
                *(uint4*)(dl + 16) = *(uint4*)(lbuf + 8);
                __syncthreads();
            }

            f32x4 acc = (f32x4){0.f, 0.f, 0.f, 0.f};
            #pragma unroll
            for (int kt = 0; kt < 8; ++kt) {
                const char* hp = (const char*)hh + lr * 528 + kt * 64 + lk * 16;
                const char* lp = (const char*)hl + lr * 528 + kt * 64 + lk * 16;
                bf16x8 ah = *(const bf16x8*)hp;
                bf16x8 al = *(const bf16x8*)lp;
                acc = __builtin_amdgcn_mfma_f32_16x16x32_bf16(ah, wfh[kt], acc, 0, 0, 0);
                acc = __builtin_amdgcn_mfma_f32_16x16x32_bf16(al, wfh[kt], acc, 0, 0, 0);
                acc = __builtin_amdgcn_mfma_f32_16x16x32_bf16(ah, wfl[kt], acc, 0, 0, 0);
            }
            #pragma unroll
            for (int i = 0; i < 4; ++i) gx[wv][lk * 4 + i][lr] = acc[i];
            __syncthreads();

            float ai = gx[0][eb][eu] + pi;
            float af = gx[1][eb][eu] + pf;
            float ag = gx[2][eb][eu] + pg;
            float ao = gx[3][eb][eu] + po;
            float gi = sigmoid_fast(ai);
            float gf = sigmoid_fast(af);
            float gg = tanh_fast(ag);
            float go = sigmoid_fast(ao);
            c = gf * c + gi * gg;
            float h = go * tanh_fast(c);

            unsigned short h16 = f2bf(h);
            unsigned short l16 = f2bf(h - bf2f(h16));
            unsigned my = (unsigned)h16 | ((unsigned)l16 << 16);
            unsigned oth = __shfl_xor(my, 1);
            if ((eu & 1) == 0) {
                unsigned long long v = (unsigned long long)my |
                                       ((unsigned long long)oth << 32);
                unsigned long long* dst =
                    hg + (size_t)((si & 1) * 2 + dir) * 2048;
                __hip_atomic_store(&dst[eb * 128 + slice * 8 + (eu >> 1)], v,
                                   __ATOMIC_RELAXED, __HIP_MEMORY_SCOPE_AGENT);
            }
            size_t oi = ((size_t)(eb * NS + s)) * 512 + dir * 256 + slice * 16 + eu;
            fhi[oi] = h16;
            flo[oi] = l16;

            asm volatile("s_waitcnt vmcnt(0)" ::: "memory");
            __syncthreads();
            if (tid == 0)
                __hip_atomic_store(&flags[bid], si + 1, __ATOMIC_RELAXED,
                                   __HIP_MEMORY_SCOPE_AGENT);
        }
        return;
    }

    // ================= HELPERS =================
    const int hid = blockIdx.x - 32;
    const int lane = tid & 63;
    const int wid = tid >> 6;
    const int lr = lane & 15, lk = lane >> 4;

    if (hid < 64) {
        const int m0 = (hid >> 3) * 128, n0 = (hid & 7) * 128;
        const int wr = (wid >> 1) * 64, wc = (wid & 1) * 64;
        const int sr = tid >> 1, sc = (tid & 1) * 16;

        f32x4 acc[4][4];
        #pragma unroll
        for (int i = 0; i < 4; ++i)
            #pragma unroll
            for (int j = 0; j < 4; ++j) acc[i][j] = (f32x4){0.f, 0.f, 0.f, 0.f};

        for (int k0 = 0; k0 < ND; k0 += 32) {
            {
                size_t oa = (size_t)(m0 + sr) * ND + k0 + sc;
                size_t ob = (size_t)(n0 + sr) * ND + k0 + sc;
                *(uint4*)&gAh[sr * 32 + sc]     = *(const uint4*)(lehi + oa);
                *(uint4*)&gAh[sr * 32 + sc + 8] = *(const uint4*)(lehi + oa + 8);
                *(uint4*)&gAl[sr * 32 + sc]     = *(const uint4*)(lelo + oa);
                *(uint4*)&gAl[sr * 32 + sc + 8] = *(const uint4*)(lelo + oa + 8);
                *(uint4*)&gBh[sr * 32 + sc]     = *(const uint4*)(lehi + ob);
                *(uint4*)&gBh[sr * 32 + sc + 8] = *(const uint4*)(lehi + ob + 8);
                *(uint4*)&gBl[sr * 32 + sc]     = *(const uint4*)(lelo + ob);
                *(uint4*)&gBl[sr * 32 + sc + 8] = *(const uint4*)(lelo + ob + 8);
            }
            __syncthreads();

            bf16x8 ah[4], al[4], bh[4], bl[4];
            #pragma unroll
            for (int mt = 0; mt < 4; ++mt) {
                int rf = wr + mt * 16 + lr;
                ah[mt] = *(const bf16x8*)&gAh[rf * 32 + lk * 8];
                al[mt] = *(const bf16x8*)&gAl[rf * 32 + lk * 8];
            }
            #pragma unroll
            for (int nt = 0; nt < 4; ++nt) {
                int rf = wc + nt * 16 + lr;
                bh[nt] = *(const bf16x8*)&gBh[rf * 32 + lk * 8];
                bl[nt] = *(const bf16x8*)&gBl[rf * 32 + lk * 8];
            }
            #pragma unroll
            for (int mt = 0; mt < 4; ++mt)
                #pragma unroll
                for (int nt = 0; nt < 4; ++nt) {
                    acc[mt][nt] = __builtin_amdgcn_mfma_f32_16x16x32_bf16(ah[mt], bh[nt], acc[mt][nt], 0, 0, 0);
                    acc[mt][nt] = __builtin_amdgcn_mfma_f32_16x16x32_bf16(al[mt], bh[nt], acc[mt][nt], 0, 0, 0);
                    acc[mt][nt] = __builtin_amdgcn_mfma_f32_16x16x32_bf16(ah[mt], bl[nt], acc[mt][nt], 0, 0, 0);
                }
            __syncthreads();
        }
        const int wr2 = (wid >> 1) * 64, wc2 = (wid & 1) * 64;
        #pragma unroll
        for (int nt = 0; nt < 4; ++nt) {
            int col = n0 + wc2 + nt * 16 + lr;
            #pragma unroll
            for (int mt = 0; mt < 4; ++mt)
                #pragma unroll
                for (int i = 0; i < 4; ++i) {
                    int row = m0 + wr2 + mt * 16 + lk * 4 + i;
                    wsc[(size_t)row * NH + col] = acc[mt][nt][i];
                }
        }
    }

    const int tr = tid >> 2, tc = (tid & 3) * 16;
    for (int job = hid; job < 1152; job += 224) {
        const float* in;
        unsigned short* outH;
        unsigned short* outL = nullptr;
        int R, C, by, bx;
        if (job < 256)        { int j = job;        in = w1;              outH = w1th0; R = ND; C = NF; by = j >> 5, bx = j & 31; }
        else if (job < 512)   { int j = job - 256;  in = w2;              outH = w2th0; R = NF; C = ND; by = j >> 3, bx = j & 7; }
        else if (job < 768)   { int j = job - 512;  in = w1 + (size_t)ND * NF; outH = w1th1; R = ND; C = NF; by = j >> 5, bx = j & 31; }
        else if (job < 1024)  { int j = job - 768;  in = w2 + (size_t)NF * ND; outH = w2th1; R = NF; C = ND; by = j >> 3, bx = j & 7; }
        else                  { int j = job - 1024; in = proj;            outH = pth; outL = ptl; R = 512; C = 1024; by = j >> 4, bx = j & 15; }

        int r0 = by * 64, c0 = bx * 64;
        __syncthreads();
        float v[16];
        const float* src = in + (size_t)(r0 + tr) * C + c0 + tc;
        *(float4*)(v)      = *(const float4*)(src);
        *(float4*)(v + 4)  = *(const float4*)(src + 4);
        *(float4*)(v + 8)  = *(const float4*)(src + 8);
        *(float4*)(v + 12) = *(const float4*)(src + 12);
        if (outL) {
            #pragma unroll
            for (int i = 0; i < 16; ++i) {
                unsigned short h = f2bf(v[i]);
                tH[(tc + i) * 72 + tr] = h;
                tL[(tc + i) * 72 + tr] = f2bf(v[i] - bf2f(h));
            }
        } else {
            #pragma unroll
            for (int i = 0; i < 16; ++i) tH[(tc + i) * 72 + tr] = f2bf(v[i]);
        }
        __syncthreads();
        size_t ob = (size_t)(c0 + tr) * R + r0 + tc;
        *(uint4*)(outH + ob)     = *(const uint4*)(&tH[tr * 72 + tc]);
        *(uint4*)(outH + ob + 8) = *(const uint4*)(&tH[tr * 72 + tc + 8]);
        if (outL) {
            *(uint4*)(outL + ob)     = *(const uint4*)(&tL[tr * 72 + tc]);
            *(uint4*)(outL + ob + 8) = *(const uint4*)(&tL[tr * 72 + tc + 8]);
        }
    }
}

// ---------------------------------------------------------------------------
// FUSED post-rec: feature transposes (fhi/flo -> fthi/ftlo) + L0 wsc softmax.
// grid = 2048: blocks 0..1023 = transpose tiles (512 hi + 512 lo);
// blocks 1024..2047 = softmax rows of wsc (N=1024, in-place split).
// All jobs independent; inputs ready when kernel starts.
// ---------------------------------------------------------------------------
__global__ __launch_bounds__(256) void post_rec(
    const unsigned short* __restrict__ fhi, const unsigned short* __restrict__ flo,
    unsigned short* __restrict__ fthi, unsigned short* __restrict__ ftlo,
    float* __restrict__ wsc)
{
    __shared__ unsigned short tile[64 * 72];
    __shared__ float lm[4];
    __shared__ float ls[4];
    const int t = threadIdx.x;

    if (blockIdx.x < 1024) {
        int job = blockIdx.x;
        const unsigned short* in;
        unsigned short* out;
        if (job < 512) { in = fhi; out = fthi; } else { in = flo; out = ftlo; job -= 512; }
        const int R = 256, C = 512;
        int z = job >> 5, jj = job & 31;          // 32 tiles per z: 8 bx x 4 by
        int bx = jj & 7, by = jj >> 3;
        in  += (size_t)z * R * C;
        out += (size_t)z * R * C;
        int r0 = by * 64, c0 = bx * 64;
        int tr = t >> 2, tc = (t & 3) * 16;

        uint4 q0 = *(const uint4*)(in + (size_t)(r0 + tr) * C + c0 + tc);
        uint4 q1 = *(const uint4*)(in + (size_t)(r0 + tr) * C + c0 + tc + 8);
        unsigned short e[16];
        *(uint4*)(e) = q0;
        *(uint4*)(e + 8) = q1;
        #pragma unroll
        for (int i = 0; i < 16; ++i) tile[(tc + i) * 72 + tr] = e[i];
        __syncthreads();

        *(uint4*)(out + (size_t)(c0 + tr) * R + r0 + tc)     = *(const uint4*)(&tile[tr * 72 + tc]);
        *(uint4*)(out + (size_t)(c0 + tr) * R + r0 + tc + 8) = *(const uint4*)(&tile[tr * 72 + tc + 8]);
        return;
    }

    // softmax row (N=1024), identical math to softmax_ip
    const int N = 1024;
    float* row = wsc + (size_t)(blockIdx.x - 1024) * N;
    unsigned short* o = (unsigned short*)row;
    float v[4];
    float m = -1e30f;
    #pragma unroll
    for (int i = 0; i < 4; ++i) { v[i] = row[t + (i << 8)]; m = fmaxf(m, v[i]); }
    for (int sh = 32; sh; sh >>= 1) m = fmaxf(m, __shfl_xor(m, sh));
    if ((t & 63) == 0) lm[t >> 6] = m;
    __syncthreads();
    m = fmaxf(fmaxf(lm[0], lm[1]), fmaxf(lm[2], lm[3]));
    float s = 0.0f;
    #pragma unroll
    for (int i = 0; i < 4; ++i) { v[i] = expf(v[i] - m); s += v[i]; }
    for (int sh = 32; sh; sh >>= 1) s += __shfl_xor(s, sh);
    if ((t & 63) == 0) ls[t >> 6] = s;
    __syncthreads();
    s = ls[0] + ls[1] + ls[2] + ls[3];
    float inv = 1.0f / s;
    __syncthreads();
    #pragma unroll
    for (int i = 0; i < 4; ++i) {
        float y = v[i] * inv;
        unsigned short h = f2bf(y);
        int j = t + (i << 8);
        o[j] = h;
        o[N + j] = f2bf(y - bf2f(h));
    }
}

// ---------------------------------------------------------------------------
// In-place split softmax (still used for s2s and L1 wsc)
// ---------------------------------------------------------------------------
__global__ __launch_bounds__(256) void softmax_ip(float* __restrict__ X, int N)
{
    float* row = X + (size_t)blockIdx.x * N;
    unsigned short* o = (unsigned short*)row;
    int t = threadIdx.x;
    int cnt = N >> 8;
    float v[4];
    float m = -1e30f;
    for (int i = 0; i < cnt; ++i) { v[i] = row[t + (i << 8)]; m = fmaxf(m, v[i]); }
    for (int sh = 32; sh; sh >>= 1) m = fmaxf(m, __shfl_xor(m, sh));
    __shared__ float lm[4];
    if ((t & 63) == 0) lm[t >> 6] = m;
    __syncthreads();
    m = fmaxf(fmaxf(lm[0], lm[1]), fmaxf(lm[2], lm[3]));
    float s = 0.0f;
    for (int i = 0; i < cnt; ++i) { v[i] = expf(v[i] - m); s += v[i]; }
    for (int sh = 32; sh; sh >>= 1) s += __shfl_xor(s, sh);
    __shared__ float ls[4];
    if ((t & 63) == 0) ls[t >> 6] = s;
    __syncthreads();
    s = ls[0] + ls[1] + ls[2] + ls[3];
    float inv = 1.0f / s;
    __syncthreads();
    for (int i = 0; i < cnt; ++i) {
        float y = v[i] * inv;
        unsigned short h = f2bf(y);
        int j = t + (i << 8);
        o[j] = h;
        o[N + j] = f2bf(y - bf2f(h));
    }
}

// ---------------------------------------------------------------------------
// out[b,h] = dot(q[b,h,:], projT[h,:]) with hi+lo reconstruction
// ---------------------------------------------------------------------------
__global__ __launch_bounds__(256) void outproj3(
    const unsigned short* __restrict__ qhi, const unsigned short* __restrict__ qlo,
    const unsigned short* __restrict__ phi, const unsigned short* __restrict__ plo,
    float* __restrict__ out)
{
    int gw = blockIdx.x * 4 + (threadIdx.x >> 6);
    int lane = threadIdx.x & 63;
    int h = gw & 1023;
    uint4 qh = ((const uint4*)(qhi + (size_t)gw * 512))[lane];
    uint4 ql = ((const uint4*)(qlo + (size_t)gw * 512))[lane];
    uint4 ph = ((const uint4*)(phi + (size_t)h * 512))[lane];
    uint4 pl = ((const uint4*)(plo + (size_t)h * 512))[lane];
    unsigned short qhe[8], qle[8], phe[8], ple[8];
    *(uint4*)qhe = qh; *(uint4*)qle = ql; *(uint4*)phe = ph; *(uint4*)ple = pl;
    float s = 0.0f;
    #pragma unroll
    for (int i = 0; i < 8; ++i) {
        float q = bf2f(qhe[i]) + bf2f(qle[i]);
        float p = bf2f(phe[i]) + bf2f(ple[i]);
        s += q * p;
    }
    for (int o = 32; o; o >>= 1) s += __shfl_xor(s, o);
    if (lane == 0) out[gw] = s;
}

// ---------------------------------------------------------------------------
// launcher
// ---------------------------------------------------------------------------
extern "C" void kernel_launch(void* const* d_in, const int* in_sizes, int n_in,
                              void* d_out, int out_size, void* d_ws, size_t ws_size,
                              hipStream_t stream)
{
    (void)in_sizes; (void)n_in; (void)out_size; (void)ws_size;

    const float* x     = (const float*)d_in[0];
    const float* le    = (const float*)d_in[1];
    const float* proj  = (const float*)d_in[2];
    const float* WihF  = (const float*)d_in[3];
    const float* WhhF  = (const float*)d_in[4];
    const float* bihF  = (const float*)d_in[5];
    const float* bhhF  = (const float*)d_in[6];
    const float* WihB  = (const float*)d_in[7];
    const float* WhhB  = (const float*)d_in[8];
    const float* bihB  = (const float*)d_in[9];
    const float* bhhB  = (const float*)d_in[10];
    const float* w1    = (const float*)d_in[11];
    const float* b1    = (const float*)d_in[12];
    const float* w2    = (const float*)d_in[13];
    const float* b2    = (const float*)d_in[14];
    const float* lng   = (const float*)d_in[15];
    const float* lnb   = (const float*)d_in[16];
    float* out = (float*)d_out;
    float* ws  = (float*)d_ws;
    unsigned short* wsu = (unsigned short*)d_ws;

    const size_t MEG = 1048576;
    const size_t R0    = 0;              // 8M: pre (4096x2048) -> qtT hi (L1)
    const size_t R1    = 8 * MEG;        // 8M: q2 hi
    const size_t AR    = 16 * MEG;       // 17M arena
    const size_t QHI   = 33 * MEG;
    const size_t QLO   = 37 * MEG;
    const size_t FHI   = 41 * MEG;
    const size_t FLO   = 42 * MEG;
    const size_t FTHI  = 43 * MEG;
    const size_t FTLO  = 44 * MEG;
    const size_t LEHI  = 45 * MEG;
    const size_t LELO  = LEHI  + MEG / 4;
    const size_t LETHI = LELO  + MEG / 4;
    const size_t LETLO = LETHI + MEG / 4;
    const size_t WIHH  = 46 * MEG;
    const size_t WIHL  = WIHH + MEG / 2;
    const size_t SYNC  = 47 * MEG;       // flags[32] + hg u64[8192]
    const size_t W1TH0 = SYNC  + MEG / 4;
    const size_t W1TH1 = W1TH0 + MEG / 2;
    const size_t W2TH0 = W1TH1 + MEG / 2;
    const size_t W2TH1 = W2TH0 + MEG / 2;
    const size_t PTH   = W2TH1 + MEG / 2;
    const size_t PTL   = PTH   + MEG / 4;
    const size_t BSUM  = PTL   + MEG / 4;

    float* pre    = ws + R0;
    float* arena  = ws + AR;
    float* bsum   = ws + BSUM;
    int*   flags  = (int*)(ws + SYNC);
    unsigned long long* hg = (unsigned long long*)(ws + SYNC + 1024);
    unsigned short* qthi  = wsu + 2 * R0;
    unsigned short* q2hi  = wsu + 2 * R1;
    unsigned short* qhi   = wsu + 2 * QHI;
    unsigned short* qlo   = wsu + 2 * QLO;
    unsigned short* fhi   = wsu + 2 * FHI;
    unsigned short* flo   = wsu + 2 * FLO;
    unsigned short* fthi  = wsu + 2 * FTHI;
    unsigned short* ftlo  = wsu + 2 * FTLO;
    unsigned short* lehi  = wsu + 2 * LEHI;
    unsigned short* lelo  = wsu + 2 * LELO;
    unsigned short* lethi = wsu + 2 * LETHI;
    unsigned short* letlo = wsu + 2 * LETLO;
    unsigned short* wihh  = wsu + 2 * WIHH;
    unsigned short* wihl  = wsu + 2 * WIHL;
    unsigned short* w1th0 = wsu + 2 * W1TH0;
    unsigned short* w1th1 = wsu + 2 * W1TH1;
    unsigned short* w2th0 = wsu + 2 * W2TH0;
    unsigned short* w2th1 = wsu + 2 * W2TH1;
    unsigned short* pth   = wsu + 2 * PTH;
    unsigned short* ptl   = wsu + 2 * PTL;

    // ---- prep (feeds pre-GEMM)
    bias_sum_kernel<<<8, 256, 0, stream>>>(bihF, bhhF, bihB, bhhB, bsum);
    cvt_split<<<512, 256, 0, stream>>>(WihF, wihh, wihl);
    cvt_split<<<512, 256, 0, stream>>>(WihB, wihh + 524288, wihl + 524288);
    cvt_split<<<512, 256, 0, stream>>>(le, lehi, lelo);
    { dim3 g(512 / 64, 1024 / 64, 1);
      cvt_split_t<<<g, 256, 0, stream>>>(le, lethi, letlo, 1024, 512); }
    hipMemsetAsync(flags, 0, 32 * sizeof(int), stream);

    unsigned short* xhi = wsu + 2 * AR;
    unsigned short* xlo = wsu + 2 * (AR + MEG);
    cvt_split<<<2048, 256, 0, stream>>>(x, xhi, xlo);

    // ---- LSTM input projection (merged F|B, 3-pass)
    gemm4(3, 0, 0, xhi, xlo, wihh, wihl, bsum, pre, nullptr, nullptr,
          NB * NS, 2048, ND, ND, ND, 0, 0, 0, 1, stream);

    // ---- FUSED: recurrence + L0 score GEMM + weight/proj cvts
    float* wsc_l0 = arena;   // 1M fl
    rec_fused<<<256, 256, 0, stream>>>(pre, WhhF, WhhB, hg, flags, fhi, flo,
                                       lehi, lelo, wsc_l0,
                                       w1, w2, w1th0, w2th0, w1th1, w2th1,
                                       proj, pth, ptl);

    // ---- FUSED: feature transposes + L0 softmax
    post_rec<<<2048, 256, 0, stream>>>(fhi, flo, fthi, ftlo, wsc_l0);

    // ---- layers
    for (int l = 0; l < 2; ++l) {
        const float* b1l = b1 + (size_t)l * NF;
        const float* b2l = b2 + (size_t)l * ND;
        const float* gl  = lng + (size_t)l * ND;
        const float* bl  = lnb + (size_t)l * ND;
        unsigned short* w1th = l ? w1th1 : w1th0;
        unsigned short* w2th = l ? w2th1 : w2th0;

        if (l == 0) {
            unsigned short* wscu = (unsigned short*)wsc_l0;
            unsigned short* q1hi = wsu + 2 * (AR + 1 * MEG);
            unsigned short* q1lo = wsu + 2 * (AR + 1 * MEG + MEG / 4);
            float* s2s = arena + 4 * MEG;
            unsigned short* s2u = (unsigned short*)s2s;

            gemm4(1, 0, 1, wscu, nullptr, lethi, nullptr, nullptr, nullptr, q1hi, q1lo,
                  NH, ND, NH, 2 * NH, NH, 0, 0, 0, 1, stream);
            gemm4(3, 0, 0, q1hi, q1lo, fhi, flo, nullptr, s2s, nullptr, nullptr,
                  NH, NS, ND, ND, ND, 0, (long)NS * ND, (long)NH * NS, 16, stream);
            softmax_ip<<<NB * NH, 256, 0, stream>>>(s2s, NS);
            gemm4(1, 0, 2, s2u, nullptr, fthi, nullptr, nullptr, nullptr, q2hi, nullptr,
                  NH, ND, NS, 2 * NS, NS,
                  (long)2 * NH * NS, (long)ND * NS, (long)NH * ND, 16, stream);
        } else {
            { dim3 g(512 / 64, 1024 / 64, 16);
              tcvt_bf16<<<g, 256, 0, stream>>>(qhi, qthi, 1024, 512); }
            float* wsc = arena;
            unsigned short* wscu = (unsigned short*)wsc;
            unsigned short* q1hi = wsu + 2 * (AR + 8 * MEG);
            unsigned short* q1lo = wsu + 2 * (AR + 10 * MEG);
            float* s2s = arena + 12 * MEG;
            unsigned short* s2u = (unsigned short*)s2s;
            for (int g8 = 0; g8 < 2; ++g8) {
                size_t qo = (size_t)g8 * 8;
                gemm4(3, 0, 0, qhi + qo * NH * ND, qlo + qo * NH * ND,
                      qhi + qo * NH * ND, qlo + qo * NH * ND, nullptr, wsc, nullptr, nullptr,
                      NH, NH, ND, ND, ND,
                      (long)NH * ND, (long)NH * ND, (long)NH * NH, 8, stream);
                softmax_ip<<<8 * NH, 256, 0, stream>>>(wsc, NH);
                gemm4(1, 0, 1, wscu, nullptr, qthi + qo * ND * NH, nullptr,
                      nullptr, nullptr, q1hi, q1lo, NH, ND, NH, 2 * NH, NH,
                      (long)2 * NH * NH, (long)ND * NH, (long)NH * ND, 8, stream);
                gemm4(3, 0, 0, q1hi, q1lo, fhi + qo * NS * ND, flo + qo * NS * ND,
                      nullptr, s2s, nullptr, nullptr, NH, NS, ND, ND, ND,
                      (long)NH * ND, (long)NS * ND, (long)NH * NS, 8, stream);
                softmax_ip<<<8 * NH, 256, 0, stream>>>(s2s, NS);
                gemm4(1, 0, 2, s2u, nullptr, fthi + qo * ND * NS, nullptr,
                      nullptr, nullptr, q2hi + qo * NH * ND, nullptr,
                      NH, ND, NS, 2 * NS, NS,
                      (long)2 * NH * NS, (long)ND * NS, (long)NH * ND, 8, stream);
            }
        }

        // FFN1 (1-pass, gelu, hi-out) then fused FFN2+bias+LN+split
        unsigned short* ffhi = wsu + 2 * AR;
        gemm4(1, 1, 2, q2hi, nullptr, w1th, nullptr, b1l, nullptr, ffhi, nullptr,
              16384, NF, ND, ND, ND, 0, 0, 0, 1, stream);
        ffn2_ln<<<256, 256, 0, stream>>>(ffhi, w2th, b2l, gl, bl, qhi, qlo);
    }

    // ---- final projection
    outproj3<<<4096, 256, 0, stream>>>(qhi, qlo, pth, ptl, out);
}

// Round 15
// 1488.811 us; speedup vs baseline: 2.2115x; 1.0088x over previous
//
#include <hip/hip_runtime.h>
#include <hip/hip_bf16.h>
#include <math.h>

// Problem dims
#define NB 16
#define NS 256
#define ND 512
#define NH 1024
#define NF 2048
#define NHID 256

typedef __attribute__((ext_vector_type(8))) short bf16x8;
typedef __attribute__((ext_vector_type(4))) float f32x4;

__device__ __forceinline__ unsigned short f2bf(float f) {
    unsigned u = __float_as_uint(f);
    unsigned r = u + 0x7fffu + ((u >> 16) & 1u);
    return (unsigned short)(r >> 16);
}
__device__ __forceinline__ float bf2f(unsigned short h) {
    return __uint_as_float(((unsigned)h) << 16);
}
__device__ __forceinline__ float sigmoid_fast(float x) {
    return 1.0f / (1.0f + __expf(-x));
}
__device__ __forceinline__ float tanh_fast(float x) {
    return 1.0f - 2.0f / (__expf(2.0f * x) + 1.0f);
}

// ---------------------------------------------------------------------------
// MFMA GEMM v4: C[M,N] = A[M,K] @ B[N,K]^T (+bias)(+gelu)
// PASSES=3 split hi/lo (~fp32); PASSES=1 bf16. OUT: 0 fp32, 1 split, 2 hi.
// ---------------------------------------------------------------------------
template<int PASSES, int ACT, int OUT>
__global__ __launch_bounds__(256) void sgemm4(
    const unsigned short* __restrict__ Ahi, const unsigned short* __restrict__ Alo,
    const unsigned short* __restrict__ Bhi, const unsigned short* __restrict__ Blo,
    const float* __restrict__ bias,
    float* __restrict__ C, unsigned short* __restrict__ Chi, unsigned short* __restrict__ Clo,
    int M, int N, int K, int lda, int ldb, long sA, long sB, long sC)
{
    __shared__ unsigned short Ah[128 * 32];
    __shared__ unsigned short Bh[128 * 32];
    __shared__ unsigned short Al[(PASSES == 3) ? 128 * 32 : 64];
    __shared__ unsigned short Bl[(PASSES == 3) ? 128 * 32 : 64];

    const int t = threadIdx.x;
    const int z = blockIdx.z;
    const int m0 = blockIdx.y * 128, n0 = blockIdx.x * 128;
    const int wid = t >> 6, lane = t & 63;
    const int wr = (wid >> 1) * 64, wc = (wid & 1) * 64;
    const int lr = lane & 15, lk = lane >> 4;
    const int rl = lane >> 2, sl = lane & 3;

    const unsigned short* pAh = Ahi + (size_t)z * sA;
    const unsigned short* pBh = Bhi + (size_t)z * sB;
    const unsigned short* pAl = (PASSES == 3) ? Alo + (size_t)z * sA : nullptr;
    const unsigned short* pBl = (PASSES == 3) ? Blo + (size_t)z * sB : nullptr;

    f32x4 acc[4][4];
    #pragma unroll
    for (int i = 0; i < 4; ++i)
        #pragma unroll
        for (int j = 0; j < 4; ++j) acc[i][j] = (f32x4){0.f, 0.f, 0.f, 0.f};

    for (int k0 = 0; k0 < K; k0 += 32) {
        #pragma unroll
        for (int e = 0; e < 2; ++e) {
            const int r = e * 64 + wid * 16 + rl;
            const size_t goA = (size_t)(m0 + r) * lda + k0 + sl * 8;
            const size_t goB = (size_t)(n0 + r) * ldb + k0 + sl * 8;
            const int lo = (e * 64 + wid * 16) * 32;
            __builtin_amdgcn_global_load_lds((const void*)(pAh + goA), (void*)&Ah[lo], 16, 0, 0);
            __builtin_amdgcn_global_load_lds((const void*)(pBh + goB), (void*)&Bh[lo], 16, 0, 0);
            if (PASSES == 3) {
                __builtin_amdgcn_global_load_lds((const void*)(pAl + goA), (void*)&Al[lo], 16, 0, 0);
                __builtin_amdgcn_global_load_lds((const void*)(pBl + goB), (void*)&Bl[lo], 16, 0, 0);
            }
        }
        __syncthreads();

        bf16x8 ah[4], bh[4], al[4], bl[4];
        #pragma unroll
        for (int mt = 0; mt < 4; ++mt) {
            int rf = wr + mt * 16 + lr;
            ah[mt] = *(const bf16x8*)&Ah[rf * 32 + lk * 8];
            if (PASSES == 3) al[mt] = *(const bf16x8*)&Al[rf * 32 + lk * 8];
        }
        #pragma unroll
        for (int nt = 0; nt < 4; ++nt) {
            int rf = wc + nt * 16 + lr;
            bh[nt] = *(const bf16x8*)&Bh[rf * 32 + lk * 8];
            if (PASSES == 3) bl[nt] = *(const bf16x8*)&Bl[rf * 32 + lk * 8];
        }
        #pragma unroll
        for (int mt = 0; mt < 4; ++mt)
            #pragma unroll
            for (int nt = 0; nt < 4; ++nt) {
                acc[mt][nt] = __builtin_amdgcn_mfma_f32_16x16x32_bf16(ah[mt], bh[nt], acc[mt][nt], 0, 0, 0);
                if (PASSES == 3) {
                    acc[mt][nt] = __builtin_amdgcn_mfma_f32_16x16x32_bf16(al[mt], bh[nt], acc[mt][nt], 0, 0, 0);
                    acc[mt][nt] = __builtin_amdgcn_mfma_f32_16x16x32_bf16(ah[mt], bl[nt], acc[mt][nt], 0, 0, 0);
                }
            }
        __syncthreads();
    }

    #pragma unroll
    for (int nt = 0; nt < 4; ++nt) {
        int col = n0 + wc + nt * 16 + lr;
        float bv = bias ? bias[col] : 0.0f;
        #pragma unroll
        for (int mt = 0; mt < 4; ++mt) {
            #pragma unroll
            for (int i = 0; i < 4; ++i) {
                int row = m0 + wr + mt * 16 + lk * 4 + i;
                float x = acc[mt][nt][i] + bv;
                if (ACT == 1) x = 0.5f * x * (1.0f + erff(x * 0.70710678118654752f));
                size_t oi = (size_t)z * sC + (size_t)row * N + col;
                if (OUT == 1) {
                    unsigned short h = f2bf(x);
                    Chi[oi] = h;
                    Clo[oi] = f2bf(x - bf2f(h));
                } else if (OUT == 2) {
                    Chi[oi] = f2bf(x);
                } else {
                    C[oi] = x;
                }
            }
        }
    }
}

static void gemm4(int passes, int act, int outm,
                  const unsigned short* Ahi, const unsigned short* Alo,
                  const unsigned short* Bhi, const unsigned short* Blo,
                  const float* bias, float* C, unsigned short* Chi, unsigned short* Clo,
                  int M, int N, int K, int lda, int ldb,
                  long sA, long sB, long sC, int Z, hipStream_t st)
{
    dim3 g(N / 128, M / 128, Z), b(256);
    if (passes == 3) {
        sgemm4<3, 0, 0><<<g, b, 0, st>>>(Ahi, Alo, Bhi, Blo, bias, C, Chi, Clo, M, N, K, lda, ldb, sA, sB, sC);
    } else if (outm == 1) {
        sgemm4<1, 0, 1><<<g, b, 0, st>>>(Ahi, Alo, Bhi, Blo, bias, C, Chi, Clo, M, N, K, lda, ldb, sA, sB, sC);
    } else if (outm == 2 && act == 1) {
        sgemm4<1, 1, 2><<<g, b, 0, st>>>(Ahi, Alo, Bhi, Blo, bias, C, Chi, Clo, M, N, K, lda, ldb, sA, sB, sC);
    } else if (outm == 2) {
        sgemm4<1, 0, 2><<<g, b, 0, st>>>(Ahi, Alo, Bhi, Blo, bias, C, Chi, Clo, M, N, K, lda, ldb, sA, sB, sC);
    } else {
        sgemm4<1, 0, 0><<<g, b, 0, st>>>(Ahi, Alo, Bhi, Blo, bias, C, Chi, Clo, M, N, K, lda, ldb, sA, sB, sC);
    }
}

// ---------------------------------------------------------------------------
// SYMMETRIC 3-pass score GEMM: C[z] = Q[z] @ Q[z]^T  (N x N, N=1024, K=512).
// Computes lower-triangle tiles only (36 of 64); off-diagonal tiles also
// write their transpose (bitwise identical: same products, same k order).
// grid = (36, 1, Z), block = 256.
// ---------------------------------------------------------------------------
__global__ __launch_bounds__(256) void sgemm_sym3(
    const unsigned short* __restrict__ Qhi, const unsigned short* __restrict__ Qlo,
    float* __restrict__ C, long sA, long sC)
{
    __shared__ unsigned short Ah[128 * 32];
    __shared__ unsigned short Bh[128 * 32];
    __shared__ unsigned short Al[128 * 32];
    __shared__ unsigned short Bl[128 * 32];

    const int t = threadIdx.x;
    const int z = blockIdx.z;
    // lower-triangle tile id -> (by, bx), by >= bx
    int tt = blockIdx.x, by = 0;
    #pragma unroll
    for (int r = 0; r < 8; ++r) {
        if (tt >= r + 1 && by == r) { tt -= r + 1; by = r + 1; }
    }
    const int bx = tt;
    const int m0 = by * 128, n0 = bx * 128;

    const int wid = t >> 6, lane = t & 63;
    const int wr = (wid >> 1) * 64, wc = (wid & 1) * 64;
    const int lr = lane & 15, lk = lane >> 4;
    const int rl = lane >> 2, sl = lane & 3;

    const unsigned short* pAh = Qhi + (size_t)z * sA;
    const unsigned short* pAl = Qlo + (size_t)z * sA;

    f32x4 acc[4][4];
    #pragma unroll
    for (int i = 0; i < 4; ++i)
        #pragma unroll
        for (int j = 0; j < 4; ++j) acc[i][j] = (f32x4){0.f, 0.f, 0.f, 0.f};

    for (int k0 = 0; k0 < ND; k0 += 32) {
        #pragma unroll
        for (int e = 0; e < 2; ++e) {
            const int r = e * 64 + wid * 16 + rl;
            const size_t goA = (size_t)(m0 + r) * ND + k0 + sl * 8;
            const size_t goB = (size_t)(n0 + r) * ND + k0 + sl * 8;
            const int lo = (e * 64 + wid * 16) * 32;
            __builtin_amdgcn_global_load_lds((const void*)(pAh + goA), (void*)&Ah[lo], 16, 0, 0);
            __builtin_amdgcn_global_load_lds((const void*)(pAh + goB), (void*)&Bh[lo], 16, 0, 0);
            __builtin_amdgcn_global_load_lds((const void*)(pAl + goA), (void*)&Al[lo], 16, 0, 0);
            __builtin_amdgcn_global_load_lds((const void*)(pAl + goB), (void*)&Bl[lo], 16, 0, 0);
        }
        __syncthreads();

        bf16x8 ah[4], bh[4], al[4], bl[4];
        #pragma unroll
        for (int mt = 0; mt < 4; ++mt) {
            int rf = wr + mt * 16 + lr;
            ah[mt] = *(const bf16x8*)&Ah[rf * 32 + lk * 8];
            al[mt] = *(const bf16x8*)&Al[rf * 32 + lk * 8];
        }
        #pragma unroll
        for (int nt = 0; nt < 4; ++nt) {
            int rf = wc + nt * 16 + lr;
            bh[nt] = *(const bf16x8*)&Bh[rf * 32 + lk * 8];
            bl[nt] = *(const bf16x8*)&Bl[rf * 32 + lk * 8];
        }
        #pragma unroll
        for (int mt = 0; mt < 4; ++mt)
            #pragma unroll
            for (int nt = 0; nt < 4; ++nt) {
                acc[mt][nt] = __builtin_amdgcn_mfma_f32_16x16x32_bf16(ah[mt], bh[nt], acc[mt][nt], 0, 0, 0);
                acc[mt][nt] = __builtin_amdgcn_mfma_f32_16x16x32_bf16(al[mt], bh[nt], acc[mt][nt], 0, 0, 0);
                acc[mt][nt] = __builtin_amdgcn_mfma_f32_16x16x32_bf16(ah[mt], bl[nt], acc[mt][nt], 0, 0, 0);
            }
        __syncthreads();
    }

    float* Cz = C + (size_t)z * sC;
    #pragma unroll
    for (int nt = 0; nt < 4; ++nt) {
        int col = n0 + wc + nt * 16 + lr;
        #pragma unroll
        for (int mt = 0; mt < 4; ++mt) {
            #pragma unroll
            for (int i = 0; i < 4; ++i) {
                int row = m0 + wr + mt * 16 + lk * 4 + i;
                float x = acc[mt][nt][i];
                Cz[(size_t)row * NH + col] = x;
                if (by != bx) Cz[(size_t)col * NH + row] = x;   // bitwise mirror
            }
        }
    }
}

// ---------------------------------------------------------------------------
// FUSED FFN2 + bias + LayerNorm + split output (unchanged from round 14).
// ---------------------------------------------------------------------------
__global__ __launch_bounds__(256) void ffn2_ln(
    const unsigned short* __restrict__ A, const unsigned short* __restrict__ B,
    const float* __restrict__ bias, const float* __restrict__ g, const float* __restrict__ bb,
    unsigned short* __restrict__ Ohi, unsigned short* __restrict__ Olo)
{
    __shared__ unsigned short Ah[64 * 32];
    __shared__ unsigned short Bh[512 * 32];
    __shared__ float stats[64][4][2];

    const int t = threadIdx.x;
    const int m0 = blockIdx.x * 64;
    const int wid = t >> 6, lane = t & 63;
    const int lr = lane & 15, lk = lane >> 4;
    const int wc = wid * 128;
    const int rl = lane >> 2, sl = lane & 3;

    f32x4 acc[4][8];
    #pragma unroll
    for (int i = 0; i < 4; ++i)
        #pragma unroll
        for (int j = 0; j < 8; ++j) acc[i][j] = (f32x4){0.f, 0.f, 0.f, 0.f};

    for (int k0 = 0; k0 < NF; k0 += 32) {
        __builtin_amdgcn_global_load_lds(
            (const void*)(A + (size_t)(m0 + wid * 16 + rl) * NF + k0 + sl * 8),
            (void*)&Ah[(wid * 16) * 32], 16, 0, 0);
        #pragma unroll
        for (int e = 0; e < 8; ++e) {
            int r = e * 64 + wid * 16 + rl;
            __builtin_amdgcn_global_load_lds(
                (const void*)(B + (size_t)r * NF + k0 + sl * 8),
                (void*)&Bh[(e * 64 + wid * 16) * 32], 16, 0, 0);
        }
        __syncthreads();

        bf16x8 af[4], bf[8];
        #pragma unroll
        for (int mt = 0; mt < 4; ++mt)
            af[mt] = *(const bf16x8*)&Ah[(mt * 16 + lr) * 32 + lk * 8];
        #pragma unroll
        for (int nt = 0; nt < 8; ++nt)
            bf[nt] = *(const bf16x8*)&Bh[(wc + nt * 16 + lr) * 32 + lk * 8];
        #pragma unroll
        for (int mt = 0; mt < 4; ++mt)
            #pragma unroll
            for (int nt = 0; nt < 8; ++nt)
                acc[mt][nt] = __builtin_amdgcn_mfma_f32_16x16x32_bf16(af[mt], bf[nt], acc[mt][nt], 0, 0, 0);
        __syncthreads();
    }

    float bv[8];
    #pragma unroll
    for (int nt = 0; nt < 8; ++nt) bv[nt] = bias[wc + nt * 16 + lr];

    float psum[4][4], psq[4][4];
    #pragma unroll
    for (int mt = 0; mt < 4; ++mt)
        #pragma unroll
        for (int i = 0; i < 4; ++i) {
            float s = 0.f, q = 0.f;
            #pragma unroll
            for (int nt = 0; nt < 8; ++nt) {
                float x = acc[mt][nt][i] + bv[nt];
                acc[mt][nt][i] = x;
                s += x;
                q += x * x;
            }
            psum[mt][i] = s;
            psq[mt][i] = q;
        }
    #pragma unroll
    for (int o = 1; o <= 8; o <<= 1)
        #pragma unroll
        for (int mt = 0; mt < 4; ++mt)
            #pragma unroll
            for (int i = 0; i < 4; ++i) {
                psum[mt][i] += __shfl_xor(psum[mt][i], o);
                psq[mt][i]  += __shfl_xor(psq[mt][i], o);
            }
    if (lr == 0) {
        #pragma unroll
        for (int mt = 0; mt < 4; ++mt)
            #pragma unroll
            for (int i = 0; i < 4; ++i) {
                int r = mt * 16 + lk * 4 + i;
                stats[r][wid][0] = psum[mt][i];
                stats[r][wid][1] = psq[mt][i];
            }
    }
    __syncthreads();

    float gv[8], betav[8];
    #pragma unroll
    for (int nt = 0; nt < 8; ++nt) {
        gv[nt]    = g[wc + nt * 16 + lr];
        betav[nt] = bb[wc + nt * 16 + lr];
    }
    #pragma unroll
    for (int mt = 0; mt < 4; ++mt)
        #pragma unroll
        for (int i = 0; i < 4; ++i) {
            int r = mt * 16 + lk * 4 + i;
            float s = stats[r][0][0] + stats[r][1][0] + stats[r][2][0] + stats[r][3][0];
            float q = stats[r][0][1] + stats[r][1][1] + stats[r][2][1] + stats[r][3][1];
            float mu = s * (1.0f / 512.0f);
            float var = q * (1.0f / 512.0f) - mu * mu;
            float inv = rsqrtf(var + 1e-5f);
            #pragma unroll
            for (int nt = 0; nt < 8; ++nt) {
                float y = (acc[mt][nt][i] - mu) * inv * gv[nt] + betav[nt];
                size_t oi = (size_t)(m0 + r) * 512 + wc + nt * 16 + lr;
                unsigned short h = f2bf(y);
                Ohi[oi] = h;
                Olo[oi] = f2bf(y - bf2f(h));
            }
        }
}

// ---------------------------------------------------------------------------
// fp32 -> split bf16 hi/lo (n multiple of 1024)
// ---------------------------------------------------------------------------
__global__ __launch_bounds__(256) void cvt_split(const float* __restrict__ in,
                                                 unsigned short* __restrict__ hi,
                                                 unsigned short* __restrict__ lo)
{
    size_t i = ((size_t)blockIdx.x * 256 + threadIdx.x) * 4;
    float4 v = *(const float4*)(in + i);
    ushort4 h, l;
    h.x = f2bf(v.x); l.x = f2bf(v.x - bf2f(h.x));
    h.y = f2bf(v.y); l.y = f2bf(v.y - bf2f(h.y));
    h.z = f2bf(v.z); l.z = f2bf(v.z - bf2f(h.z));
    h.w = f2bf(v.w); l.w = f2bf(v.w - bf2f(h.w));
    *(ushort4*)(hi + i) = h;
    *(ushort4*)(lo + i) = l;
}

// ---------------------------------------------------------------------------
// fp32 (R,C) -> split bf16 hi/lo TRANSPOSED (C,R). R,C mult of 64.
// ---------------------------------------------------------------------------
__global__ __launch_bounds__(256) void cvt_split_t(const float* __restrict__ in,
                                                   unsigned short* __restrict__ hiT,
                                                   unsigned short* __restrict__ loT,
                                                   int R, int C)
{
    __shared__ unsigned short tileH[64 * 72];
    __shared__ unsigned short tileL[64 * 72];
    int r0 = blockIdx.y * 64, c0 = blockIdx.x * 64;
    int t = threadIdx.x;
    int tr = t >> 2, tc = (t & 3) * 16;

    float v[16];
    const float* src = in + (size_t)(r0 + tr) * C + c0 + tc;
    *(float4*)(v)      = *(const float4*)(src);
    *(float4*)(v + 4)  = *(const float4*)(src + 4);
    *(float4*)(v + 8)  = *(const float4*)(src + 8);
    *(float4*)(v + 12) = *(const float4*)(src + 12);
    #pragma unroll
    for (int i = 0; i < 16; ++i) {
        unsigned short h = f2bf(v[i]);
        tileH[(tc + i) * 72 + tr] = h;
        tileL[(tc + i) * 72 + tr] = f2bf(v[i] - bf2f(h));
    }
    __syncthreads();

    size_t ob = (size_t)(c0 + tr) * R + r0 + tc;
    *(uint4*)(hiT + ob)     = *(const uint4*)(&tileH[tr * 72 + tc]);
    *(uint4*)(hiT + ob + 8) = *(const uint4*)(&tileH[tr * 72 + tc + 8]);
    *(uint4*)(loT + ob)     = *(const uint4*)(&tileL[tr * 72 + tc]);
    *(uint4*)(loT + ob + 8) = *(const uint4*)(&tileL[tr * 72 + tc + 8]);
}

// ---------------------------------------------------------------------------
// bf16 (R,C) -> (C,R) transpose, z-batched. R,C multiples of 64.
// ---------------------------------------------------------------------------
__global__ __launch_bounds__(256) void tcvt_bf16(const unsigned short* __restrict__ in,
                                                 unsigned short* __restrict__ out,
                                                 int R, int C)
{
    __shared__ unsigned short tile[64 * 72];
    int z = blockIdx.z;
    in += (size_t)z * R * C;
    out += (size_t)z * R * C;
    int r0 = blockIdx.y * 64, c0 = blockIdx.x * 64;
    int t = threadIdx.x;
    int tr = t >> 2, tc = (t & 3) * 16;

    uint4 q0 = *(const uint4*)(in + (size_t)(r0 + tr) * C + c0 + tc);
    uint4 q1 = *(const uint4*)(in + (size_t)(r0 + tr) * C + c0 + tc + 8);
    unsigned short e[16];
    *(uint4*)(e) = q0;
    *(uint4*)(e + 8) = q1;
    #pragma unroll
    for (int i = 0; i < 16; ++i) tile[(tc + i) * 72 + tr] = e[i];
    __syncthreads();

    uint4 o0 = *(const uint4*)(&tile[tr * 72 + tc]);
    uint4 o1 = *(const uint4*)(&tile[tr * 72 + tc + 8]);
    *(uint4*)(out + (size_t)(c0 + tr) * R + r0 + tc) = o0;
    *(uint4*)(out + (size_t)(c0 + tr) * R + r0 + tc + 8) = o1;
}

// ---------------------------------------------------------------------------
// bias combine
// ---------------------------------------------------------------------------
__global__ __launch_bounds__(256) void bias_sum_kernel(
    const float* bihF, const float* bhhF, const float* bihB, const float* bhhB,
    float* out)
{
    int i = blockIdx.x * 256 + threadIdx.x;
    if (i < 1024) out[i] = bihF[i] + bhhF[i];
    else out[i] = bihB[i - 1024] + bhhB[i - 1024];
}

// ---------------------------------------------------------------------------
// FUSED rec + helpers (unchanged; rec path identical to measured 809us).
// ---------------------------------------------------------------------------
__global__ __launch_bounds__(256) void rec_fused(
    const float* __restrict__ pre,
    const float* __restrict__ WhhF, const float* __restrict__ WhhB,
    unsigned long long* __restrict__ hg, int* __restrict__ flags,
    unsigned short* __restrict__ fhi, unsigned short* __restrict__ flo,
    const unsigned short* __restrict__ lehi, const unsigned short* __restrict__ lelo,
    float* __restrict__ wsc,
    const float* __restrict__ w1, const float* __restrict__ w2,
    unsigned short* __restrict__ w1th0, unsigned short* __restrict__ w2th0,
    unsigned short* __restrict__ w1th1, unsigned short* __restrict__ w2th1,
    const float* __restrict__ proj,
    unsigned short* __restrict__ pth, unsigned short* __restrict__ ptl)
{
    __shared__ unsigned short hh[16 * 264];
    __shared__ unsigned short hl[16 * 264];
    __shared__ float gx[4][16][17];
    __shared__ unsigned short gAh[128 * 32];
    __shared__ unsigned short gAl[128 * 32];
    __shared__ unsigned short gBh[128 * 32];
    __shared__ unsigned short gBl[128 * 32];
    __shared__ unsigned short tH[64 * 72];
    __shared__ unsigned short tL[64 * 72];

    const int tid = threadIdx.x;

    if (blockIdx.x < 32) {
        const int bid = blockIdx.x;
        const int dir = bid >> 4, slice = bid & 15;
        const float* Whh = dir ? WhhB : WhhF;
        const int wv = tid >> 6;
        const int lane = tid & 63;
        const int lr = lane & 15;
        const int lk = lane >> 4;
        const int eb = tid >> 4;
        const int eu = tid & 15;

        bf16x8 wfh[8], wfl[8];
        {
            const float* wrow = Whh + (size_t)(wv * 256 + slice * 16 + lr) * 256 + lk * 8;
            #pragma unroll
            for (int kt = 0; kt < 8; ++kt) {
                float4 a = *(const float4*)(wrow + kt * 32);
                float4 b = *(const float4*)(wrow + kt * 32 + 4);
                float v[8] = {a.x, a.y, a.z, a.w, b.x, b.y, b.z, b.w};
                unsigned short hhv[8], llv[8];
                #pragma unroll
                for (int i = 0; i < 8; ++i) {
                    unsigned short h = f2bf(v[i]);
                    hhv[i] = h;
                    llv[i] = f2bf(v[i] - bf2f(h));
                }
                wfh[kt] = *(bf16x8*)hhv;
                wfl[kt] = *(bf16x8*)llv;
            }
        }
        for (int i = tid; i < 16 * 264; i += 256) { hh[i] = 0; hl[i] = 0; }

        float c = 0.0f;
        __syncthreads();

        for (int si = 0; si < NS; ++si) {
            const int s = dir ? (NS - 1 - si) : si;
            const float* pp = pre + ((size_t)(eb * NS + s)) * 2048 + dir * 1024 + slice * 16 + eu;
            float pi = pp[0], pf = pp[256], pg = pp[512], po = pp[768];

            if (si > 0) {
                if (tid < 16) {
                    while (__hip_atomic_load(&flags[dir * 16 + tid], __ATOMIC_RELAXED,
                                             __HIP_MEMORY_SCOPE_AGENT) < si) {
                        __builtin_amdgcn_s_sleep(1);
                    }
                }
                __syncthreads();
                const unsigned long long* src =
                    hg + (size_t)(((si - 1) & 1) * 2 + dir) * 2048;
                const int b2 = tid >> 4, pb = (tid & 15) * 8;
                unsigned short hbuf[16], lbuf[16];
                #pragma unroll
                for (int j = 0; j < 8; ++j) {
                    unsigned long long v = __hip_atomic_load(
                        &src[b2 * 128 + pb + j], __ATOMIC_RELAXED,
                        __HIP_MEMORY_SCOPE_AGENT);
                    hbuf[2 * j]     = (unsigned short)(v & 0xffff);
                    lbuf[2 * j]     = (unsigned short)((v >> 16) & 0xffff);
                    hbuf[2 * j + 1] = (unsigned short)((v >> 32) & 0xffff);
                    lbuf[2 * j + 1] = (unsigned short)(v >> 48);
                }
                char* dh = (char*)hh + b2 * 528 + (tid & 15) * 32;
                char* dl = (char*)hl + b2 * 528 + (tid & 15) * 32;
                *(uint4*)dh        = *(uint4*)(hbuf);
                *(uint4*)(dh + 16) = *(uint4*)(hbuf + 8);
                *(uint4*)dl        = *(uint4*)(lbuf);
                *(uint4*)(dl + 16) = *(uint4*)(lbuf + 8);
                __syncthreads();
            }

            f32x4 acc = (f32x4){0.f, 0.f, 0.f, 0.f};
            #pragma unroll
            for (int kt = 0; kt < 8; ++kt) {
                const char* hp = (const char*)hh + lr * 528 + kt * 64 + lk * 16;
                const char* lp = (const char*)hl + lr * 528 + kt * 64 + lk * 16;
                bf16x8 ah = *(const bf16x8*)hp;
                bf16x8 al = *(const bf16x8*)lp;
                acc = __builtin_amdgcn_mfma_f32_16x16x32_bf16(ah, wfh[kt], acc, 0, 0, 0);
                acc = __builtin_amdgcn_mfma_f32_16x16x32_bf16(al, wfh[kt], acc, 0, 0, 0);
                acc = __builtin_amdgcn_mfma_f32_16x16x32_bf16(ah, wfl[kt], acc, 0, 0, 0);
            }
            #pragma unroll
            for (int i = 0; i < 4; ++i) gx[wv][lk * 4 + i][lr] = acc[i];
            __syncthreads();

            float ai = gx[0][eb][eu] + pi;
            float af = gx[1][eb][eu] + pf;
            float ag = gx[2][eb][eu] + pg;
            float ao = gx[3][eb][eu] + po;
            float gi = sigmoid_fast(ai);
            float gf = sigmoid_fast(af);
            float gg = tanh_fast(ag);
            float go = sigmoid_fast(ao);
            c = gf * c + gi * gg;
            float h = go * tanh_fast(c);

            unsigned short h16 = f2bf(h);
            unsigned short l16 = f2bf(h - bf2f(h16));
            unsigned my = (unsigned)h16 | ((unsigned)l16 << 16);
            unsigned oth = __shfl_xor(my, 1);
            if ((eu & 1) == 0) {
                unsigned long long v = (unsigned long long)my |
                                       ((unsigned long long)oth << 32);
                unsigned long long* dst =
                    hg + (size_t)((si & 1) * 2 + dir) * 2048;
                __hip_atomic_store(&dst[eb * 128 + slice * 8 + (eu >> 1)], v,
                                   __ATOMIC_RELAXED, __HIP_MEMORY_SCOPE_AGENT);
            }
            size_t oi = ((size_t)(eb * NS + s)) * 512 + dir * 256 + slice * 16 + eu;
            fhi[oi] = h16;
            flo[oi] = l16;

            asm volatile("s_waitcnt vmcnt(0)" ::: "memory");
            __syncthreads();
            if (tid == 0)
                __hip_atomic_store(&flags[bid], si + 1, __ATOMIC_RELAXED,
                                   __HIP_MEMORY_SCOPE_AGENT);
        }
        return;
    }

    // ================= HELPERS =================
    const int hid = blockIdx.x - 32;
    const int lane = tid & 63;
    const int wid = tid >> 6;
    const int lr = lane & 15, lk = lane >> 4;

    if (hid < 64) {
        const int m0 = (hid >> 3) * 128, n0 = (hid & 7) * 128;
        const int wr = (wid >> 1) * 64, wc = (wid & 1) * 64;
        const int sr = tid >> 1, sc = (tid & 1) * 16;

        f32x4 acc[4][4];
        #pragma unroll
        for (int i = 0; i < 4; ++i)
            #pragma unroll
            for (int j = 0; j < 4; ++j) acc[i][j] = (f32x4){0.f, 0.f, 0.f, 0.f};

        for (int k0 = 0; k0 < ND; k0 += 32) {
            {
                size_t oa = (size_t)(m0 + sr) * ND + k0 + sc;
                size_t ob = (size_t)(n0 + sr) * ND + k0 + sc;
                *(uint4*)&gAh[sr * 32 + sc]     = *(const uint4*)(lehi + oa);
                *(uint4*)&gAh[sr * 32 + sc + 8] = *(const uint4*)(lehi + oa + 8);
                *(uint4*)&gAl[sr * 32 + sc]     = *(const uint4*)(lelo + oa);
                *(uint4*)&gAl[sr * 32 + sc + 8] = *(const uint4*)(lelo + oa + 8);
                *(uint4*)&gBh[sr * 32 + sc]     = *(const uint4*)(lehi + ob);
                *(uint4*)&gBh[sr * 32 + sc + 8] = *(const uint4*)(lehi + ob + 8);
                *(uint4*)&gBl[sr * 32 + sc]     = *(const uint4*)(lelo + ob);
                *(uint4*)&gBl[sr * 32 + sc + 8] = *(const uint4*)(lelo + ob + 8);
            }
            __syncthreads();

            bf16x8 ah[4], al[4], bh[4], bl[4];
            #pragma unroll
            for (int mt = 0; mt < 4; ++mt) {
                int rf = wr + mt * 16 + lr;
                ah[mt] = *(const bf16x8*)&gAh[rf * 32 + lk * 8];
                al[mt] = *(const bf16x8*)&gAl[rf * 32 + lk * 8];
            }
            #pragma unroll
            for (int nt = 0; nt < 4; ++nt) {
                int rf = wc + nt * 16 + lr;
                bh[nt] = *(const bf16x8*)&gBh[rf * 32 + lk * 8];
                bl[nt] = *(const bf16x8*)&gBl[rf * 32 + lk * 8];
            }
            #pragma unroll
            for (int mt = 0; mt < 4; ++mt)
                #pragma unroll
                for (int nt = 0; nt < 4; ++nt) {
                    acc[mt][nt] = __builtin_amdgcn_mfma_f32_16x16x32_bf16(ah[mt], bh[nt], acc[mt][nt], 0, 0, 0);
                    acc[mt][nt] = __builtin_amdgcn_mfma_f32_16x16x32_bf16(al[mt], bh[nt], acc[mt][nt], 0, 0, 0);
                    acc[mt][nt] = __builtin_amdgcn_mfma_f32_16x16x32_bf16(ah[mt], bl[nt], acc[mt][nt], 0, 0, 0);
                }
            __syncthreads();
        }
        const int wr2 = (wid >> 1) * 64, wc2 = (wid & 1) * 64;
        #pragma unroll
        for (int nt = 0; nt < 4; ++nt) {
            int col = n0 + wc2 + nt * 16 + lr;
            #pragma unroll
            for (int mt = 0; mt < 4; ++mt)
                #pragma unroll
                for (int i = 0; i < 4; ++i) {
                    int row = m0 + wr2 + mt * 16 + lk * 4 + i;
                    wsc[(size_t)row * NH + col] = acc[mt][nt][i];
                }
        }
    }

    const int tr = tid >> 2, tc = (tid & 3) * 16;
    for (int job = hid; job < 1152; job += 224) {
        const float* in;
        unsigned short* outH;
        unsigned short* outL = nullptr;
        int R, C, by, bx;
        if (job < 256)        { int j = job;        in = w1;              outH = w1th0; R = ND; C = NF; by = j >> 5, bx = j & 31; }
        else if (job < 512)   { int j = job - 256;  in = w2;              outH = w2th0; R = NF; C = ND; by = j >> 3, bx = j & 7; }
        else if (job < 768)   { int j = job - 512;  in = w1 + (size_t)ND * NF; outH = w1th1; R = ND; C = NF; by = j >> 5, bx = j & 31; }
        else if (job < 1024)  { int j = job - 768;  in = w2 + (size_t)NF * ND; outH = w2th1; R = NF; C = ND; by = j >> 3, bx = j & 7; }
        else                  { int j = job - 1024; in = proj;            outH = pth; outL = ptl; R = 512; C = 1024; by = j >> 4, bx = j & 15; }

        int r0 = by * 64, c0 = bx * 64;
        __syncthreads();
        float v[16];
        const float* src = in + (size_t)(r0 + tr) * C + c0 + tc;
        *(float4*)(v)      = *(const float4*)(src);
        *(float4*)(v + 4)  = *(const float4*)(src + 4);
        *(float4*)(v + 8)  = *(const float4*)(src + 8);
        *(float4*)(v + 12) = *(const float4*)(src + 12);
        if (outL) {
            #pragma unroll
            for (int i = 0; i < 16; ++i) {
                unsigned short h = f2bf(v[i]);
                tH[(tc + i) * 72 + tr] = h;
                tL[(tc + i) * 72 + tr] = f2bf(v[i] - bf2f(h));
            }
        } else {
            #pragma unroll
            for (int i = 0; i < 16; ++i) tH[(tc + i) * 72 + tr] = f2bf(v[i]);
        }
        __syncthreads();
        size_t ob = (size_t)(c0 + tr) * R + r0 + tc;
        *(uint4*)(outH + ob)     = *(const uint4*)(&tH[tr * 72 + tc]);
        *(uint4*)(outH + ob + 8) = *(const uint4*)(&tH[tr * 72 + tc + 8]);
        if (outL) {
            *(uint4*)(outL + ob)     = *(const uint4*)(&tL[tr * 72 + tc]);
            *(uint4*)(outL + ob + 8) = *(const uint4*)(&tL[tr * 72 + tc + 8]);
        }
    }
}

// ---------------------------------------------------------------------------
// FUSED post-rec: feature transposes + L0 wsc softmax (unchanged).
// ---------------------------------------------------------------------------
__global__ __launch_bounds__(256) void post_rec(
    const unsigned short* __restrict__ fhi, const unsigned short* __restrict__ flo,
    unsigned short* __restrict__ fthi, unsigned short* __restrict__ ftlo,
    float* __restrict__ wsc)
{
    __shared__ unsigned short tile[64 * 72];
    __shared__ float lm[4];
    __shared__ float ls[4];
    const int t = threadIdx.x;

    if (blockIdx.x < 1024) {
        int job = blockIdx.x;
        const unsigned short* in;
        unsigned short* out;
        if (job < 512) { in = fhi; out = fthi; } else { in = flo; out = ftlo; job -= 512; }
        const int R = 256, C = 512;
        int z = job >> 5, jj = job & 31;
        int bx = jj & 7, by = jj >> 3;
        in  += (size_t)z * R * C;
        out += (size_t)z * R * C;
        int r0 = by * 64, c0 = bx * 64;
        int tr = t >> 2, tc = (t & 3) * 16;

        uint4 q0 = *(const uint4*)(in + (size_t)(r0 + tr) * C + c0 + tc);
        uint4 q1 = *(const uint4*)(in + (size_t)(r0 + tr) * C + c0 + tc + 8);
        unsigned short e[16];
        *(uint4*)(e) = q0;
        *(uint4*)(e + 8) = q1;
        #pragma unroll
        for (int i = 0; i < 16; ++i) tile[(tc + i) * 72 + tr] = e[i];
        __syncthreads();

        *(uint4*)(out + (size_t)(c0 + tr) * R + r0 + tc)     = *(const uint4*)(&tile[tr * 72 + tc]);
        *(uint4*)(out + (size_t)(c0 + tr) * R + r0 + tc + 8) = *(const uint4*)(&tile[tr * 72 + tc + 8]);
        return;
    }

    const int N = 1024;
    float* row = wsc + (size_t)(blockIdx.x - 1024) * N;
    unsigned short* o = (unsigned short*)row;
    float v[4];
    float m = -1e30f;
    #pragma unroll
    for (int i = 0; i < 4; ++i) { v[i] = row[t + (i << 8)]; m = fmaxf(m, v[i]); }
    for (int sh = 32; sh; sh >>= 1) m = fmaxf(m, __shfl_xor(m, sh));
    if ((t & 63) == 0) lm[t >> 6] = m;
    __syncthreads();
    m = fmaxf(fmaxf(lm[0], lm[1]), fmaxf(lm[2], lm[3]));
    float s = 0.0f;
    #pragma unroll
    for (int i = 0; i < 4; ++i) { v[i] = expf(v[i] - m); s += v[i]; }
    for (int sh = 32; sh; sh >>= 1) s += __shfl_xor(s, sh);
    if ((t & 63) == 0) ls[t >> 6] = s;
    __syncthreads();
    s = ls[0] + ls[1] + ls[2] + ls[3];
    float inv = 1.0f / s;
    __syncthreads();
    #pragma unroll
    for (int i = 0; i < 4; ++i) {
        float y = v[i] * inv;
        unsigned short h = f2bf(y);
        int j = t + (i << 8);
        o[j] = h;
        o[N + j] = f2bf(y - bf2f(h));
    }
}

// ---------------------------------------------------------------------------
// In-place split softmax
// ---------------------------------------------------------------------------
__global__ __launch_bounds__(256) void softmax_ip(float* __restrict__ X, int N)
{
    float* row = X + (size_t)blockIdx.x * N;
    unsigned short* o = (unsigned short*)row;
    int t = threadIdx.x;
    int cnt = N >> 8;
    float v[4];
    float m = -1e30f;
    for (int i = 0; i < cnt; ++i) { v[i] = row[t + (i << 8)]; m = fmaxf(m, v[i]); }
    for (int sh = 32; sh; sh >>= 1) m = fmaxf(m, __shfl_xor(m, sh));
    __shared__ float lm[4];
    if ((t & 63) == 0) lm[t >> 6] = m;
    __syncthreads();
    m = fmaxf(fmaxf(lm[0], lm[1]), fmaxf(lm[2], lm[3]));
    float s = 0.0f;
    for (int i = 0; i < cnt; ++i) { v[i] = expf(v[i] - m); s += v[i]; }
    for (int sh = 32; sh; sh >>= 1) s += __shfl_xor(s, sh);
    __shared__ float ls[4];
    if ((t & 63) == 0) ls[t >> 6] = s;
    __syncthreads();
    s = ls[0] + ls[1] + ls[2] + ls[3];
    float inv = 1.0f / s;
    __syncthreads();
    for (int i = 0; i < cnt; ++i) {
        float y = v[i] * inv;
        unsigned short h = f2bf(y);
        int j = t + (i << 8);
        o[j] = h;
        o[N + j] = f2bf(y - bf2f(h));
    }
}

// ---------------------------------------------------------------------------
// out[b,h] = dot(q[b,h,:], projT[h,:]) with hi+lo reconstruction
// ---------------------------------------------------------------------------
__global__ __launch_bounds__(256) void outproj3(
    const unsigned short* __restrict__ qhi, const unsigned short* __restrict__ qlo,
    const unsigned short* __restrict__ phi, const unsigned short* __restrict__ plo,
    float* __restrict__ out)
{
    int gw = blockIdx.x * 4 + (threadIdx.x >> 6);
    int lane = threadIdx.x & 63;
    int h = gw & 1023;
    uint4 qh = ((const uint4*)(qhi + (size_t)gw * 512))[lane];
    uint4 ql = ((const uint4*)(qlo + (size_t)gw * 512))[lane];
    uint4 ph = ((const uint4*)(phi + (size_t)h * 512))[lane];
    uint4 pl = ((const uint4*)(plo + (size_t)h * 512))[lane];
    unsigned short qhe[8], qle[8], phe[8], ple[8];
    *(uint4*)qhe = qh; *(uint4*)qle = ql; *(uint4*)phe = ph; *(uint4*)ple = pl;
    float s = 0.0f;
    #pragma unroll
    for (int i = 0; i < 8; ++i) {
        float q = bf2f(qhe[i]) + bf2f(qle[i]);
        float p = bf2f(phe[i]) + bf2f(ple[i]);
        s += q * p;
    }
    for (int o = 32; o; o >>= 1) s += __shfl_xor(s, o);
    if (lane == 0) out[gw] = s;
}

// ---------------------------------------------------------------------------
// launcher
// ---------------------------------------------------------------------------
extern "C" void kernel_launch(void* const* d_in, const int* in_sizes, int n_in,
                              void* d_out, int out_size, void* d_ws, size_t ws_size,
                              hipStream_t stream)
{
    (void)in_sizes; (void)n_in; (void)out_size; (void)ws_size;

    const float* x     = (const float*)d_in[0];
    const float* le    = (const float*)d_in[1];
    const float* proj  = (const float*)d_in[2];
    const float* WihF  = (const float*)d_in[3];
    const float* WhhF  = (const float*)d_in[4];
    const float* bihF  = (const float*)d_in[5];
    const float* bhhF  = (const float*)d_in[6];
    const float* WihB  = (const float*)d_in[7];
    const float* WhhB  = (const float*)d_in[8];
    const float* bihB  = (const float*)d_in[9];
    const float* bhhB  = (const float*)d_in[10];
    const float* w1    = (const float*)d_in[11];
    const float* b1    = (const float*)d_in[12];
    const float* w2    = (const float*)d_in[13];
    const float* b2    = (const float*)d_in[14];
    const float* lng   = (const float*)d_in[15];
    const float* lnb   = (const float*)d_in[16];
    float* out = (float*)d_out;
    float* ws  = (float*)d_ws;
    unsigned short* wsu = (unsigned short*)d_ws;

    const size_t MEG = 1048576;
    const size_t R0    = 0;              // 8M: pre -> qtT hi [0,4M) + q1hi [4M,8M)
    const size_t R1    = 8 * MEG;        // 8M: q2 hi [0,4M) + q1lo [4M,8M)
    const size_t AR    = 16 * MEG;       // 17M arena: wsc (16M fl) / ffhi
    const size_t QHI   = 33 * MEG;
    const size_t QLO   = 37 * MEG;       // also s2s fp32 in L1 window
    const size_t FHI   = 41 * MEG;
    const size_t FLO   = 42 * MEG;
    const size_t FTHI  = 43 * MEG;
    const size_t FTLO  = 44 * MEG;
    const size_t LEHI  = 45 * MEG;
    const size_t LELO  = LEHI  + MEG / 4;
    const size_t LETHI = LELO  + MEG / 4;
    const size_t LETLO = LETHI + MEG / 4;
    const size_t WIHH  = 46 * MEG;
    const size_t WIHL  = WIHH + MEG / 2;
    const size_t SYNC  = 47 * MEG;       // flags[32] + hg u64[8192]
    const size_t W1TH0 = SYNC  + MEG / 4;
    const size_t W1TH1 = W1TH0 + MEG / 2;
    const size_t W2TH0 = W1TH1 + MEG / 2;
    const size_t W2TH1 = W2TH0 + MEG / 2;
    const size_t PTH   = W2TH1 + MEG / 2;
    const size_t PTL   = PTH   + MEG / 4;
    const size_t BSUM  = PTL   + MEG / 4;

    float* pre    = ws + R0;
    float* arena  = ws + AR;
    float* bsum   = ws + BSUM;
    int*   flags  = (int*)(ws + SYNC);
    unsigned long long* hg = (unsigned long long*)(ws + SYNC + 1024);
    unsigned short* qthi  = wsu + 2 * R0;
    unsigned short* q2hi  = wsu + 2 * R1;
    unsigned short* qhi   = wsu + 2 * QHI;
    unsigned short* qlo   = wsu + 2 * QLO;
    unsigned short* fhi   = wsu + 2 * FHI;
    unsigned short* flo   = wsu + 2 * FLO;
    unsigned short* fthi  = wsu + 2 * FTHI;
    unsigned short* ftlo  = wsu + 2 * FTLO;
    unsigned short* lehi  = wsu + 2 * LEHI;
    unsigned short* lelo  = wsu + 2 * LELO;
    unsigned short* lethi = wsu + 2 * LETHI;
    unsigned short* letlo = wsu + 2 * LETLO;
    unsigned short* wihh  = wsu + 2 * WIHH;
    unsigned short* wihl  = wsu + 2 * WIHL;
    unsigned short* w1th0 = wsu + 2 * W1TH0;
    unsigned short* w1th1 = wsu + 2 * W1TH1;
    unsigned short* w2th0 = wsu + 2 * W2TH0;
    unsigned short* w2th1 = wsu + 2 * W2TH1;
    unsigned short* pth   = wsu + 2 * PTH;
    unsigned short* ptl   = wsu + 2 * PTL;

    // ---- prep (feeds pre-GEMM)
    bias_sum_kernel<<<8, 256, 0, stream>>>(bihF, bhhF, bihB, bhhB, bsum);
    cvt_split<<<512, 256, 0, stream>>>(WihF, wihh, wihl);
    cvt_split<<<512, 256, 0, stream>>>(WihB, wihh + 524288, wihl + 524288);
    cvt_split<<<512, 256, 0, stream>>>(le, lehi, lelo);
    { dim3 g(512 / 64, 1024 / 64, 1);
      cvt_split_t<<<g, 256, 0, stream>>>(le, lethi, letlo, 1024, 512); }
    hipMemsetAsync(flags, 0, 32 * sizeof(int), stream);

    unsigned short* xhi = wsu + 2 * AR;
    unsigned short* xlo = wsu + 2 * (AR + MEG);
    cvt_split<<<2048, 256, 0, stream>>>(x, xhi, xlo);

    // ---- LSTM input projection (merged F|B, 3-pass)
    gemm4(3, 0, 0, xhi, xlo, wihh, wihl, bsum, pre, nullptr, nullptr,
          NB * NS, 2048, ND, ND, ND, 0, 0, 0, 1, stream);

    // ---- FUSED: recurrence + L0 score GEMM + weight/proj cvts
    float* wsc_l0 = arena;   // 1M fl
    rec_fused<<<256, 256, 0, stream>>>(pre, WhhF, WhhB, hg, flags, fhi, flo,
                                       lehi, lelo, wsc_l0,
                                       w1, w2, w1th0, w2th0, w1th1, w2th1,
                                       proj, pth, ptl);

    // ---- FUSED: feature transposes + L0 softmax
    post_rec<<<2048, 256, 0, stream>>>(fhi, flo, fthi, ftlo, wsc_l0);

    // ---- layers
    for (int l = 0; l < 2; ++l) {
        const float* b1l = b1 + (size_t)l * NF;
        const float* b2l = b2 + (size_t)l * ND;
        const float* gl  = lng + (size_t)l * ND;
        const float* bl  = lnb + (size_t)l * ND;
        unsigned short* w1th = l ? w1th1 : w1th0;
        unsigned short* w2th = l ? w2th1 : w2th0;

        if (l == 0) {
            unsigned short* wscu = (unsigned short*)wsc_l0;
            unsigned short* q1hi = wsu + 2 * (AR + 1 * MEG);
            unsigned short* q1lo = wsu + 2 * (AR + 1 * MEG + MEG / 4);
            float* s2s = arena + 4 * MEG;
            unsigned short* s2u = (unsigned short*)s2s;

            gemm4(1, 0, 1, wscu, nullptr, lethi, nullptr, nullptr, nullptr, q1hi, q1lo,
                  NH, ND, NH, 2 * NH, NH, 0, 0, 0, 1, stream);
            gemm4(3, 0, 0, q1hi, q1lo, fhi, flo, nullptr, s2s, nullptr, nullptr,
                  NH, NS, ND, ND, ND, 0, (long)NS * ND, (long)NH * NS, 16, stream);
            softmax_ip<<<NB * NH, 256, 0, stream>>>(s2s, NS);
            gemm4(1, 0, 2, s2u, nullptr, fthi, nullptr, nullptr, nullptr, q2hi, nullptr,
                  NH, ND, NS, 2 * NS, NS,
                  (long)2 * NH * NS, (long)ND * NS, (long)NH * ND, 16, stream);
        } else {
            // qt transpose (hi only, q1 path)
            { dim3 g(512 / 64, 1024 / 64, 16);
              tcvt_bf16<<<g, 256, 0, stream>>>(qhi, qthi, 1024, 512); }
            // Z=16 symmetric score GEMM: wsc = q @ q^T (lower triangle + mirror)
            float* wsc = arena;                                    // 16M fl
            unsigned short* wscu = (unsigned short*)wsc;
            unsigned short* q1hi = wsu + 2 * (R0 + 4 * MEG);       // 8M u16
            unsigned short* q1lo = wsu + 2 * (R1 + 4 * MEG);       // 8M u16
            float* s2s = ws + QLO;                                 // 4M fl (qlo dead here)
            unsigned short* s2u = (unsigned short*)s2s;

            { dim3 g(36, 1, 16), b(256);
              sgemm_sym3<<<g, b, 0, stream>>>(qhi, qlo, wsc,
                                              (long)NH * ND, (long)NH * NH); }
            softmax_ip<<<16 * NH, 256, 0, stream>>>(wsc, NH);
            gemm4(1, 0, 1, wscu, nullptr, qthi, nullptr, nullptr, nullptr, q1hi, q1lo,
                  NH, ND, NH, 2 * NH, NH,
                  (long)2 * NH * NH, (long)ND * NH, (long)NH * ND, 16, stream);
            gemm4(3, 0, 0, q1hi, q1lo, fhi, flo, nullptr, s2s, nullptr, nullptr,
                  NH, NS, ND, ND, ND,
                  (long)NH * ND, (long)NS * ND, (long)NH * NS, 16, stream);
            softmax_ip<<<16 * NH, 256, 0, stream>>>(s2s, NS);
            gemm4(1, 0, 2, s2u, nullptr, fthi, nullptr, nullptr, nullptr, q2hi, nullptr,
                  NH, ND, NS, 2 * NS, NS,
                  (long)2 * NH * NS, (long)ND * NS, (long)NH * ND, 16, stream);
        }

        // FFN1 (1-pass, gelu, hi-out) then fused FFN2+bias+LN+split
        unsigned short* ffhi = wsu + 2 * AR;
        gemm4(1, 1, 2, q2hi, nullptr, w1th, nullptr, b1l, nullptr, ffhi, nullptr,
              16384, NF, ND, ND, ND, 0, 0, 0, 1, stream);
        ffn2_ln<<<256, 256, 0, stream>>>(ffhi, w2th, b2l, gl, bl, qhi, qlo);
    }

    // ---- final projection
    outproj3<<<4096, 256, 0, stream>>>(qhi, qlo, pth, ptl, out);
}